// Round 6
// baseline (22515.939 us; speedup 1.0000x reference)
//
#include <hip/hip_runtime.h>
#include <cstdint>
#include <cstddef>

#define BB 512
#define TT 32
#define LL 1024
#define ZZ 128

typedef unsigned short ushort_t;
typedef __attribute__((ext_vector_type(8))) short s8v;    // 8 bf16 (4 VGPRs)
typedef __attribute__((ext_vector_type(4))) float f32x4;

// ---------------- math helpers ----------------
__device__ __forceinline__ float sigf(float x) { return 1.0f / (1.0f + expf(-x)); }

__device__ __forceinline__ ushort_t f2bf(float f) {
  uint32_t u = __float_as_uint(f);
  uint32_t r = (u + 0x7FFFu + ((u >> 16) & 1u)) >> 16;   // RNE
  return (ushort_t)r;
}
__device__ __forceinline__ float bf2f(ushort_t h) {
  return __uint_as_float(((uint32_t)h) << 16);
}
__device__ __forceinline__ void splitf(float v, ushort_t& hi, ushort_t& lo) {
  hi = f2bf(v);
  lo = f2bf(v - bf2f(hi));
}

// XLA ErfInv32 (Giles polynomial)
__device__ __forceinline__ float jax_erfinv(float x) {
  float w = -log1pf(-x * x);
  float p;
  if (w < 5.0f) {
    w = w - 2.5f;
    p = 2.81022636e-08f;
    p = fmaf(p, w, 3.43273939e-07f);
    p = fmaf(p, w, -3.5233877e-06f);
    p = fmaf(p, w, -4.39150654e-06f);
    p = fmaf(p, w, 0.00021858087f);
    p = fmaf(p, w, -0.00125372503f);
    p = fmaf(p, w, -0.00417768164f);
    p = fmaf(p, w, 0.246640727f);
    p = fmaf(p, w, 1.50140941f);
  } else {
    w = sqrtf(w) - 3.0f;
    p = -0.000200214257f;
    p = fmaf(p, w, 0.000100950558f);
    p = fmaf(p, w, 0.00134934322f);
    p = fmaf(p, w, -0.00367342844f);
    p = fmaf(p, w, 0.00573950773f);
    p = fmaf(p, w, -0.0076224613f);
    p = fmaf(p, w, 0.00943887047f);
    p = fmaf(p, w, 1.00167406f);
    p = fmaf(p, w, 2.83297682f);
  }
  return p * x;
}

// Threefry-2x32, 20 rounds (JAX schedule)
__device__ __forceinline__ void threefry(uint32_t k0, uint32_t k1,
                                         uint32_t x0, uint32_t x1,
                                         uint32_t& o0, uint32_t& o1) {
  uint32_t ks0 = k0, ks1 = k1, ks2 = k0 ^ k1 ^ 0x1BD11BDAu;
  x0 += ks0; x1 += ks1;
#define TF_ROT(x, d) (((x) << (d)) | ((x) >> (32 - (d))))
#define TF_RND(r) { x0 += x1; x1 = TF_ROT(x1, r); x1 ^= x0; }
  TF_RND(13) TF_RND(15) TF_RND(26) TF_RND(6)
  x0 += ks1; x1 += ks2 + 1u;
  TF_RND(17) TF_RND(29) TF_RND(16) TF_RND(24)
  x0 += ks2; x1 += ks0 + 2u;
  TF_RND(13) TF_RND(15) TF_RND(26) TF_RND(6)
  x0 += ks0; x1 += ks1 + 3u;
  TF_RND(17) TF_RND(29) TF_RND(16) TF_RND(24)
  x0 += ks1; x1 += ks2 + 4u;
  TF_RND(13) TF_RND(15) TF_RND(26) TF_RND(6)
  x0 += ks2; x1 += ks0 + 5u;
#undef TF_RND
#undef TF_ROT
  o0 = x0; o1 = x1;
}

__device__ __forceinline__ float bits_to_normal(uint32_t bits) {
  uint32_t fb = (bits >> 9) | 0x3f800000u;
  float f = __uint_as_float(fb) - 1.0f;
  const float lo = -0.99999994f;
  float u = fmaxf(lo, f * 2.0f + lo);
  return 1.41421356237f * jax_erfinv(u);
}

// ---------------- weight split: f32 -> bf16 hi/lo ----------------
__global__ __launch_bounds__(256) void k_split(const float* __restrict__ src,
                                               ushort_t* __restrict__ hi,
                                               ushort_t* __restrict__ lo, int n) {
  int i = blockIdx.x * 256 + threadIdx.x;
  if (i >= n) return;
  ushort_t h, l;
  splitf(src[i], h, l);
  hi[i] = h; lo[i] = l;
}

// ---------------- MFMA GEMM: C[512][N] = sum_seg A_s @ W_s^T + b0 + b1 ----------------
// Tile 64(M) x 128(N), BK=64; 4 waves as 2x2, each wave 32x64 out (2x4 16x16 frags).
struct Seg { const ushort_t* A; const ushort_t* W; int K; int lda; int ldw; };
struct SegList { Seg s[9]; int n; };

__device__ __forceinline__ void load_tiles(const Seg& sg, int bm, int bn, int N, int k0,
                                           int tid, s8v va[2], s8v vw[4]) {
#pragma unroll
  for (int i = 0; i < 2; ++i) {
    int cch = tid + 256 * i;
    int row = cch >> 3, col = cch & 7;
    va[i] = *(const s8v*)(sg.A + (size_t)(bm + row) * sg.lda + k0 + col * 8);
  }
#pragma unroll
  for (int i = 0; i < 4; ++i) {
    int cch = tid + 256 * i;
    int row = cch >> 3, col = cch & 7;
    int n = bn + row;
    if (n < N) vw[i] = *(const s8v*)(sg.W + (size_t)n * sg.ldw + k0 + col * 8);
    else       vw[i] = (s8v)(short)0;
  }
}

__global__ __launch_bounds__(256) void mfma_gemm(
    float* __restrict__ C, int N, SegList segs,
    const float* __restrict__ b0, const float* __restrict__ b1) {
  __shared__ __align__(16) ushort_t As[64][72];    // pad 8 elems: stride 36 dwords
  __shared__ __align__(16) ushort_t Ws[128][72];
  const int bm = blockIdx.y * 64, bn = blockIdx.x * 128;
  const int tid = threadIdx.x;
  const int w = tid >> 6, lane = tid & 63;
  const int wr = w >> 1, wc = w & 1;               // wave grid 2(M) x 2(N)
  const int lr = lane & 15, lq = lane >> 4;
  f32x4 acc[2][4] = {};

  int si = 0, k0 = 0;
  s8v va[2], vw[4];
  load_tiles(segs.s[0], bm, bn, N, 0, tid, va, vw);
  while (1) {
    __syncthreads();
#pragma unroll
    for (int i = 0; i < 2; ++i) {
      int cch = tid + 256 * i;
      *(s8v*)&As[cch >> 3][(cch & 7) * 8] = va[i];
    }
#pragma unroll
    for (int i = 0; i < 4; ++i) {
      int cch = tid + 256 * i;
      *(s8v*)&Ws[cch >> 3][(cch & 7) * 8] = vw[i];
    }
    __syncthreads();
    int nsi = si, nk0 = k0 + 64;
    if (nk0 >= segs.s[si].K) { nk0 = 0; nsi = si + 1; }
    const bool more = (nsi < segs.n);
    if (more) load_tiles(segs.s[nsi], bm, bn, N, nk0, tid, va, vw);
#pragma unroll
    for (int ks = 0; ks < 2; ++ks) {
      s8v a0 = *(const s8v*)&As[wr * 32 + lr][ks * 32 + lq * 8];
      s8v a1 = *(const s8v*)&As[wr * 32 + 16 + lr][ks * 32 + lq * 8];
#pragma unroll
      for (int j = 0; j < 4; ++j) {
        s8v bf = *(const s8v*)&Ws[wc * 64 + j * 16 + lr][ks * 32 + lq * 8];
        acc[0][j] = __builtin_amdgcn_mfma_f32_16x16x32_bf16(a0, bf, acc[0][j], 0, 0, 0);
        acc[1][j] = __builtin_amdgcn_mfma_f32_16x16x32_bf16(a1, bf, acc[1][j], 0, 0, 0);
      }
    }
    if (!more) break;
    si = nsi; k0 = nk0;
  }
#pragma unroll
  for (int j = 0; j < 4; ++j) {
    int col = bn + wc * 64 + j * 16 + lr;
    if (col < N) {
      float bias = (b0 ? b0[col] : 0.f) + (b1 ? b1[col] : 0.f);
#pragma unroll
      for (int m = 0; m < 2; ++m)
#pragma unroll
        for (int q = 0; q < 4; ++q) {
          int rr = bm + wr * 32 + m * 16 + lq * 4 + q;  // C/D: col=lane&15, row=(lane>>4)*4+q
          C[(size_t)rr * N + col] = acc[m][j][q] + bias;
        }
    }
  }
}

// ---------------- fused attn(read) + read einsums ----------------
__global__ __launch_bounds__(256) void k_fread(
    const float* __restrict__ x, const float* __restrict__ c,
    const float* __restrict__ h_dec,
    const float* __restrict__ raW, const float* __restrict__ rab,
    ushort_t* __restrict__ rH, ushort_t* __restrict__ rL) {
  int b = blockIdx.x;
  __shared__ float a_sh[5];
  __shared__ float fx[12][64], fy[12][64];
  __shared__ float srow[24];
  __shared__ float X[64][64];
  __shared__ float Xh[64][64];
  __shared__ float tmp[12][64], tmph[12][64];
  int tid = threadIdx.x, wv = tid >> 6, lane = tid & 63;
  const float* h = h_dec + (size_t)b * LL;
  // attention params: 5 dots of length 1024
  for (int o = wv; o < 5; o += 4) {
    float s = 0.f;
    const float* wrow = raW + (size_t)o * LL;
    for (int k = lane; k < LL; k += 64) s += h[k] * wrow[k];
#pragma unroll
    for (int d = 32; d; d >>= 1) s += __shfl_xor(s, d, 64);
    if (lane == 0) a_sh[o] = s + rab[o];
  }
  // canvas + input load
  for (int e = tid; e < 4096; e += 256) {
    float xv = x[(size_t)b * 4096 + e];
    float cv = c[(size_t)b * 4096 + e];
    X[e >> 6][e & 63] = xv;
    Xh[e >> 6][e & 63] = xv - sigf(cv);
  }
  __syncthreads();
  float gx = 32.5f * (a_sh[0] + 1.f);
  float gy = 32.5f * (a_sh[1] + 1.f);
  float i2v = 0.5f * expf(-a_sh[2]);
  float delta = (63.f / 11.f) * expf(a_sh[3]);
  float gam = expf(a_sh[4]);
  for (int e = tid; e < 768; e += 256) {
    int n = e >> 6, p = e & 63;
    float mu_x = gx + ((float)n - 5.5f) * delta;
    float mu_y = gy + ((float)n - 5.5f) * delta;
    float dx = (float)(p + 1) - mu_x;
    float dy = (float)(p + 1) - mu_y;
    fx[n][p] = expf(-i2v * dx * dx);
    fy[n][p] = expf(-i2v * dy * dy);
  }
  __syncthreads();
  if (tid < 24) {
    int n = tid % 12;
    float s = 0.f;
    if (tid < 12) { for (int p = 0; p < 64; ++p) s += fx[n][p]; }
    else          { for (int p = 0; p < 64; ++p) s += fy[n][p]; }
    srow[tid] = s + 6.4e-7f;   // sum(F + 1e-8) = sum(F) + 64e-8
  }
  __syncthreads();
  for (int e = tid; e < 768; e += 256) {
    int n = e >> 6, p = e & 63;
    fx[n][p] /= srow[n];
    fy[n][p] /= srow[12 + n];
  }
  __syncthreads();
  for (int e = tid; e < 768; e += 256) {
    int n = e >> 6, w2 = e & 63;
    float s = 0.f, sh = 0.f;
    for (int hh = 0; hh < 64; ++hh) {
      float f = fy[n][hh];
      s  = fmaf(f, X[hh][w2], s);
      sh = fmaf(f, Xh[hh][w2], sh);
    }
    tmp[n][w2] = s; tmph[n][w2] = sh;
  }
  __syncthreads();
  if (tid < 144) {
    int n = tid / 12, m = tid % 12;
    float s = 0.f, sh = 0.f;
    for (int w2 = 0; w2 < 64; ++w2) {
      float f = fx[m][w2];
      s  = fmaf(tmp[n][w2], f, s);
      sh = fmaf(tmph[n][w2], f, sh);
    }
    float v0 = gam * s, v1 = gam * sh;
    size_t i0 = (size_t)b * 320 + n * 12 + m;   // lda 320 (zero-padded to BK=64)
    size_t i1 = i0 + 144;
    ushort_t h0, l0, h1, l1;
    splitf(v0, h0, l0); splitf(v1, h1, l1);
    rH[i0] = h0; rL[i0] = l0;
    rH[i1] = h1; rL[i1] = l1;
  }
}

// ---------------- fused stats GEMM (f32) + z sample ----------------
__global__ __launch_bounds__(256) void k_stats_z(
    const float* __restrict__ h_enc,
    const float* __restrict__ zW, const float* __restrict__ zb,
    ushort_t* __restrict__ zH, ushort_t* __restrict__ zL,
    float* __restrict__ out_mu, float* __restrict__ out_sg, int t) {
  int b = blockIdx.x;
  __shared__ float h_sh[1024];
  __shared__ float st[256];
  int tid = threadIdx.x, wv = tid >> 6, lane = tid & 63;
  for (int e = tid; e < 1024; e += 256) h_sh[e] = h_enc[(size_t)b * 1024 + e];
  __syncthreads();
  for (int n = wv; n < 256; n += 4) {
    const float* wrow = zW + (size_t)n * 1024;
    float s = 0.f;
    for (int k = lane; k < 1024; k += 64) s += h_sh[k] * wrow[k];
#pragma unroll
    for (int d = 32; d; d >>= 1) s += __shfl_xor(s, d, 64);
    if (lane == 0) st[n] = s + zb[n];
  }
  __syncthreads();
  if (tid < 128) {
    float mu = st[tid];
    float sg = expf(st[128 + tid]);
    int i = b * 128 + tid;
    uint32_t kA, kB, o0, o1;
    threefry(0u, 42u, 0u, (uint32_t)t, kA, kB);
    threefry(kA, kB, 0u, (uint32_t)i, o0, o1);
    float zv = mu + sg * bits_to_normal(o0 ^ o1);
    ushort_t zh, zl;
    splitf(zv, zh, zl);
    zH[i] = zh; zL[i] = zl;
    out_mu[(size_t)b * 4096 + tid * 32 + t] = mu;
    out_sg[(size_t)b * 4096 + tid * 32 + t] = sg;
  }
}

// ---------------- fused write patch + attn(write) + canvas update ----------------
__global__ __launch_bounds__(256) void k_fwrite(
    float* __restrict__ c, const float* __restrict__ h_dec,
    const float* __restrict__ wW, const float* __restrict__ wb,
    const float* __restrict__ waW, const float* __restrict__ wab) {
  int b = blockIdx.x;
  __shared__ float h_sh[1024];
  __shared__ float wsm[12][12];
  __shared__ float a_sh[5];
  __shared__ float fx[12][64], fy[12][64];
  __shared__ float srow[24];
  __shared__ float tmp[12][64];
  int tid = threadIdx.x, wv = tid >> 6, lane = tid & 63;
  for (int e = tid; e < 1024; e += 256) h_sh[e] = h_dec[(size_t)b * 1024 + e];
  __syncthreads();
  // 144 write-patch dots + 5 attention dots
  for (int n = wv; n < 149; n += 4) {
    const float* wrow = (n < 144) ? (wW + (size_t)n * 1024) : (waW + (size_t)(n - 144) * 1024);
    float s = 0.f;
    for (int k = lane; k < 1024; k += 64) s += h_sh[k] * wrow[k];
#pragma unroll
    for (int d = 32; d; d >>= 1) s += __shfl_xor(s, d, 64);
    if (lane == 0) {
      if (n < 144) wsm[n / 12][n % 12] = s + wb[n];
      else         a_sh[n - 144] = s + wab[n - 144];
    }
  }
  __syncthreads();
  float gx = 32.5f * (a_sh[0] + 1.f);
  float gy = 32.5f * (a_sh[1] + 1.f);
  float i2v = 0.5f * expf(-a_sh[2]);
  float delta = (63.f / 11.f) * expf(a_sh[3]);
  float gam = expf(-a_sh[4]);
  for (int e = tid; e < 768; e += 256) {
    int n = e >> 6, p = e & 63;
    float mu_x = gx + ((float)n - 5.5f) * delta;
    float mu_y = gy + ((float)n - 5.5f) * delta;
    float dx = (float)(p + 1) - mu_x;
    float dy = (float)(p + 1) - mu_y;
    fx[n][p] = expf(-i2v * dx * dx);
    fy[n][p] = expf(-i2v * dy * dy);
  }
  __syncthreads();
  if (tid < 24) {
    int n = tid % 12;
    float s = 0.f;
    if (tid < 12) { for (int p = 0; p < 64; ++p) s += fx[n][p]; }
    else          { for (int p = 0; p < 64; ++p) s += fy[n][p]; }
    srow[tid] = s + 6.4e-7f;
  }
  __syncthreads();
  for (int e = tid; e < 768; e += 256) {
    int n = e >> 6, p = e & 63;
    fx[n][p] /= srow[n];
    fy[n][p] /= srow[12 + n];
  }
  __syncthreads();
  for (int e = tid; e < 768; e += 256) {
    int n = e >> 6, w2 = e & 63;
    float s = 0.f;
#pragma unroll
    for (int m = 0; m < 12; ++m) s = fmaf(wsm[n][m], fx[m][w2], s);
    tmp[n][w2] = s;
  }
  __syncthreads();
  for (int e = tid; e < 4096; e += 256) {
    int hh = e >> 6, w2 = e & 63;
    float s = 0.f;
#pragma unroll
    for (int n = 0; n < 12; ++n) s = fmaf(fy[n][hh], tmp[n][w2], s);
    c[(size_t)b * 4096 + e] += gam * s;
  }
}

// ---------------- LSTM gates (+ bf16 split of h) ----------------
__global__ __launch_bounds__(256) void k_lstm(const float* __restrict__ g,
                                              float* __restrict__ h, float* __restrict__ cst,
                                              ushort_t* __restrict__ hH,
                                              ushort_t* __restrict__ hL) {
  int i = blockIdx.x * 256 + threadIdx.x;
  int b = i >> 10, u = i & 1023;
  const float* gb = g + (size_t)b * 4096;
  float ig = gb[u], fg = gb[1024 + u], gg = gb[2048 + u], og = gb[3072 + u];
  float cv = sigf(fg) * cst[i] + sigf(ig) * tanhf(gg);
  cst[i] = cv;
  float hv = sigf(og) * tanhf(cv);
  h[i] = hv;
  ushort_t hh, hl;
  splitf(hv, hh, hl);
  hH[i] = hh; hL[i] = hl;
}

// ---------------- host launch ----------------
extern "C" void kernel_launch(void* const* d_in, const int* in_sizes, int n_in,
                              void* d_out, int out_size, void* d_ws, size_t ws_size,
                              hipStream_t stream) {
  const float* x       = (const float*)d_in[0];
  const float* enc_Wih = (const float*)d_in[1];
  const float* enc_Whh = (const float*)d_in[2];
  const float* enc_bih = (const float*)d_in[3];
  const float* enc_bhh = (const float*)d_in[4];
  const float* dec_Wih = (const float*)d_in[5];
  const float* dec_Whh = (const float*)d_in[6];
  const float* dec_bih = (const float*)d_in[7];
  const float* dec_bhh = (const float*)d_in[8];
  const float* zW  = (const float*)d_in[9];
  const float* zb  = (const float*)d_in[10];
  const float* wW  = (const float*)d_in[11];
  const float* wb  = (const float*)d_in[12];
  const float* raW = (const float*)d_in[13];
  const float* rab = (const float*)d_in[14];
  const float* waW = (const float*)d_in[15];
  const float* wab = (const float*)d_in[16];

  float* out = (float*)d_out;
  float* c      = out;
  float* out_mu = out + 2097152;
  float* out_sg = out + 4194304;

  // ---- workspace layout (bytes, 256-aligned) ----
  char* base = (char*)d_ws;
  size_t off = 0;
  auto alloc = [&](size_t bytes) -> char* {
    char* p = base + off;
    off = (off + bytes + 255) & ~(size_t)255;
    return p;
  };
  // zero-block (contiguous, first): states + recurrent splits + padded r
  float* h_enc = (float*)alloc(2097152);
  float* c_enc = (float*)alloc(2097152);
  float* h_dec = (float*)alloc(2097152);
  float* c_dec = (float*)alloc(2097152);
  ushort_t* hdH = (ushort_t*)alloc(1048576);
  ushort_t* hdL = (ushort_t*)alloc(1048576);
  ushort_t* heH = (ushort_t*)alloc(1048576);
  ushort_t* heL = (ushort_t*)alloc(1048576);
  ushort_t* rH  = (ushort_t*)alloc(327680);   // 512 x 320 (cols 288..319 stay zero)
  ushort_t* rL  = (ushort_t*)alloc(327680);
  size_t zero_bytes = off;
  // per-step buffers
  ushort_t* zH = (ushort_t*)alloc(131072);
  ushort_t* zL = (ushort_t*)alloc(131072);
  float* gbuf  = (float*)alloc(8388608);
  // weight splits (bf16 hi/lo)
  ushort_t* eWihH = (ushort_t*)alloc(10747904);
  ushort_t* eWihL = (ushort_t*)alloc(10747904);
  ushort_t* eWhhH = (ushort_t*)alloc(8388608);
  ushort_t* eWhhL = (ushort_t*)alloc(8388608);
  ushort_t* dWihH = (ushort_t*)alloc(1048576);
  ushort_t* dWihL = (ushort_t*)alloc(1048576);
  ushort_t* dWhhH = (ushort_t*)alloc(8388608);
  ushort_t* dWhhL = (ushort_t*)alloc(8388608);

  hipMemsetAsync(c, 0, (size_t)2097152 * sizeof(float), stream);
  hipMemsetAsync(base, 0, zero_bytes, stream);

  // split weights once per launch
  k_split<<<(5373952 + 255) / 256, 256, 0, stream>>>(enc_Wih, eWihH, eWihL, 5373952);
  k_split<<<(4194304 + 255) / 256, 256, 0, stream>>>(enc_Whh, eWhhH, eWhhL, 4194304);
  k_split<<<(524288 + 255) / 256, 256, 0, stream>>>(dec_Wih, dWihH, dWihL, 524288);
  k_split<<<(4194304 + 255) / 256, 256, 0, stream>>>(dec_Whh, dWhhH, dWhhL, 4194304);

  SegList encS, decS;
  encS.n = 9;
  encS.s[0] = {rH,  eWihH,       320,  320, 1312};
  encS.s[1] = {rL,  eWihH,       320,  320, 1312};
  encS.s[2] = {rH,  eWihL,       320,  320, 1312};
  encS.s[3] = {hdH, eWihH + 288, 1024, 1024, 1312};
  encS.s[4] = {hdL, eWihH + 288, 1024, 1024, 1312};
  encS.s[5] = {hdH, eWihL + 288, 1024, 1024, 1312};
  encS.s[6] = {heH, eWhhH,       1024, 1024, 1024};
  encS.s[7] = {heL, eWhhH,       1024, 1024, 1024};
  encS.s[8] = {heH, eWhhL,       1024, 1024, 1024};
  decS.n = 6;
  decS.s[0] = {zH,  dWihH, 128,  128, 128};
  decS.s[1] = {zL,  dWihH, 128,  128, 128};
  decS.s[2] = {zH,  dWihL, 128,  128, 128};
  decS.s[3] = {hdH, dWhhH, 1024, 1024, 1024};
  decS.s[4] = {hdL, dWhhH, 1024, 1024, 1024};
  decS.s[5] = {hdH, dWhhL, 1024, 1024, 1024};

  for (int t = 0; t < TT; ++t) {
    k_fread<<<512, 256, 0, stream>>>(x, c, h_dec, raW, rab, rH, rL);
    mfma_gemm<<<dim3(32, 8), 256, 0, stream>>>(gbuf, 4096, encS, enc_bih, enc_bhh);
    k_lstm<<<2048, 256, 0, stream>>>(gbuf, h_enc, c_enc, heH, heL);
    k_stats_z<<<512, 256, 0, stream>>>(h_enc, zW, zb, zH, zL, out_mu, out_sg, t);
    mfma_gemm<<<dim3(32, 8), 256, 0, stream>>>(gbuf, 4096, decS, dec_bih, dec_bhh);
    k_lstm<<<2048, 256, 0, stream>>>(gbuf, h_dec, c_dec, hdH, hdL);
    k_fwrite<<<512, 256, 0, stream>>>(c, h_dec, wW, wb, waW, wab);
  }
}

// Round 9
// 13232.013 us; speedup vs baseline: 1.7016x; 1.7016x over previous
//
#include <hip/hip_runtime.h>
#include <cstdint>
#include <cstddef>

#define BB 512
#define TT 32
#define LL 1024
#define ZZ 128

typedef unsigned short ushort_t;
typedef __attribute__((ext_vector_type(8))) short s8v;    // 8 bf16 (4 VGPRs)
typedef __attribute__((ext_vector_type(4))) float f32x4;

// ---------------- math helpers ----------------
__device__ __forceinline__ float sigf(float x) { return 1.0f / (1.0f + expf(-x)); }

__device__ __forceinline__ ushort_t f2bf(float f) {
  uint32_t u = __float_as_uint(f);
  uint32_t r = (u + 0x7FFFu + ((u >> 16) & 1u)) >> 16;   // RNE
  return (ushort_t)r;
}
__device__ __forceinline__ float bf2f(ushort_t h) {
  return __uint_as_float(((uint32_t)h) << 16);
}
__device__ __forceinline__ void splitf(float v, ushort_t& hi, ushort_t& lo) {
  hi = f2bf(v);
  lo = f2bf(v - bf2f(hi));
}

// XLA ErfInv32 (Giles polynomial)
__device__ __forceinline__ float jax_erfinv(float x) {
  float w = -log1pf(-x * x);
  float p;
  if (w < 5.0f) {
    w = w - 2.5f;
    p = 2.81022636e-08f;
    p = fmaf(p, w, 3.43273939e-07f);
    p = fmaf(p, w, -3.5233877e-06f);
    p = fmaf(p, w, -4.39150654e-06f);
    p = fmaf(p, w, 0.00021858087f);
    p = fmaf(p, w, -0.00125372503f);
    p = fmaf(p, w, -0.00417768164f);
    p = fmaf(p, w, 0.246640727f);
    p = fmaf(p, w, 1.50140941f);
  } else {
    w = sqrtf(w) - 3.0f;
    p = -0.000200214257f;
    p = fmaf(p, w, 0.000100950558f);
    p = fmaf(p, w, 0.00134934322f);
    p = fmaf(p, w, -0.00367342844f);
    p = fmaf(p, w, 0.00573950773f);
    p = fmaf(p, w, -0.0076224613f);
    p = fmaf(p, w, 0.00943887047f);
    p = fmaf(p, w, 1.00167406f);
    p = fmaf(p, w, 2.83297682f);
  }
  return p * x;
}

// Threefry-2x32, 20 rounds (JAX schedule)
__device__ __forceinline__ void threefry(uint32_t k0, uint32_t k1,
                                         uint32_t x0, uint32_t x1,
                                         uint32_t& o0, uint32_t& o1) {
  uint32_t ks0 = k0, ks1 = k1, ks2 = k0 ^ k1 ^ 0x1BD11BDAu;
  x0 += ks0; x1 += ks1;
#define TF_ROT(x, d) (((x) << (d)) | ((x) >> (32 - (d))))
#define TF_RND(r) { x0 += x1; x1 = TF_ROT(x1, r); x1 ^= x0; }
  TF_RND(13) TF_RND(15) TF_RND(26) TF_RND(6)
  x0 += ks1; x1 += ks2 + 1u;
  TF_RND(17) TF_RND(29) TF_RND(16) TF_RND(24)
  x0 += ks2; x1 += ks0 + 2u;
  TF_RND(13) TF_RND(15) TF_RND(26) TF_RND(6)
  x0 += ks0; x1 += ks1 + 3u;
  TF_RND(17) TF_RND(29) TF_RND(16) TF_RND(24)
  x0 += ks1; x1 += ks2 + 4u;
  TF_RND(13) TF_RND(15) TF_RND(26) TF_RND(6)
  x0 += ks2; x1 += ks0 + 5u;
#undef TF_RND
#undef TF_ROT
  o0 = x0; o1 = x1;
}

__device__ __forceinline__ float bits_to_normal(uint32_t bits) {
  uint32_t fb = (bits >> 9) | 0x3f800000u;
  float f = __uint_as_float(fb) - 1.0f;
  const float lo = -0.99999994f;
  float u = fmaxf(lo, f * 2.0f + lo);
  return 1.41421356237f * jax_erfinv(u);
}

// ---------------- weight split: f32 -> bf16 hi/lo ----------------
__global__ __launch_bounds__(256) void k_split(const float* __restrict__ src,
                                               ushort_t* __restrict__ hi,
                                               ushort_t* __restrict__ lo, int n) {
  int i = blockIdx.x * 256 + threadIdx.x;
  if (i >= n) return;
  ushort_t h, l;
  splitf(src[i], h, l);
  hi[i] = h; lo[i] = l;
}

// ---------------- MFMA GEMM: C[512][N] = sum_seg A_s @ W_s^T + b0 + b1 ----------------
// Tile 64(M) x 128(N), BK=64; 4 waves as 2x2, each wave 32x64 out (2x4 16x16 frags).
struct Seg { const ushort_t* A; const ushort_t* W; int K; int lda; int ldw; };
struct SegList { Seg s[9]; int n; };

__device__ __forceinline__ void load_tiles(const Seg& sg, int bm, int bn, int N, int k0,
                                           int tid, s8v va[2], s8v vw[4]) {
#pragma unroll
  for (int i = 0; i < 2; ++i) {
    int cch = tid + 256 * i;
    int row = cch >> 3, col = cch & 7;
    va[i] = *(const s8v*)(sg.A + (size_t)(bm + row) * sg.lda + k0 + col * 8);
  }
#pragma unroll
  for (int i = 0; i < 4; ++i) {
    int cch = tid + 256 * i;
    int row = cch >> 3, col = cch & 7;
    int n = bn + row;
    if (n < N) vw[i] = *(const s8v*)(sg.W + (size_t)n * sg.ldw + k0 + col * 8);
    else       vw[i] = (s8v)(short)0;
  }
}

__global__ __launch_bounds__(256) void mfma_gemm(
    float* __restrict__ C, int N, SegList segs,
    const float* __restrict__ b0, const float* __restrict__ b1) {
  __shared__ __align__(16) ushort_t As[64][72];    // pad 8 elems: stride 36 dwords
  __shared__ __align__(16) ushort_t Ws[128][72];
  const int bm = blockIdx.y * 64, bn = blockIdx.x * 128;
  const int tid = threadIdx.x;
  const int w = tid >> 6, lane = tid & 63;
  const int wr = w >> 1, wc = w & 1;               // wave grid 2(M) x 2(N)
  const int lr = lane & 15, lq = lane >> 4;
  f32x4 acc[2][4] = {};

  int si = 0, k0 = 0;
  s8v va[2], vw[4];
  load_tiles(segs.s[0], bm, bn, N, 0, tid, va, vw);
  while (1) {
    __syncthreads();
#pragma unroll
    for (int i = 0; i < 2; ++i) {
      int cch = tid + 256 * i;
      *(s8v*)&As[cch >> 3][(cch & 7) * 8] = va[i];
    }
#pragma unroll
    for (int i = 0; i < 4; ++i) {
      int cch = tid + 256 * i;
      *(s8v*)&Ws[cch >> 3][(cch & 7) * 8] = vw[i];
    }
    __syncthreads();
    int nsi = si, nk0 = k0 + 64;
    if (nk0 >= segs.s[si].K) { nk0 = 0; nsi = si + 1; }
    const bool more = (nsi < segs.n);
    if (more) load_tiles(segs.s[nsi], bm, bn, N, nk0, tid, va, vw);
#pragma unroll
    for (int ks = 0; ks < 2; ++ks) {
      s8v a0 = *(const s8v*)&As[wr * 32 + lr][ks * 32 + lq * 8];
      s8v a1 = *(const s8v*)&As[wr * 32 + 16 + lr][ks * 32 + lq * 8];
#pragma unroll
      for (int j = 0; j < 4; ++j) {
        s8v bf = *(const s8v*)&Ws[wc * 64 + j * 16 + lr][ks * 32 + lq * 8];
        acc[0][j] = __builtin_amdgcn_mfma_f32_16x16x32_bf16(a0, bf, acc[0][j], 0, 0, 0);
        acc[1][j] = __builtin_amdgcn_mfma_f32_16x16x32_bf16(a1, bf, acc[1][j], 0, 0, 0);
      }
    }
    if (!more) break;
    si = nsi; k0 = nk0;
  }
#pragma unroll
  for (int j = 0; j < 4; ++j) {
    int col = bn + wc * 64 + j * 16 + lr;
    if (col < N) {
      float bias = (b0 ? b0[col] : 0.f) + (b1 ? b1[col] : 0.f);
#pragma unroll
      for (int m = 0; m < 2; ++m)
#pragma unroll
        for (int q = 0; q < 4; ++q) {
          int rr = bm + wr * 32 + m * 16 + lq * 4 + q;  // C/D: col=lane&15, row=(lane>>4)*4+q
          C[(size_t)rr * N + col] = acc[m][j][q] + bias;
        }
    }
  }
}

// ---------------- fused attn(read) + read einsums ----------------
__global__ __launch_bounds__(256) void k_fread(
    const float* __restrict__ x, const float* __restrict__ c,
    const float* __restrict__ h_dec,
    const float* __restrict__ raW, const float* __restrict__ rab,
    ushort_t* __restrict__ rH, ushort_t* __restrict__ rL) {
  int b = blockIdx.x;
  __shared__ float a_sh[5];
  __shared__ float fx[12][64], fy[12][64];
  __shared__ float srow[24];
  __shared__ float X[64][64];
  __shared__ float Xh[64][64];
  __shared__ float tmp[12][64], tmph[12][64];
  int tid = threadIdx.x, wv = tid >> 6, lane = tid & 63;
  const float* h = h_dec + (size_t)b * LL;
  // attention params: 5 dots of length 1024
  for (int o = wv; o < 5; o += 4) {
    float s = 0.f;
    const float* wrow = raW + (size_t)o * LL;
    for (int k = lane; k < LL; k += 64) s += h[k] * wrow[k];
#pragma unroll
    for (int d = 32; d; d >>= 1) s += __shfl_xor(s, d, 64);
    if (lane == 0) a_sh[o] = s + rab[o];
  }
  // canvas + input load
  for (int e = tid; e < 4096; e += 256) {
    float xv = x[(size_t)b * 4096 + e];
    float cv = c[(size_t)b * 4096 + e];
    X[e >> 6][e & 63] = xv;
    Xh[e >> 6][e & 63] = xv - sigf(cv);
  }
  __syncthreads();
  float gx = 32.5f * (a_sh[0] + 1.f);
  float gy = 32.5f * (a_sh[1] + 1.f);
  float i2v = 0.5f * expf(-a_sh[2]);
  float delta = (63.f / 11.f) * expf(a_sh[3]);
  float gam = expf(a_sh[4]);
  for (int e = tid; e < 768; e += 256) {
    int n = e >> 6, p = e & 63;
    float mu_x = gx + ((float)n - 5.5f) * delta;
    float mu_y = gy + ((float)n - 5.5f) * delta;
    float dx = (float)(p + 1) - mu_x;
    float dy = (float)(p + 1) - mu_y;
    fx[n][p] = expf(-i2v * dx * dx);
    fy[n][p] = expf(-i2v * dy * dy);
  }
  __syncthreads();
  if (tid < 24) {
    int n = tid % 12;
    float s = 0.f;
    if (tid < 12) { for (int p = 0; p < 64; ++p) s += fx[n][p]; }
    else          { for (int p = 0; p < 64; ++p) s += fy[n][p]; }
    srow[tid] = s + 6.4e-7f;   // sum(F + 1e-8) = sum(F) + 64e-8
  }
  __syncthreads();
  for (int e = tid; e < 768; e += 256) {
    int n = e >> 6, p = e & 63;
    fx[n][p] /= srow[n];
    fy[n][p] /= srow[12 + n];
  }
  __syncthreads();
  for (int e = tid; e < 768; e += 256) {
    int n = e >> 6, w2 = e & 63;
    float s = 0.f, sh = 0.f;
    for (int hh = 0; hh < 64; ++hh) {
      float f = fy[n][hh];
      s  = fmaf(f, X[hh][w2], s);
      sh = fmaf(f, Xh[hh][w2], sh);
    }
    tmp[n][w2] = s; tmph[n][w2] = sh;
  }
  __syncthreads();
  if (tid < 144) {
    int n = tid / 12, m = tid % 12;
    float s = 0.f, sh = 0.f;
    for (int w2 = 0; w2 < 64; ++w2) {
      float f = fx[m][w2];
      s  = fmaf(tmp[n][w2], f, s);
      sh = fmaf(tmph[n][w2], f, sh);
    }
    float v0 = gam * s, v1 = gam * sh;
    size_t i0 = (size_t)b * 320 + n * 12 + m;   // lda 320 (zero-padded to BK=64)
    size_t i1 = i0 + 144;
    ushort_t h0, l0, h1, l1;
    splitf(v0, h0, l0); splitf(v1, h1, l1);
    rH[i0] = h0; rL[i0] = l0;
    rH[i1] = h1; rL[i1] = l1;
  }
}

// ---------------- z = mu + sig*eps (inline threefry RNG) ----------------
__global__ __launch_bounds__(256) void k_z(const float* __restrict__ stats,
                                           ushort_t* __restrict__ zH,
                                           ushort_t* __restrict__ zL,
                                           float* __restrict__ out_mu,
                                           float* __restrict__ out_sg, int t) {
  int i = blockIdx.x * 256 + threadIdx.x;  // < 65536
  int b = i >> 7, zi = i & 127;
  uint32_t kA, kB, o0, o1;
  threefry(0u, 42u, 0u, (uint32_t)t, kA, kB);          // split(key(42),32)[t]
  threefry(kA, kB, 0u, (uint32_t)i, o0, o1);           // random_bits
  float ep = bits_to_normal(o0 ^ o1);
  float mu = stats[(size_t)b * 256 + zi];
  float sg = expf(stats[(size_t)b * 256 + 128 + zi]);
  float zv = mu + sg * ep;
  ushort_t zh, zl;
  splitf(zv, zh, zl);
  zH[i] = zh; zL[i] = zl;
  out_mu[(size_t)b * 4096 + zi * 32 + t] = mu;
  out_sg[(size_t)b * 4096 + zi * 32 + t] = sg;
}

// ---------------- fused write patch + attn(write) + canvas update ----------------
__global__ __launch_bounds__(256) void k_fwrite(
    float* __restrict__ c, const float* __restrict__ h_dec,
    const float* __restrict__ wW, const float* __restrict__ wb,
    const float* __restrict__ waW, const float* __restrict__ wab) {
  int b = blockIdx.x;
  __shared__ float h_sh[1024];
  __shared__ float wsm[12][12];
  __shared__ float a_sh[5];
  __shared__ float fx[12][64], fy[12][64];
  __shared__ float srow[24];
  __shared__ float tmp[12][64];
  int tid = threadIdx.x, wv = tid >> 6, lane = tid & 63;
  for (int e = tid; e < 1024; e += 256) h_sh[e] = h_dec[(size_t)b * 1024 + e];
  __syncthreads();
  // 144 write-patch dots + 5 attention dots
  for (int n = wv; n < 149; n += 4) {
    const float* wrow = (n < 144) ? (wW + (size_t)n * 1024) : (waW + (size_t)(n - 144) * 1024);
    float s = 0.f;
    for (int k = lane; k < 1024; k += 64) s += h_sh[k] * wrow[k];
#pragma unroll
    for (int d = 32; d; d >>= 1) s += __shfl_xor(s, d, 64);
    if (lane == 0) {
      if (n < 144) wsm[n / 12][n % 12] = s + wb[n];
      else         a_sh[n - 144] = s + wab[n - 144];
    }
  }
  __syncthreads();
  float gx = 32.5f * (a_sh[0] + 1.f);
  float gy = 32.5f * (a_sh[1] + 1.f);
  float i2v = 0.5f * expf(-a_sh[2]);
  float delta = (63.f / 11.f) * expf(a_sh[3]);
  float gam = expf(-a_sh[4]);
  for (int e = tid; e < 768; e += 256) {
    int n = e >> 6, p = e & 63;
    float mu_x = gx + ((float)n - 5.5f) * delta;
    float mu_y = gy + ((float)n - 5.5f) * delta;
    float dx = (float)(p + 1) - mu_x;
    float dy = (float)(p + 1) - mu_y;
    fx[n][p] = expf(-i2v * dx * dx);
    fy[n][p] = expf(-i2v * dy * dy);
  }
  __syncthreads();
  if (tid < 24) {
    int n = tid % 12;
    float s = 0.f;
    if (tid < 12) { for (int p = 0; p < 64; ++p) s += fx[n][p]; }
    else          { for (int p = 0; p < 64; ++p) s += fy[n][p]; }
    srow[tid] = s + 6.4e-7f;
  }
  __syncthreads();
  for (int e = tid; e < 768; e += 256) {
    int n = e >> 6, p = e & 63;
    fx[n][p] /= srow[n];
    fy[n][p] /= srow[12 + n];
  }
  __syncthreads();
  for (int e = tid; e < 768; e += 256) {
    int n = e >> 6, w2 = e & 63;
    float s = 0.f;
#pragma unroll
    for (int m = 0; m < 12; ++m) s = fmaf(wsm[n][m], fx[m][w2], s);
    tmp[n][w2] = s;
  }
  __syncthreads();
  for (int e = tid; e < 4096; e += 256) {
    int hh = e >> 6, w2 = e & 63;
    float s = 0.f;
#pragma unroll
    for (int n = 0; n < 12; ++n) s = fmaf(fy[n][hh], tmp[n][w2], s);
    c[(size_t)b * 4096 + e] += gam * s;
  }
}

// ---------------- LSTM gates (+ bf16 split of h) ----------------
__global__ __launch_bounds__(256) void k_lstm(const float* __restrict__ g,
                                              float* __restrict__ h, float* __restrict__ cst,
                                              ushort_t* __restrict__ hH,
                                              ushort_t* __restrict__ hL) {
  int i = blockIdx.x * 256 + threadIdx.x;
  int b = i >> 10, u = i & 1023;
  const float* gb = g + (size_t)b * 4096;
  float ig = gb[u], fg = gb[1024 + u], gg = gb[2048 + u], og = gb[3072 + u];
  float cv = sigf(fg) * cst[i] + sigf(ig) * tanhf(gg);
  cst[i] = cv;
  float hv = sigf(og) * tanhf(cv);
  h[i] = hv;
  ushort_t hh, hl;
  splitf(hv, hh, hl);
  hH[i] = hh; hL[i] = hl;
}

// ---------------- host launch ----------------
extern "C" void kernel_launch(void* const* d_in, const int* in_sizes, int n_in,
                              void* d_out, int out_size, void* d_ws, size_t ws_size,
                              hipStream_t stream) {
  const float* x       = (const float*)d_in[0];
  const float* enc_Wih = (const float*)d_in[1];
  const float* enc_Whh = (const float*)d_in[2];
  const float* enc_bih = (const float*)d_in[3];
  const float* enc_bhh = (const float*)d_in[4];
  const float* dec_Wih = (const float*)d_in[5];
  const float* dec_Whh = (const float*)d_in[6];
  const float* dec_bih = (const float*)d_in[7];
  const float* dec_bhh = (const float*)d_in[8];
  const float* zW  = (const float*)d_in[9];
  const float* zb  = (const float*)d_in[10];
  const float* wW  = (const float*)d_in[11];
  const float* wb  = (const float*)d_in[12];
  const float* raW = (const float*)d_in[13];
  const float* rab = (const float*)d_in[14];
  const float* waW = (const float*)d_in[15];
  const float* wab = (const float*)d_in[16];

  float* out = (float*)d_out;
  float* c      = out;
  float* out_mu = out + 2097152;
  float* out_sg = out + 4194304;

  // ---- workspace layout (bytes, 256-aligned) ----
  char* base = (char*)d_ws;
  size_t off = 0;
  auto alloc = [&](size_t bytes) -> char* {
    char* p = base + off;
    off = (off + bytes + 255) & ~(size_t)255;
    return p;
  };
  // zero-block (contiguous, first): states + recurrent splits + padded r
  float* h_enc = (float*)alloc(2097152);
  float* c_enc = (float*)alloc(2097152);
  float* h_dec = (float*)alloc(2097152);
  float* c_dec = (float*)alloc(2097152);
  ushort_t* hdH = (ushort_t*)alloc(1048576);
  ushort_t* hdL = (ushort_t*)alloc(1048576);
  ushort_t* heH = (ushort_t*)alloc(1048576);
  ushort_t* heL = (ushort_t*)alloc(1048576);
  ushort_t* rH  = (ushort_t*)alloc(327680);   // 512 x 320 (cols 288..319 stay zero)
  ushort_t* rL  = (ushort_t*)alloc(327680);
  size_t zero_bytes = off;
  // per-step buffers
  ushort_t* zH = (ushort_t*)alloc(131072);
  ushort_t* zL = (ushort_t*)alloc(131072);
  float* gbuf  = (float*)alloc(8388608);
  float* stats = (float*)alloc(524288);
  // weight splits (bf16 hi/lo)
  ushort_t* eWihH = (ushort_t*)alloc(10747904);
  ushort_t* eWihL = (ushort_t*)alloc(10747904);
  ushort_t* eWhhH = (ushort_t*)alloc(8388608);
  ushort_t* eWhhL = (ushort_t*)alloc(8388608);
  ushort_t* dWihH = (ushort_t*)alloc(1048576);
  ushort_t* dWihL = (ushort_t*)alloc(1048576);
  ushort_t* dWhhH = (ushort_t*)alloc(8388608);
  ushort_t* dWhhL = (ushort_t*)alloc(8388608);
  ushort_t* zWH   = (ushort_t*)alloc(524288);
  ushort_t* zWL   = (ushort_t*)alloc(524288);

  hipMemsetAsync(c, 0, (size_t)2097152 * sizeof(float), stream);
  hipMemsetAsync(base, 0, zero_bytes, stream);

  // split weights once per launch
  k_split<<<(5373952 + 255) / 256, 256, 0, stream>>>(enc_Wih, eWihH, eWihL, 5373952);
  k_split<<<(4194304 + 255) / 256, 256, 0, stream>>>(enc_Whh, eWhhH, eWhhL, 4194304);
  k_split<<<(524288 + 255) / 256, 256, 0, stream>>>(dec_Wih, dWihH, dWihL, 524288);
  k_split<<<(4194304 + 255) / 256, 256, 0, stream>>>(dec_Whh, dWhhH, dWhhL, 4194304);
  k_split<<<(262144 + 255) / 256, 256, 0, stream>>>(zW, zWH, zWL, 262144);

  SegList encS, decS, staS;
  encS.n = 9;
  encS.s[0] = {rH,  eWihH,       320,  320, 1312};
  encS.s[1] = {rL,  eWihH,       320,  320, 1312};
  encS.s[2] = {rH,  eWihL,       320,  320, 1312};
  encS.s[3] = {hdH, eWihH + 288, 1024, 1024, 1312};
  encS.s[4] = {hdL, eWihH + 288, 1024, 1024, 1312};
  encS.s[5] = {hdH, eWihL + 288, 1024, 1024, 1312};
  encS.s[6] = {heH, eWhhH,       1024, 1024, 1024};
  encS.s[7] = {heL, eWhhH,       1024, 1024, 1024};
  encS.s[8] = {heH, eWhhL,       1024, 1024, 1024};
  decS.n = 6;
  decS.s[0] = {zH,  dWihH, 128,  128, 128};
  decS.s[1] = {zL,  dWihH, 128,  128, 128};
  decS.s[2] = {zH,  dWihL, 128,  128, 128};
  decS.s[3] = {hdH, dWhhH, 1024, 1024, 1024};
  decS.s[4] = {hdL, dWhhH, 1024, 1024, 1024};
  decS.s[5] = {hdH, dWhhL, 1024, 1024, 1024};
  staS.n = 3;
  staS.s[0] = {heH, zWH, 1024, 1024, 1024};
  staS.s[1] = {heL, zWH, 1024, 1024, 1024};
  staS.s[2] = {heH, zWL, 1024, 1024, 1024};

  for (int t = 0; t < TT; ++t) {
    k_fread<<<512, 256, 0, stream>>>(x, c, h_dec, raW, rab, rH, rL);
    mfma_gemm<<<dim3(32, 8), 256, 0, stream>>>(gbuf, 4096, encS, enc_bih, enc_bhh);
    k_lstm<<<2048, 256, 0, stream>>>(gbuf, h_enc, c_enc, heH, heL);
    mfma_gemm<<<dim3(2, 8), 256, 0, stream>>>(stats, 256, staS, zb, nullptr);
    k_z<<<256, 256, 0, stream>>>(stats, zH, zL, out_mu, out_sg, t);
    mfma_gemm<<<dim3(32, 8), 256, 0, stream>>>(gbuf, 4096, decS, dec_bih, dec_bhh);
    k_lstm<<<2048, 256, 0, stream>>>(gbuf, h_dec, c_dec, hdH, hdL);
    k_fwrite<<<512, 256, 0, stream>>>(c, h_dec, wW, wb, waW, wab);
  }
}

// Round 10
// 8321.455 us; speedup vs baseline: 2.7058x; 1.5901x over previous
//
#include <hip/hip_runtime.h>
#include <cstdint>
#include <cstddef>

#define BB 512
#define TT 32
#define LL 1024
#define ZZ 128

typedef unsigned short ushort_t;
typedef __attribute__((ext_vector_type(8))) short s8v;    // 8 bf16 (4 VGPRs)
typedef __attribute__((ext_vector_type(4))) float f32x4;

// ---------------- math helpers ----------------
__device__ __forceinline__ float sigf(float x) { return 1.0f / (1.0f + expf(-x)); }

__device__ __forceinline__ ushort_t f2bf(float f) {
  uint32_t u = __float_as_uint(f);
  uint32_t r = (u + 0x7FFFu + ((u >> 16) & 1u)) >> 16;   // RNE
  return (ushort_t)r;
}
__device__ __forceinline__ float bf2f(ushort_t h) {
  return __uint_as_float(((uint32_t)h) << 16);
}
__device__ __forceinline__ void splitf(float v, ushort_t& hi, ushort_t& lo) {
  hi = f2bf(v);
  lo = f2bf(v - bf2f(hi));
}

// XLA ErfInv32 (Giles polynomial)
__device__ __forceinline__ float jax_erfinv(float x) {
  float w = -log1pf(-x * x);
  float p;
  if (w < 5.0f) {
    w = w - 2.5f;
    p = 2.81022636e-08f;
    p = fmaf(p, w, 3.43273939e-07f);
    p = fmaf(p, w, -3.5233877e-06f);
    p = fmaf(p, w, -4.39150654e-06f);
    p = fmaf(p, w, 0.00021858087f);
    p = fmaf(p, w, -0.00125372503f);
    p = fmaf(p, w, -0.00417768164f);
    p = fmaf(p, w, 0.246640727f);
    p = fmaf(p, w, 1.50140941f);
  } else {
    w = sqrtf(w) - 3.0f;
    p = -0.000200214257f;
    p = fmaf(p, w, 0.000100950558f);
    p = fmaf(p, w, 0.00134934322f);
    p = fmaf(p, w, -0.00367342844f);
    p = fmaf(p, w, 0.00573950773f);
    p = fmaf(p, w, -0.0076224613f);
    p = fmaf(p, w, 0.00943887047f);
    p = fmaf(p, w, 1.00167406f);
    p = fmaf(p, w, 2.83297682f);
  }
  return p * x;
}

// Threefry-2x32, 20 rounds (JAX schedule)
__device__ __forceinline__ void threefry(uint32_t k0, uint32_t k1,
                                         uint32_t x0, uint32_t x1,
                                         uint32_t& o0, uint32_t& o1) {
  uint32_t ks0 = k0, ks1 = k1, ks2 = k0 ^ k1 ^ 0x1BD11BDAu;
  x0 += ks0; x1 += ks1;
#define TF_ROT(x, d) (((x) << (d)) | ((x) >> (32 - (d))))
#define TF_RND(r) { x0 += x1; x1 = TF_ROT(x1, r); x1 ^= x0; }
  TF_RND(13) TF_RND(15) TF_RND(26) TF_RND(6)
  x0 += ks1; x1 += ks2 + 1u;
  TF_RND(17) TF_RND(29) TF_RND(16) TF_RND(24)
  x0 += ks2; x1 += ks0 + 2u;
  TF_RND(13) TF_RND(15) TF_RND(26) TF_RND(6)
  x0 += ks0; x1 += ks1 + 3u;
  TF_RND(17) TF_RND(29) TF_RND(16) TF_RND(24)
  x0 += ks1; x1 += ks2 + 4u;
  TF_RND(13) TF_RND(15) TF_RND(26) TF_RND(6)
  x0 += ks2; x1 += ks0 + 5u;
#undef TF_RND
#undef TF_ROT
  o0 = x0; o1 = x1;
}

__device__ __forceinline__ float bits_to_normal(uint32_t bits) {
  uint32_t fb = (bits >> 9) | 0x3f800000u;
  float f = __uint_as_float(fb) - 1.0f;
  const float lo = -0.99999994f;
  float u = fmaxf(lo, f * 2.0f + lo);
  return 1.41421356237f * jax_erfinv(u);
}

// ---------------- weight split: f32 -> bf16 hi/lo ----------------
__global__ __launch_bounds__(256) void k_split(const float* __restrict__ src,
                                               ushort_t* __restrict__ hi,
                                               ushort_t* __restrict__ lo, int n) {
  int i = blockIdx.x * 256 + threadIdx.x;
  if (i >= n) return;
  ushort_t h, l;
  splitf(src[i], h, l);
  hi[i] = h; lo[i] = l;
}

// combined bias for [wW | waW] GEMM
__global__ void k_catbias(const float* __restrict__ wb, const float* __restrict__ wab,
                          float* __restrict__ cb) {
  int i = threadIdx.x;   // 160 threads
  cb[i] = (i < 144) ? wb[i] : (i < 149 ? wab[i - 144] : 0.f);
}

// ---------------- MFMA GEMM: C[512][N] = sum_seg A_s @ W_s^T + b0 + b1 ----------------
// Tile 64(M) x 128(N), BK=64; 4 waves as 2x2, each wave 32x64 out (2x4 16x16 frags).
struct Seg { const ushort_t* A; const ushort_t* W; int K; int lda; int ldw; };
struct SegList { Seg s[9]; int n; };

__device__ __forceinline__ void load_tiles(const Seg& sg, int bm, int bn, int N, int k0,
                                           int tid, s8v va[2], s8v vw[4]) {
#pragma unroll
  for (int i = 0; i < 2; ++i) {
    int cch = tid + 256 * i;
    int row = cch >> 3, col = cch & 7;
    va[i] = *(const s8v*)(sg.A + (size_t)(bm + row) * sg.lda + k0 + col * 8);
  }
#pragma unroll
  for (int i = 0; i < 4; ++i) {
    int cch = tid + 256 * i;
    int row = cch >> 3, col = cch & 7;
    int n = bn + row;
    if (n < N) vw[i] = *(const s8v*)(sg.W + (size_t)n * sg.ldw + k0 + col * 8);
    else       vw[i] = (s8v)(short)0;
  }
}

__global__ __launch_bounds__(256) void mfma_gemm(
    float* __restrict__ C, int N, SegList segs,
    const float* __restrict__ b0, const float* __restrict__ b1) {
  __shared__ __align__(16) ushort_t As[64][72];    // pad 8 elems: stride 36 dwords
  __shared__ __align__(16) ushort_t Ws[128][72];
  const int bm = blockIdx.y * 64, bn = blockIdx.x * 128;
  const int tid = threadIdx.x;
  const int w = tid >> 6, lane = tid & 63;
  const int wr = w >> 1, wc = w & 1;               // wave grid 2(M) x 2(N)
  const int lr = lane & 15, lq = lane >> 4;
  f32x4 acc[2][4] = {};

  int si = 0, k0 = 0;
  s8v va[2], vw[4];
  load_tiles(segs.s[0], bm, bn, N, 0, tid, va, vw);
  while (1) {
    __syncthreads();
#pragma unroll
    for (int i = 0; i < 2; ++i) {
      int cch = tid + 256 * i;
      *(s8v*)&As[cch >> 3][(cch & 7) * 8] = va[i];
    }
#pragma unroll
    for (int i = 0; i < 4; ++i) {
      int cch = tid + 256 * i;
      *(s8v*)&Ws[cch >> 3][(cch & 7) * 8] = vw[i];
    }
    __syncthreads();
    int nsi = si, nk0 = k0 + 64;
    if (nk0 >= segs.s[si].K) { nk0 = 0; nsi = si + 1; }
    const bool more = (nsi < segs.n);
    if (more) load_tiles(segs.s[nsi], bm, bn, N, nk0, tid, va, vw);
#pragma unroll
    for (int ks = 0; ks < 2; ++ks) {
      s8v a0 = *(const s8v*)&As[wr * 32 + lr][ks * 32 + lq * 8];
      s8v a1 = *(const s8v*)&As[wr * 32 + 16 + lr][ks * 32 + lq * 8];
#pragma unroll
      for (int j = 0; j < 4; ++j) {
        s8v bf = *(const s8v*)&Ws[wc * 64 + j * 16 + lr][ks * 32 + lq * 8];
        acc[0][j] = __builtin_amdgcn_mfma_f32_16x16x32_bf16(a0, bf, acc[0][j], 0, 0, 0);
        acc[1][j] = __builtin_amdgcn_mfma_f32_16x16x32_bf16(a1, bf, acc[1][j], 0, 0, 0);
      }
    }
    if (!more) break;
    si = nsi; k0 = nk0;
  }
#pragma unroll
  for (int j = 0; j < 4; ++j) {
    int col = bn + wc * 64 + j * 16 + lr;
    if (col < N) {
      float bias = (b0 ? b0[col] : 0.f) + (b1 ? b1[col] : 0.f);
#pragma unroll
      for (int m = 0; m < 2; ++m)
#pragma unroll
        for (int q = 0; q < 4; ++q) {
          int rr = bm + wr * 32 + m * 16 + lq * 4 + q;  // C/D: col=lane&15, row=(lane>>4)*4+q
          C[(size_t)rr * N + col] = acc[m][j][q] + bias;
        }
    }
  }
}

// ---------------- fused attn(read) + read einsums ----------------
__global__ __launch_bounds__(256) void k_fread(
    const float* __restrict__ x, const float* __restrict__ c,
    const float* __restrict__ h_dec,
    const float* __restrict__ raW, const float* __restrict__ rab,
    ushort_t* __restrict__ rH, ushort_t* __restrict__ rL) {
  int b = blockIdx.x;
  __shared__ float a_sh[5];
  __shared__ float fx[12][64], fy[12][64];
  __shared__ float srow[24];
  __shared__ float X[64][64];
  __shared__ float Xh[64][64];
  __shared__ float tmp[12][64], tmph[12][64];
  int tid = threadIdx.x, wv = tid >> 6, lane = tid & 63;
  const float* h = h_dec + (size_t)b * LL;
  // attention params: 5 dots of length 1024
  for (int o = wv; o < 5; o += 4) {
    float s = 0.f;
    const float* wrow = raW + (size_t)o * LL;
    for (int k = lane; k < LL; k += 64) s += h[k] * wrow[k];
#pragma unroll
    for (int d = 32; d; d >>= 1) s += __shfl_xor(s, d, 64);
    if (lane == 0) a_sh[o] = s + rab[o];
  }
  // canvas + input load
  for (int e = tid; e < 4096; e += 256) {
    float xv = x[(size_t)b * 4096 + e];
    float cv = c[(size_t)b * 4096 + e];
    X[e >> 6][e & 63] = xv;
    Xh[e >> 6][e & 63] = xv - sigf(cv);
  }
  __syncthreads();
  float gx = 32.5f * (a_sh[0] + 1.f);
  float gy = 32.5f * (a_sh[1] + 1.f);
  float i2v = 0.5f * expf(-a_sh[2]);
  float delta = (63.f / 11.f) * expf(a_sh[3]);
  float gam = expf(a_sh[4]);
  for (int e = tid; e < 768; e += 256) {
    int n = e >> 6, p = e & 63;
    float mu_x = gx + ((float)n - 5.5f) * delta;
    float mu_y = gy + ((float)n - 5.5f) * delta;
    float dx = (float)(p + 1) - mu_x;
    float dy = (float)(p + 1) - mu_y;
    fx[n][p] = expf(-i2v * dx * dx);
    fy[n][p] = expf(-i2v * dy * dy);
  }
  __syncthreads();
  if (tid < 24) {
    int n = tid % 12;
    float s = 0.f;
    if (tid < 12) { for (int p = 0; p < 64; ++p) s += fx[n][p]; }
    else          { for (int p = 0; p < 64; ++p) s += fy[n][p]; }
    srow[tid] = s + 6.4e-7f;   // sum(F + 1e-8) = sum(F) + 64e-8
  }
  __syncthreads();
  for (int e = tid; e < 768; e += 256) {
    int n = e >> 6, p = e & 63;
    fx[n][p] /= srow[n];
    fy[n][p] /= srow[12 + n];
  }
  __syncthreads();
  for (int e = tid; e < 768; e += 256) {
    int n = e >> 6, w2 = e & 63;
    float s = 0.f, sh = 0.f;
    for (int hh = 0; hh < 64; ++hh) {
      float f = fy[n][hh];
      s  = fmaf(f, X[hh][w2], s);
      sh = fmaf(f, Xh[hh][w2], sh);
    }
    tmp[n][w2] = s; tmph[n][w2] = sh;
  }
  __syncthreads();
  if (tid < 144) {
    int n = tid / 12, m = tid % 12;
    float s = 0.f, sh = 0.f;
    for (int w2 = 0; w2 < 64; ++w2) {
      float f = fx[m][w2];
      s  = fmaf(tmp[n][w2], f, s);
      sh = fmaf(tmph[n][w2], f, sh);
    }
    float v0 = gam * s, v1 = gam * sh;
    size_t i0 = (size_t)b * 320 + n * 12 + m;   // lda 320 (zero-padded to BK=64)
    size_t i1 = i0 + 144;
    ushort_t h0, l0, h1, l1;
    splitf(v0, h0, l0); splitf(v1, h1, l1);
    rH[i0] = h0; rL[i0] = l0;
    rH[i1] = h1; rL[i1] = l1;
  }
}

// ---------------- z = mu + sig*eps (inline threefry RNG) ----------------
__global__ __launch_bounds__(256) void k_z(const float* __restrict__ stats,
                                           ushort_t* __restrict__ zH,
                                           ushort_t* __restrict__ zL,
                                           float* __restrict__ out_mu,
                                           float* __restrict__ out_sg, int t) {
  int i = blockIdx.x * 256 + threadIdx.x;  // < 65536
  int b = i >> 7, zi = i & 127;
  uint32_t kA, kB, o0, o1;
  threefry(0u, 42u, 0u, (uint32_t)t, kA, kB);          // split(key(42),32)[t]
  threefry(kA, kB, 0u, (uint32_t)i, o0, o1);           // random_bits
  float ep = bits_to_normal(o0 ^ o1);
  float mu = stats[(size_t)b * 256 + zi];
  float sg = expf(stats[(size_t)b * 256 + 128 + zi]);
  float zv = mu + sg * ep;
  ushort_t zh, zl;
  splitf(zv, zh, zl);
  zH[i] = zh; zL[i] = zl;
  out_mu[(size_t)b * 4096 + zi * 32 + t] = mu;
  out_sg[(size_t)b * 4096 + zi * 32 + t] = sg;
}

// ---------------- write: filterbank from precomputed wva + canvas update ----------------
__global__ __launch_bounds__(256) void k_fwrite(
    float* __restrict__ c, const float* __restrict__ wva) {
  int b = blockIdx.x;
  __shared__ float wsm[12][12];
  __shared__ float a_sh[5];
  __shared__ float fx[12][64], fy[12][64];
  __shared__ float srow[24];
  __shared__ float tmp[12][64];
  int tid = threadIdx.x;
  if (tid < 144) wsm[tid / 12][tid % 12] = wva[(size_t)b * 160 + tid];
  else if (tid < 149) a_sh[tid - 144] = wva[(size_t)b * 160 + tid];
  __syncthreads();
  float gx = 32.5f * (a_sh[0] + 1.f);
  float gy = 32.5f * (a_sh[1] + 1.f);
  float i2v = 0.5f * expf(-a_sh[2]);
  float delta = (63.f / 11.f) * expf(a_sh[3]);
  float gam = expf(-a_sh[4]);
  for (int e = tid; e < 768; e += 256) {
    int n = e >> 6, p = e & 63;
    float mu_x = gx + ((float)n - 5.5f) * delta;
    float mu_y = gy + ((float)n - 5.5f) * delta;
    float dx = (float)(p + 1) - mu_x;
    float dy = (float)(p + 1) - mu_y;
    fx[n][p] = expf(-i2v * dx * dx);
    fy[n][p] = expf(-i2v * dy * dy);
  }
  __syncthreads();
  if (tid < 24) {
    int n = tid % 12;
    float s = 0.f;
    if (tid < 12) { for (int p = 0; p < 64; ++p) s += fx[n][p]; }
    else          { for (int p = 0; p < 64; ++p) s += fy[n][p]; }
    srow[tid] = s + 6.4e-7f;
  }
  __syncthreads();
  for (int e = tid; e < 768; e += 256) {
    int n = e >> 6, p = e & 63;
    fx[n][p] /= srow[n];
    fy[n][p] /= srow[12 + n];
  }
  __syncthreads();
  for (int e = tid; e < 768; e += 256) {
    int n = e >> 6, w2 = e & 63;
    float s = 0.f;
#pragma unroll
    for (int m = 0; m < 12; ++m) s = fmaf(wsm[n][m], fx[m][w2], s);
    tmp[n][w2] = s;
  }
  __syncthreads();
  for (int e = tid; e < 4096; e += 256) {
    int hh = e >> 6, w2 = e & 63;
    float s = 0.f;
#pragma unroll
    for (int n = 0; n < 12; ++n) s = fmaf(fy[n][hh], tmp[n][w2], s);
    c[(size_t)b * 4096 + e] += gam * s;
  }
}

// ---------------- LSTM gates (+ bf16 split of h) ----------------
__global__ __launch_bounds__(256) void k_lstm(const float* __restrict__ g,
                                              float* __restrict__ h, float* __restrict__ cst,
                                              ushort_t* __restrict__ hH,
                                              ushort_t* __restrict__ hL) {
  int i = blockIdx.x * 256 + threadIdx.x;
  int b = i >> 10, u = i & 1023;
  const float* gb = g + (size_t)b * 4096;
  float ig = gb[u], fg = gb[1024 + u], gg = gb[2048 + u], og = gb[3072 + u];
  float cv = sigf(fg) * cst[i] + sigf(ig) * tanhf(gg);
  cst[i] = cv;
  float hv = sigf(og) * tanhf(cv);
  h[i] = hv;
  ushort_t hh, hl;
  splitf(hv, hh, hl);
  hH[i] = hh; hL[i] = hl;
}

// ---------------- host launch ----------------
extern "C" void kernel_launch(void* const* d_in, const int* in_sizes, int n_in,
                              void* d_out, int out_size, void* d_ws, size_t ws_size,
                              hipStream_t stream) {
  const float* x       = (const float*)d_in[0];
  const float* enc_Wih = (const float*)d_in[1];
  const float* enc_Whh = (const float*)d_in[2];
  const float* enc_bih = (const float*)d_in[3];
  const float* enc_bhh = (const float*)d_in[4];
  const float* dec_Wih = (const float*)d_in[5];
  const float* dec_Whh = (const float*)d_in[6];
  const float* dec_bih = (const float*)d_in[7];
  const float* dec_bhh = (const float*)d_in[8];
  const float* zW  = (const float*)d_in[9];
  const float* zb  = (const float*)d_in[10];
  const float* wW  = (const float*)d_in[11];
  const float* wb  = (const float*)d_in[12];
  const float* raW = (const float*)d_in[13];
  const float* rab = (const float*)d_in[14];
  const float* waW = (const float*)d_in[15];
  const float* wab = (const float*)d_in[16];

  float* out = (float*)d_out;
  float* c      = out;
  float* out_mu = out + 2097152;
  float* out_sg = out + 4194304;

  // ---- workspace layout (bytes, 256-aligned) ----
  char* base = (char*)d_ws;
  size_t off = 0;
  auto alloc = [&](size_t bytes) -> char* {
    char* p = base + off;
    off = (off + bytes + 255) & ~(size_t)255;
    return p;
  };
  // zero-block (contiguous, first): states + recurrent splits + padded r + combined wW/waW
  float* h_enc = (float*)alloc(2097152);
  float* c_enc = (float*)alloc(2097152);
  float* h_dec = (float*)alloc(2097152);
  float* c_dec = (float*)alloc(2097152);
  ushort_t* hdH = (ushort_t*)alloc(1048576);
  ushort_t* hdL = (ushort_t*)alloc(1048576);
  ushort_t* heH = (ushort_t*)alloc(1048576);
  ushort_t* heL = (ushort_t*)alloc(1048576);
  ushort_t* rH  = (ushort_t*)alloc(327680);   // 512 x 320 (cols 288..319 stay zero)
  ushort_t* rL  = (ushort_t*)alloc(327680);
  ushort_t* cWH = (ushort_t*)alloc(327680);   // 160 x 1024 (rows 149..159 stay zero)
  ushort_t* cWL = (ushort_t*)alloc(327680);
  size_t zero_bytes = off;
  // per-step buffers
  ushort_t* zH = (ushort_t*)alloc(131072);
  ushort_t* zL = (ushort_t*)alloc(131072);
  float* gbuf  = (float*)alloc(8388608);
  float* stats = (float*)alloc(524288);
  float* wva   = (float*)alloc(327680);       // 512 x 160
  float* cb    = (float*)alloc(640);          // 160 combined bias
  // weight splits (bf16 hi/lo)
  ushort_t* eWihH = (ushort_t*)alloc(10747904);
  ushort_t* eWihL = (ushort_t*)alloc(10747904);
  ushort_t* eWhhH = (ushort_t*)alloc(8388608);
  ushort_t* eWhhL = (ushort_t*)alloc(8388608);
  ushort_t* dWihH = (ushort_t*)alloc(1048576);
  ushort_t* dWihL = (ushort_t*)alloc(1048576);
  ushort_t* dWhhH = (ushort_t*)alloc(8388608);
  ushort_t* dWhhL = (ushort_t*)alloc(8388608);
  ushort_t* zWH   = (ushort_t*)alloc(524288);
  ushort_t* zWL   = (ushort_t*)alloc(524288);

  hipMemsetAsync(c, 0, (size_t)2097152 * sizeof(float), stream);
  hipMemsetAsync(base, 0, zero_bytes, stream);

  // split weights once per launch
  k_split<<<(5373952 + 255) / 256, 256, 0, stream>>>(enc_Wih, eWihH, eWihL, 5373952);
  k_split<<<(4194304 + 255) / 256, 256, 0, stream>>>(enc_Whh, eWhhH, eWhhL, 4194304);
  k_split<<<(524288 + 255) / 256, 256, 0, stream>>>(dec_Wih, dWihH, dWihL, 524288);
  k_split<<<(4194304 + 255) / 256, 256, 0, stream>>>(dec_Whh, dWhhH, dWhhL, 4194304);
  k_split<<<(262144 + 255) / 256, 256, 0, stream>>>(zW, zWH, zWL, 262144);
  k_split<<<(147456 + 255) / 256, 256, 0, stream>>>(wW, cWH, cWL, 147456);
  k_split<<<(5120 + 255) / 256, 256, 0, stream>>>(waW, cWH + 147456, cWL + 147456, 5120);
  k_catbias<<<1, 160, 0, stream>>>(wb, wab, cb);

  SegList encS, decS, staS, wvS;
  encS.n = 9;
  encS.s[0] = {rH,  eWihH,       320,  320, 1312};
  encS.s[1] = {rL,  eWihH,       320,  320, 1312};
  encS.s[2] = {rH,  eWihL,       320,  320, 1312};
  encS.s[3] = {hdH, eWihH + 288, 1024, 1024, 1312};
  encS.s[4] = {hdL, eWihH + 288, 1024, 1024, 1312};
  encS.s[5] = {hdH, eWihL + 288, 1024, 1024, 1312};
  encS.s[6] = {heH, eWhhH,       1024, 1024, 1024};
  encS.s[7] = {heL, eWhhH,       1024, 1024, 1024};
  encS.s[8] = {heH, eWhhL,       1024, 1024, 1024};
  decS.n = 6;
  decS.s[0] = {zH,  dWihH, 128,  128, 128};
  decS.s[1] = {zL,  dWihH, 128,  128, 128};
  decS.s[2] = {zH,  dWihL, 128,  128, 128};
  decS.s[3] = {hdH, dWhhH, 1024, 1024, 1024};
  decS.s[4] = {hdL, dWhhH, 1024, 1024, 1024};
  decS.s[5] = {hdH, dWhhL, 1024, 1024, 1024};
  staS.n = 3;
  staS.s[0] = {heH, zWH, 1024, 1024, 1024};
  staS.s[1] = {heL, zWH, 1024, 1024, 1024};
  staS.s[2] = {heH, zWL, 1024, 1024, 1024};
  wvS.n = 3;
  wvS.s[0] = {hdH, cWH, 1024, 1024, 1024};
  wvS.s[1] = {hdL, cWH, 1024, 1024, 1024};
  wvS.s[2] = {hdH, cWL, 1024, 1024, 1024};

  for (int t = 0; t < TT; ++t) {
    k_fread<<<512, 256, 0, stream>>>(x, c, h_dec, raW, rab, rH, rL);
    mfma_gemm<<<dim3(32, 8), 256, 0, stream>>>(gbuf, 4096, encS, enc_bih, enc_bhh);
    k_lstm<<<2048, 256, 0, stream>>>(gbuf, h_enc, c_enc, heH, heL);
    mfma_gemm<<<dim3(2, 8), 256, 0, stream>>>(stats, 256, staS, zb, nullptr);
    k_z<<<256, 256, 0, stream>>>(stats, zH, zL, out_mu, out_sg, t);
    mfma_gemm<<<dim3(32, 8), 256, 0, stream>>>(gbuf, 4096, decS, dec_bih, dec_bhh);
    k_lstm<<<2048, 256, 0, stream>>>(gbuf, h_dec, c_dec, hdH, hdL);
    mfma_gemm<<<dim3(2, 8), 256, 0, stream>>>(wva, 160, wvS, cb, nullptr);
    k_fwrite<<<512, 256, 0, stream>>>(c, wva);
  }
}

// Round 11
// 7960.468 us; speedup vs baseline: 2.8285x; 1.0453x over previous
//
#include <hip/hip_runtime.h>
#include <cstdint>
#include <cstddef>

#define BB 512
#define TT 32
#define LL 1024
#define ZZ 128

typedef unsigned short ushort_t;
typedef __attribute__((ext_vector_type(8))) short s8v;    // 8 bf16 (4 VGPRs)
typedef __attribute__((ext_vector_type(4))) float f32x4;

// ---------------- math helpers ----------------
__device__ __forceinline__ float sigf(float x) { return 1.0f / (1.0f + expf(-x)); }

__device__ __forceinline__ ushort_t f2bf(float f) {
  uint32_t u = __float_as_uint(f);
  uint32_t r = (u + 0x7FFFu + ((u >> 16) & 1u)) >> 16;   // RNE
  return (ushort_t)r;
}
__device__ __forceinline__ float bf2f(ushort_t h) {
  return __uint_as_float(((uint32_t)h) << 16);
}
__device__ __forceinline__ void splitf(float v, ushort_t& hi, ushort_t& lo) {
  hi = f2bf(v);
  lo = f2bf(v - bf2f(hi));
}

// XLA ErfInv32 (Giles polynomial)
__device__ __forceinline__ float jax_erfinv(float x) {
  float w = -log1pf(-x * x);
  float p;
  if (w < 5.0f) {
    w = w - 2.5f;
    p = 2.81022636e-08f;
    p = fmaf(p, w, 3.43273939e-07f);
    p = fmaf(p, w, -3.5233877e-06f);
    p = fmaf(p, w, -4.39150654e-06f);
    p = fmaf(p, w, 0.00021858087f);
    p = fmaf(p, w, -0.00125372503f);
    p = fmaf(p, w, -0.00417768164f);
    p = fmaf(p, w, 0.246640727f);
    p = fmaf(p, w, 1.50140941f);
  } else {
    w = sqrtf(w) - 3.0f;
    p = -0.000200214257f;
    p = fmaf(p, w, 0.000100950558f);
    p = fmaf(p, w, 0.00134934322f);
    p = fmaf(p, w, -0.00367342844f);
    p = fmaf(p, w, 0.00573950773f);
    p = fmaf(p, w, -0.0076224613f);
    p = fmaf(p, w, 0.00943887047f);
    p = fmaf(p, w, 1.00167406f);
    p = fmaf(p, w, 2.83297682f);
  }
  return p * x;
}

// Threefry-2x32, 20 rounds (JAX schedule)
__device__ __forceinline__ void threefry(uint32_t k0, uint32_t k1,
                                         uint32_t x0, uint32_t x1,
                                         uint32_t& o0, uint32_t& o1) {
  uint32_t ks0 = k0, ks1 = k1, ks2 = k0 ^ k1 ^ 0x1BD11BDAu;
  x0 += ks0; x1 += ks1;
#define TF_ROT(x, d) (((x) << (d)) | ((x) >> (32 - (d))))
#define TF_RND(r) { x0 += x1; x1 = TF_ROT(x1, r); x1 ^= x0; }
  TF_RND(13) TF_RND(15) TF_RND(26) TF_RND(6)
  x0 += ks1; x1 += ks2 + 1u;
  TF_RND(17) TF_RND(29) TF_RND(16) TF_RND(24)
  x0 += ks2; x1 += ks0 + 2u;
  TF_RND(13) TF_RND(15) TF_RND(26) TF_RND(6)
  x0 += ks0; x1 += ks1 + 3u;
  TF_RND(17) TF_RND(29) TF_RND(16) TF_RND(24)
  x0 += ks1; x1 += ks2 + 4u;
  TF_RND(13) TF_RND(15) TF_RND(26) TF_RND(6)
  x0 += ks2; x1 += ks0 + 5u;
#undef TF_RND
#undef TF_ROT
  o0 = x0; o1 = x1;
}

__device__ __forceinline__ float bits_to_normal(uint32_t bits) {
  uint32_t fb = (bits >> 9) | 0x3f800000u;
  float f = __uint_as_float(fb) - 1.0f;
  const float lo = -0.99999994f;
  float u = fmaxf(lo, f * 2.0f + lo);
  return 1.41421356237f * jax_erfinv(u);
}

// ---------------- weight split: f32 -> bf16 hi/lo ----------------
__global__ __launch_bounds__(256) void k_split(const float* __restrict__ src,
                                               ushort_t* __restrict__ hi,
                                               ushort_t* __restrict__ lo, int n) {
  int i = blockIdx.x * 256 + threadIdx.x;
  if (i >= n) return;
  ushort_t h, l;
  splitf(src[i], h, l);
  hi[i] = h; lo[i] = l;
}

// combined bias for [wW | waW | raW] GEMM (raW rows get 0; fread adds rab itself)
__global__ void k_catbias(const float* __restrict__ wb, const float* __restrict__ wab,
                          float* __restrict__ cb) {
  int i = threadIdx.x;   // 176 threads
  cb[i] = (i < 144) ? wb[i] : (i < 149 ? wab[i - 144] : 0.f);
}

// ---------------- MFMA GEMM: C[512][N] = sum_seg A_s @ W_s^T + b0 + b1 ----------------
// Tile 32(M) x 128(N), BK=64; 4 waves as 1x4, each wave 32x32 out (2x2 16x16 frags).
// Grid (N/128, 16) -> 512 blocks for N=4096 = 2 blocks/CU.
struct Seg { const ushort_t* A; const ushort_t* W; int K; int lda; int ldw; };
struct SegList { Seg s[9]; int n; };

__device__ __forceinline__ void load_tiles(const Seg& sg, int bm, int bn, int N, int k0,
                                           int tid, s8v& va, s8v vw[4]) {
  va = *(const s8v*)(sg.A + (size_t)(bm + (tid >> 3)) * sg.lda + k0 + (tid & 7) * 8);
#pragma unroll
  for (int i = 0; i < 4; ++i) {
    int cch = tid + 256 * i;
    int row = cch >> 3, col = cch & 7;
    int n = bn + row;
    if (n < N) vw[i] = *(const s8v*)(sg.W + (size_t)n * sg.ldw + k0 + col * 8);
    else       vw[i] = (s8v)(short)0;
  }
}

__global__ __launch_bounds__(256) void mfma_gemm(
    float* __restrict__ C, int N, SegList segs,
    const float* __restrict__ b0, const float* __restrict__ b1) {
  __shared__ __align__(16) ushort_t As[32][72];    // pad 8 elems: stride 36 dwords
  __shared__ __align__(16) ushort_t Ws[128][72];
  const int bm = blockIdx.y * 32, bn = blockIdx.x * 128;
  const int tid = threadIdx.x;
  const int w = tid >> 6, lane = tid & 63;
  const int lr = lane & 15, lq = lane >> 4;
  f32x4 acc[2][2] = {};

  int si = 0, k0 = 0;
  s8v va, vw[4];
  load_tiles(segs.s[0], bm, bn, N, 0, tid, va, vw);
  while (1) {
    __syncthreads();
    *(s8v*)&As[tid >> 3][(tid & 7) * 8] = va;
#pragma unroll
    for (int i = 0; i < 4; ++i) {
      int cch = tid + 256 * i;
      *(s8v*)&Ws[cch >> 3][(cch & 7) * 8] = vw[i];
    }
    __syncthreads();
    int nsi = si, nk0 = k0 + 64;
    if (nk0 >= segs.s[si].K) { nk0 = 0; nsi = si + 1; }
    const bool more = (nsi < segs.n);
    if (more) load_tiles(segs.s[nsi], bm, bn, N, nk0, tid, va, vw);
#pragma unroll
    for (int ks = 0; ks < 2; ++ks) {
      s8v a0 = *(const s8v*)&As[lr][ks * 32 + lq * 8];
      s8v a1 = *(const s8v*)&As[16 + lr][ks * 32 + lq * 8];
#pragma unroll
      for (int j = 0; j < 2; ++j) {
        s8v bf = *(const s8v*)&Ws[w * 32 + j * 16 + lr][ks * 32 + lq * 8];
        acc[0][j] = __builtin_amdgcn_mfma_f32_16x16x32_bf16(a0, bf, acc[0][j], 0, 0, 0);
        acc[1][j] = __builtin_amdgcn_mfma_f32_16x16x32_bf16(a1, bf, acc[1][j], 0, 0, 0);
      }
    }
    if (!more) break;
    si = nsi; k0 = nk0;
  }
#pragma unroll
  for (int j = 0; j < 2; ++j) {
    int col = bn + w * 32 + j * 16 + lr;
    if (col < N) {
      float bias = (b0 ? b0[col] : 0.f) + (b1 ? b1[col] : 0.f);
#pragma unroll
      for (int m = 0; m < 2; ++m)
#pragma unroll
        for (int q = 0; q < 4; ++q) {
          int rr = bm + m * 16 + lq * 4 + q;   // C/D: col=lane&15, row=(lane>>4)*4+q
          C[(size_t)rr * N + col] = acc[m][j][q] + bias;
        }
    }
  }
}

// ---------------- fused attn(read) + read einsums ----------------
// attn params come from wva[b][149..153] (raW@h_dec from prev step's GEMM; 0 at t=0)
__global__ __launch_bounds__(256) void k_fread(
    const float* __restrict__ x, const float* __restrict__ c,
    const float* __restrict__ wva, const float* __restrict__ rab,
    ushort_t* __restrict__ rH, ushort_t* __restrict__ rL) {
  int b = blockIdx.x;
  __shared__ float a_sh[5];
  __shared__ float fx[12][64], fy[12][64];
  __shared__ float srow[24];
  __shared__ float X[64][64];
  __shared__ float Xh[64][64];
  __shared__ float tmp[12][64], tmph[12][64];
  int tid = threadIdx.x;
  if (tid < 5) a_sh[tid] = wva[(size_t)b * 176 + 149 + tid] + rab[tid];
  // canvas + input load
  for (int e = tid; e < 4096; e += 256) {
    float xv = x[(size_t)b * 4096 + e];
    float cv = c[(size_t)b * 4096 + e];
    X[e >> 6][e & 63] = xv;
    Xh[e >> 6][e & 63] = xv - sigf(cv);
  }
  __syncthreads();
  float gx = 32.5f * (a_sh[0] + 1.f);
  float gy = 32.5f * (a_sh[1] + 1.f);
  float i2v = 0.5f * expf(-a_sh[2]);
  float delta = (63.f / 11.f) * expf(a_sh[3]);
  float gam = expf(a_sh[4]);
  for (int e = tid; e < 768; e += 256) {
    int n = e >> 6, p = e & 63;
    float mu_x = gx + ((float)n - 5.5f) * delta;
    float mu_y = gy + ((float)n - 5.5f) * delta;
    float dx = (float)(p + 1) - mu_x;
    float dy = (float)(p + 1) - mu_y;
    fx[n][p] = expf(-i2v * dx * dx);
    fy[n][p] = expf(-i2v * dy * dy);
  }
  __syncthreads();
  if (tid < 24) {
    int n = tid % 12;
    float s = 0.f;
    if (tid < 12) { for (int p = 0; p < 64; ++p) s += fx[n][p]; }
    else          { for (int p = 0; p < 64; ++p) s += fy[n][p]; }
    srow[tid] = s + 6.4e-7f;   // sum(F + 1e-8) = sum(F) + 64e-8
  }
  __syncthreads();
  for (int e = tid; e < 768; e += 256) {
    int n = e >> 6, p = e & 63;
    fx[n][p] /= srow[n];
    fy[n][p] /= srow[12 + n];
  }
  __syncthreads();
  for (int e = tid; e < 768; e += 256) {
    int n = e >> 6, w2 = e & 63;
    float s = 0.f, sh = 0.f;
    for (int hh = 0; hh < 64; ++hh) {
      float f = fy[n][hh];
      s  = fmaf(f, X[hh][w2], s);
      sh = fmaf(f, Xh[hh][w2], sh);
    }
    tmp[n][w2] = s; tmph[n][w2] = sh;
  }
  __syncthreads();
  if (tid < 144) {
    int n = tid / 12, m = tid % 12;
    float s = 0.f, sh = 0.f;
    for (int w2 = 0; w2 < 64; ++w2) {
      float f = fx[m][w2];
      s  = fmaf(tmp[n][w2], f, s);
      sh = fmaf(tmph[n][w2], f, sh);
    }
    float v0 = gam * s, v1 = gam * sh;
    size_t i0 = (size_t)b * 320 + n * 12 + m;   // lda 320 (zero-padded to BK=64)
    size_t i1 = i0 + 144;
    ushort_t h0, l0, h1, l1;
    splitf(v0, h0, l0); splitf(v1, h1, l1);
    rH[i0] = h0; rL[i0] = l0;
    rH[i1] = h1; rL[i1] = l1;
  }
}

// ---------------- z = mu + sig*eps (inline threefry RNG) ----------------
__global__ __launch_bounds__(256) void k_z(const float* __restrict__ stats,
                                           ushort_t* __restrict__ zH,
                                           ushort_t* __restrict__ zL,
                                           float* __restrict__ out_mu,
                                           float* __restrict__ out_sg, int t) {
  int i = blockIdx.x * 256 + threadIdx.x;  // < 65536
  int b = i >> 7, zi = i & 127;
  uint32_t kA, kB, o0, o1;
  threefry(0u, 42u, 0u, (uint32_t)t, kA, kB);          // split(key(42),32)[t]
  threefry(kA, kB, 0u, (uint32_t)i, o0, o1);           // random_bits
  float ep = bits_to_normal(o0 ^ o1);
  float mu = stats[(size_t)b * 256 + zi];
  float sg = expf(stats[(size_t)b * 256 + 128 + zi]);
  float zv = mu + sg * ep;
  ushort_t zh, zl;
  splitf(zv, zh, zl);
  zH[i] = zh; zL[i] = zl;
  out_mu[(size_t)b * 4096 + zi * 32 + t] = mu;
  out_sg[(size_t)b * 4096 + zi * 32 + t] = sg;
}

// ---------------- write: filterbank from precomputed wva + canvas update ----------------
__global__ __launch_bounds__(256) void k_fwrite(
    float* __restrict__ c, const float* __restrict__ wva) {
  int b = blockIdx.x;
  __shared__ float wsm[12][12];
  __shared__ float a_sh[5];
  __shared__ float fx[12][64], fy[12][64];
  __shared__ float srow[24];
  __shared__ float tmp[12][64];
  int tid = threadIdx.x;
  if (tid < 144) wsm[tid / 12][tid % 12] = wva[(size_t)b * 176 + tid];
  else if (tid < 149) a_sh[tid - 144] = wva[(size_t)b * 176 + tid];
  __syncthreads();
  float gx = 32.5f * (a_sh[0] + 1.f);
  float gy = 32.5f * (a_sh[1] + 1.f);
  float i2v = 0.5f * expf(-a_sh[2]);
  float delta = (63.f / 11.f) * expf(a_sh[3]);
  float gam = expf(-a_sh[4]);
  for (int e = tid; e < 768; e += 256) {
    int n = e >> 6, p = e & 63;
    float mu_x = gx + ((float)n - 5.5f) * delta;
    float mu_y = gy + ((float)n - 5.5f) * delta;
    float dx = (float)(p + 1) - mu_x;
    float dy = (float)(p + 1) - mu_y;
    fx[n][p] = expf(-i2v * dx * dx);
    fy[n][p] = expf(-i2v * dy * dy);
  }
  __syncthreads();
  if (tid < 24) {
    int n = tid % 12;
    float s = 0.f;
    if (tid < 12) { for (int p = 0; p < 64; ++p) s += fx[n][p]; }
    else          { for (int p = 0; p < 64; ++p) s += fy[n][p]; }
    srow[tid] = s + 6.4e-7f;
  }
  __syncthreads();
  for (int e = tid; e < 768; e += 256) {
    int n = e >> 6, p = e & 63;
    fx[n][p] /= srow[n];
    fy[n][p] /= srow[12 + n];
  }
  __syncthreads();
  for (int e = tid; e < 768; e += 256) {
    int n = e >> 6, w2 = e & 63;
    float s = 0.f;
#pragma unroll
    for (int m = 0; m < 12; ++m) s = fmaf(wsm[n][m], fx[m][w2], s);
    tmp[n][w2] = s;
  }
  __syncthreads();
  for (int e = tid; e < 4096; e += 256) {
    int hh = e >> 6, w2 = e & 63;
    float s = 0.f;
#pragma unroll
    for (int n = 0; n < 12; ++n) s = fmaf(fy[n][hh], tmp[n][w2], s);
    c[(size_t)b * 4096 + e] += gam * s;
  }
}

// ---------------- LSTM gates (+ bf16 split of h) ----------------
__global__ __launch_bounds__(256) void k_lstm(const float* __restrict__ g,
                                              float* __restrict__ h, float* __restrict__ cst,
                                              ushort_t* __restrict__ hH,
                                              ushort_t* __restrict__ hL) {
  int i = blockIdx.x * 256 + threadIdx.x;
  int b = i >> 10, u = i & 1023;
  const float* gb = g + (size_t)b * 4096;
  float ig = gb[u], fg = gb[1024 + u], gg = gb[2048 + u], og = gb[3072 + u];
  float cv = sigf(fg) * cst[i] + sigf(ig) * tanhf(gg);
  cst[i] = cv;
  float hv = sigf(og) * tanhf(cv);
  h[i] = hv;
  ushort_t hh, hl;
  splitf(hv, hh, hl);
  hH[i] = hh; hL[i] = hl;
}

// ---------------- host launch ----------------
extern "C" void kernel_launch(void* const* d_in, const int* in_sizes, int n_in,
                              void* d_out, int out_size, void* d_ws, size_t ws_size,
                              hipStream_t stream) {
  const float* x       = (const float*)d_in[0];
  const float* enc_Wih = (const float*)d_in[1];
  const float* enc_Whh = (const float*)d_in[2];
  const float* enc_bih = (const float*)d_in[3];
  const float* enc_bhh = (const float*)d_in[4];
  const float* dec_Wih = (const float*)d_in[5];
  const float* dec_Whh = (const float*)d_in[6];
  const float* dec_bih = (const float*)d_in[7];
  const float* dec_bhh = (const float*)d_in[8];
  const float* zW  = (const float*)d_in[9];
  const float* zb  = (const float*)d_in[10];
  const float* wW  = (const float*)d_in[11];
  const float* wb  = (const float*)d_in[12];
  const float* raW = (const float*)d_in[13];
  const float* rab = (const float*)d_in[14];
  const float* waW = (const float*)d_in[15];
  const float* wab = (const float*)d_in[16];

  float* out = (float*)d_out;
  float* c      = out;
  float* out_mu = out + 2097152;
  float* out_sg = out + 4194304;

  // ---- workspace layout (bytes, 256-aligned) ----
  char* base = (char*)d_ws;
  size_t off = 0;
  auto alloc = [&](size_t bytes) -> char* {
    char* p = base + off;
    off = (off + bytes + 255) & ~(size_t)255;
    return p;
  };
  // zero-block (contiguous, first): states + recurrent splits + padded r + combined W + wva
  float* h_enc = (float*)alloc(2097152);
  float* c_enc = (float*)alloc(2097152);
  float* h_dec = (float*)alloc(2097152);
  float* c_dec = (float*)alloc(2097152);
  ushort_t* hdH = (ushort_t*)alloc(1048576);
  ushort_t* hdL = (ushort_t*)alloc(1048576);
  ushort_t* heH = (ushort_t*)alloc(1048576);
  ushort_t* heL = (ushort_t*)alloc(1048576);
  ushort_t* rH  = (ushort_t*)alloc(327680);   // 512 x 320 (cols 288..319 stay zero)
  ushort_t* rL  = (ushort_t*)alloc(327680);
  ushort_t* cWH = (ushort_t*)alloc(360448);   // 176 x 1024 (rows 154..175 stay zero)
  ushort_t* cWL = (ushort_t*)alloc(360448);
  float* wva    = (float*)alloc(360448);      // 512 x 176 (zero for t=0 fread)
  size_t zero_bytes = off;
  // per-step buffers
  ushort_t* zH = (ushort_t*)alloc(131072);
  ushort_t* zL = (ushort_t*)alloc(131072);
  float* gbuf  = (float*)alloc(8388608);
  float* stats = (float*)alloc(524288);
  float* cb    = (float*)alloc(704);          // 176 combined bias
  // weight splits (bf16 hi/lo)
  ushort_t* eWihH = (ushort_t*)alloc(10747904);
  ushort_t* eWihL = (ushort_t*)alloc(10747904);
  ushort_t* eWhhH = (ushort_t*)alloc(8388608);
  ushort_t* eWhhL = (ushort_t*)alloc(8388608);
  ushort_t* dWihH = (ushort_t*)alloc(1048576);
  ushort_t* dWihL = (ushort_t*)alloc(1048576);
  ushort_t* dWhhH = (ushort_t*)alloc(8388608);
  ushort_t* dWhhL = (ushort_t*)alloc(8388608);
  ushort_t* zWH   = (ushort_t*)alloc(524288);
  ushort_t* zWL   = (ushort_t*)alloc(524288);

  hipMemsetAsync(c, 0, (size_t)2097152 * sizeof(float), stream);
  hipMemsetAsync(base, 0, zero_bytes, stream);

  // split weights once per launch
  k_split<<<(5373952 + 255) / 256, 256, 0, stream>>>(enc_Wih, eWihH, eWihL, 5373952);
  k_split<<<(4194304 + 255) / 256, 256, 0, stream>>>(enc_Whh, eWhhH, eWhhL, 4194304);
  k_split<<<(524288 + 255) / 256, 256, 0, stream>>>(dec_Wih, dWihH, dWihL, 524288);
  k_split<<<(4194304 + 255) / 256, 256, 0, stream>>>(dec_Whh, dWhhH, dWhhL, 4194304);
  k_split<<<(262144 + 255) / 256, 256, 0, stream>>>(zW, zWH, zWL, 262144);
  k_split<<<(147456 + 255) / 256, 256, 0, stream>>>(wW, cWH, cWL, 147456);
  k_split<<<(5120 + 255) / 256, 256, 0, stream>>>(waW, cWH + 147456, cWL + 147456, 5120);
  k_split<<<(5120 + 255) / 256, 256, 0, stream>>>(raW, cWH + 152576, cWL + 152576, 5120);
  k_catbias<<<1, 176, 0, stream>>>(wb, wab, cb);

  SegList encS, decS, staS, wvS;
  encS.n = 9;
  encS.s[0] = {rH,  eWihH,       320,  320, 1312};
  encS.s[1] = {rL,  eWihH,       320,  320, 1312};
  encS.s[2] = {rH,  eWihL,       320,  320, 1312};
  encS.s[3] = {hdH, eWihH + 288, 1024, 1024, 1312};
  encS.s[4] = {hdL, eWihH + 288, 1024, 1024, 1312};
  encS.s[5] = {hdH, eWihL + 288, 1024, 1024, 1312};
  encS.s[6] = {heH, eWhhH,       1024, 1024, 1024};
  encS.s[7] = {heL, eWhhH,       1024, 1024, 1024};
  encS.s[8] = {heH, eWhhL,       1024, 1024, 1024};
  decS.n = 6;
  decS.s[0] = {zH,  dWihH, 128,  128, 128};
  decS.s[1] = {zL,  dWihH, 128,  128, 128};
  decS.s[2] = {zH,  dWihL, 128,  128, 128};
  decS.s[3] = {hdH, dWhhH, 1024, 1024, 1024};
  decS.s[4] = {hdL, dWhhH, 1024, 1024, 1024};
  decS.s[5] = {hdH, dWhhL, 1024, 1024, 1024};
  staS.n = 3;
  staS.s[0] = {heH, zWH, 1024, 1024, 1024};
  staS.s[1] = {heL, zWH, 1024, 1024, 1024};
  staS.s[2] = {heH, zWL, 1024, 1024, 1024};
  wvS.n = 3;
  wvS.s[0] = {hdH, cWH, 1024, 1024, 1024};
  wvS.s[1] = {hdL, cWH, 1024, 1024, 1024};
  wvS.s[2] = {hdH, cWL, 1024, 1024, 1024};

  for (int t = 0; t < TT; ++t) {
    k_fread<<<512, 256, 0, stream>>>(x, c, wva, rab, rH, rL);
    mfma_gemm<<<dim3(32, 16), 256, 0, stream>>>(gbuf, 4096, encS, enc_bih, enc_bhh);
    k_lstm<<<2048, 256, 0, stream>>>(gbuf, h_enc, c_enc, heH, heL);
    mfma_gemm<<<dim3(2, 16), 256, 0, stream>>>(stats, 256, staS, zb, nullptr);
    k_z<<<256, 256, 0, stream>>>(stats, zH, zL, out_mu, out_sg, t);
    mfma_gemm<<<dim3(32, 16), 256, 0, stream>>>(gbuf, 4096, decS, dec_bih, dec_bhh);
    k_lstm<<<2048, 256, 0, stream>>>(gbuf, h_dec, c_dec, hdH, hdL);
    mfma_gemm<<<dim3(2, 16), 256, 0, stream>>>(wva, 176, wvS, cb, nullptr);
    k_fwrite<<<512, 256, 0, stream>>>(c, wva);
  }
}

// Round 12
// 6564.789 us; speedup vs baseline: 3.4298x; 1.2126x over previous
//
#include <hip/hip_runtime.h>
#include <cstdint>
#include <cstddef>

#define BB 512
#define TT 32
#define LL 1024
#define ZZ 128

typedef unsigned short ushort_t;
typedef __attribute__((ext_vector_type(8))) short s8v;    // 8 bf16 (4 VGPRs)
typedef __attribute__((ext_vector_type(4))) float f32x4;

// ---------------- math helpers ----------------
__device__ __forceinline__ float sigf(float x) { return 1.0f / (1.0f + expf(-x)); }

__device__ __forceinline__ ushort_t f2bf(float f) {
  uint32_t u = __float_as_uint(f);
  uint32_t r = (u + 0x7FFFu + ((u >> 16) & 1u)) >> 16;   // RNE
  return (ushort_t)r;
}
__device__ __forceinline__ float bf2f(ushort_t h) {
  return __uint_as_float(((uint32_t)h) << 16);
}
__device__ __forceinline__ void splitf(float v, ushort_t& hi, ushort_t& lo) {
  hi = f2bf(v);
  lo = f2bf(v - bf2f(hi));
}

// XLA ErfInv32 (Giles polynomial)
__device__ __forceinline__ float jax_erfinv(float x) {
  float w = -log1pf(-x * x);
  float p;
  if (w < 5.0f) {
    w = w - 2.5f;
    p = 2.81022636e-08f;
    p = fmaf(p, w, 3.43273939e-07f);
    p = fmaf(p, w, -3.5233877e-06f);
    p = fmaf(p, w, -4.39150654e-06f);
    p = fmaf(p, w, 0.00021858087f);
    p = fmaf(p, w, -0.00125372503f);
    p = fmaf(p, w, -0.00417768164f);
    p = fmaf(p, w, 0.246640727f);
    p = fmaf(p, w, 1.50140941f);
  } else {
    w = sqrtf(w) - 3.0f;
    p = -0.000200214257f;
    p = fmaf(p, w, 0.000100950558f);
    p = fmaf(p, w, 0.00134934322f);
    p = fmaf(p, w, -0.00367342844f);
    p = fmaf(p, w, 0.00573950773f);
    p = fmaf(p, w, -0.0076224613f);
    p = fmaf(p, w, 0.00943887047f);
    p = fmaf(p, w, 1.00167406f);
    p = fmaf(p, w, 2.83297682f);
  }
  return p * x;
}

// Threefry-2x32, 20 rounds (JAX schedule)
__device__ __forceinline__ void threefry(uint32_t k0, uint32_t k1,
                                         uint32_t x0, uint32_t x1,
                                         uint32_t& o0, uint32_t& o1) {
  uint32_t ks0 = k0, ks1 = k1, ks2 = k0 ^ k1 ^ 0x1BD11BDAu;
  x0 += ks0; x1 += ks1;
#define TF_ROT(x, d) (((x) << (d)) | ((x) >> (32 - (d))))
#define TF_RND(r) { x0 += x1; x1 = TF_ROT(x1, r); x1 ^= x0; }
  TF_RND(13) TF_RND(15) TF_RND(26) TF_RND(6)
  x0 += ks1; x1 += ks2 + 1u;
  TF_RND(17) TF_RND(29) TF_RND(16) TF_RND(24)
  x0 += ks2; x1 += ks0 + 2u;
  TF_RND(13) TF_RND(15) TF_RND(26) TF_RND(6)
  x0 += ks0; x1 += ks1 + 3u;
  TF_RND(17) TF_RND(29) TF_RND(16) TF_RND(24)
  x0 += ks1; x1 += ks2 + 4u;
  TF_RND(13) TF_RND(15) TF_RND(26) TF_RND(6)
  x0 += ks2; x1 += ks0 + 5u;
#undef TF_RND
#undef TF_ROT
  o0 = x0; o1 = x1;
}

__device__ __forceinline__ float bits_to_normal(uint32_t bits) {
  uint32_t fb = (bits >> 9) | 0x3f800000u;
  float f = __uint_as_float(fb) - 1.0f;
  const float lo = -0.99999994f;
  float u = fmaxf(lo, f * 2.0f + lo);
  return 1.41421356237f * jax_erfinv(u);
}

// ---------------- weight split: f32 -> bf16 hi/lo ----------------
__global__ __launch_bounds__(256) void k_split(const float* __restrict__ src,
                                               ushort_t* __restrict__ hi,
                                               ushort_t* __restrict__ lo, int n) {
  int i = blockIdx.x * 256 + threadIdx.x;
  if (i >= n) return;
  ushort_t h, l;
  splitf(src[i], h, l);
  hi[i] = h; lo[i] = l;
}

// combined bias for [wW | waW | raW] GEMM (raW rows get 0; fread adds rab itself)
__global__ void k_catbias(const float* __restrict__ wb, const float* __restrict__ wab,
                          float* __restrict__ cb) {
  int i = threadIdx.x;   // 176 threads
  cb[i] = (i < 144) ? wb[i] : (i < 149 ? wab[i - 144] : 0.f);
}

// ---------------- MFMA GEMM with split-K -------------------------------------
// Tile 64(M) x 128(N), BK=64; 4 waves as 2x2, each wave 32x64 out (2x4 frags).
// blockIdx.z selects segment-partition; output goes to C + z*zstride (raw, no
// bias when split — reduction+bias folded into consumer).
struct Seg { const ushort_t* A; const ushort_t* W; int K; int lda; int ldw; };
struct SegList2 { Seg s[2][9]; int n[2]; };

__device__ __forceinline__ void load_tiles(const Seg& sg, int bm, int bn, int N, int k0,
                                           int tid, s8v va[2], s8v vw[4]) {
#pragma unroll
  for (int i = 0; i < 2; ++i) {
    int cch = tid + 256 * i;
    int row = cch >> 3, col = cch & 7;
    va[i] = *(const s8v*)(sg.A + (size_t)(bm + row) * sg.lda + k0 + col * 8);
  }
#pragma unroll
  for (int i = 0; i < 4; ++i) {
    int cch = tid + 256 * i;
    int row = cch >> 3, col = cch & 7;
    int n = bn + row;
    if (n < N) vw[i] = *(const s8v*)(sg.W + (size_t)n * sg.ldw + k0 + col * 8);
    else       vw[i] = (s8v)(short)0;
  }
}

__global__ __launch_bounds__(256) void mfma_gemm(
    float* __restrict__ C, unsigned zstride, int N, SegList2 segs2,
    const float* __restrict__ b0, const float* __restrict__ b1) {
  __shared__ __align__(16) ushort_t As[64][72];    // pad 8 elems
  __shared__ __align__(16) ushort_t Ws[128][72];
  const int z = blockIdx.z;
  const Seg* segs = segs2.s[z];
  const int nseg = segs2.n[z];
  C += (size_t)z * zstride;
  const int bm = blockIdx.y * 64, bn = blockIdx.x * 128;
  const int tid = threadIdx.x;
  const int w = tid >> 6, lane = tid & 63;
  const int wr = w >> 1, wc = w & 1;               // wave grid 2(M) x 2(N)
  const int lr = lane & 15, lq = lane >> 4;
  f32x4 acc[2][4] = {};

  int si = 0, k0 = 0;
  s8v va[2], vw[4];
  load_tiles(segs[0], bm, bn, N, 0, tid, va, vw);
  while (1) {
    __syncthreads();
#pragma unroll
    for (int i = 0; i < 2; ++i) {
      int cch = tid + 256 * i;
      *(s8v*)&As[cch >> 3][(cch & 7) * 8] = va[i];
    }
#pragma unroll
    for (int i = 0; i < 4; ++i) {
      int cch = tid + 256 * i;
      *(s8v*)&Ws[cch >> 3][(cch & 7) * 8] = vw[i];
    }
    __syncthreads();
    int nsi = si, nk0 = k0 + 64;
    if (nk0 >= segs[si].K) { nk0 = 0; nsi = si + 1; }
    const bool more = (nsi < nseg);
    if (more) load_tiles(segs[nsi], bm, bn, N, nk0, tid, va, vw);
#pragma unroll
    for (int ks = 0; ks < 2; ++ks) {
      s8v a0 = *(const s8v*)&As[wr * 32 + lr][ks * 32 + lq * 8];
      s8v a1 = *(const s8v*)&As[wr * 32 + 16 + lr][ks * 32 + lq * 8];
#pragma unroll
      for (int j = 0; j < 4; ++j) {
        s8v bf = *(const s8v*)&Ws[wc * 64 + j * 16 + lr][ks * 32 + lq * 8];
        acc[0][j] = __builtin_amdgcn_mfma_f32_16x16x32_bf16(a0, bf, acc[0][j], 0, 0, 0);
        acc[1][j] = __builtin_amdgcn_mfma_f32_16x16x32_bf16(a1, bf, acc[1][j], 0, 0, 0);
      }
    }
    if (!more) break;
    si = nsi; k0 = nk0;
  }
#pragma unroll
  for (int j = 0; j < 4; ++j) {
    int col = bn + wc * 64 + j * 16 + lr;
    if (col < N) {
      float bias = (b0 ? b0[col] : 0.f) + (b1 ? b1[col] : 0.f);
#pragma unroll
      for (int m = 0; m < 2; ++m)
#pragma unroll
        for (int q = 0; q < 4; ++q) {
          int rr = bm + wr * 32 + m * 16 + lq * 4 + q;  // C/D: col=lane&15, row=(lane>>4)*4+q
          C[(size_t)rr * N + col] = acc[m][j][q] + bias;
        }
    }
  }
}

// ---------------- fused attn(read) + read einsums ----------------
// attn params come from wva[b][149..153] (raW@h_dec from prev step's GEMM; 0 at t=0)
__global__ __launch_bounds__(256) void k_fread(
    const float* __restrict__ x, const float* __restrict__ c,
    const float* __restrict__ wva, const float* __restrict__ rab,
    ushort_t* __restrict__ rH, ushort_t* __restrict__ rL) {
  int b = blockIdx.x;
  __shared__ float a_sh[5];
  __shared__ float fx[12][64], fy[12][64];
  __shared__ float srow[24];
  __shared__ float X[64][64];
  __shared__ float Xh[64][64];
  __shared__ float tmp[12][64], tmph[12][64];
  int tid = threadIdx.x;
  if (tid < 5) a_sh[tid] = wva[(size_t)b * 176 + 149 + tid] + rab[tid];
  for (int e = tid; e < 4096; e += 256) {
    float xv = x[(size_t)b * 4096 + e];
    float cv = c[(size_t)b * 4096 + e];
    X[e >> 6][e & 63] = xv;
    Xh[e >> 6][e & 63] = xv - sigf(cv);
  }
  __syncthreads();
  float gx = 32.5f * (a_sh[0] + 1.f);
  float gy = 32.5f * (a_sh[1] + 1.f);
  float i2v = 0.5f * expf(-a_sh[2]);
  float delta = (63.f / 11.f) * expf(a_sh[3]);
  float gam = expf(a_sh[4]);
  for (int e = tid; e < 768; e += 256) {
    int n = e >> 6, p = e & 63;
    float mu_x = gx + ((float)n - 5.5f) * delta;
    float mu_y = gy + ((float)n - 5.5f) * delta;
    float dx = (float)(p + 1) - mu_x;
    float dy = (float)(p + 1) - mu_y;
    fx[n][p] = expf(-i2v * dx * dx);
    fy[n][p] = expf(-i2v * dy * dy);
  }
  __syncthreads();
  if (tid < 24) {
    int n = tid % 12;
    float s = 0.f;
    if (tid < 12) { for (int p = 0; p < 64; ++p) s += fx[n][p]; }
    else          { for (int p = 0; p < 64; ++p) s += fy[n][p]; }
    srow[tid] = s + 6.4e-7f;   // sum(F + 1e-8) = sum(F) + 64e-8
  }
  __syncthreads();
  for (int e = tid; e < 768; e += 256) {
    int n = e >> 6, p = e & 63;
    fx[n][p] /= srow[n];
    fy[n][p] /= srow[12 + n];
  }
  __syncthreads();
  for (int e = tid; e < 768; e += 256) {
    int n = e >> 6, w2 = e & 63;
    float s = 0.f, sh = 0.f;
    for (int hh = 0; hh < 64; ++hh) {
      float f = fy[n][hh];
      s  = fmaf(f, X[hh][w2], s);
      sh = fmaf(f, Xh[hh][w2], sh);
    }
    tmp[n][w2] = s; tmph[n][w2] = sh;
  }
  __syncthreads();
  if (tid < 144) {
    int n = tid / 12, m = tid % 12;
    float s = 0.f, sh = 0.f;
    for (int w2 = 0; w2 < 64; ++w2) {
      float f = fx[m][w2];
      s  = fmaf(tmp[n][w2], f, s);
      sh = fmaf(tmph[n][w2], f, sh);
    }
    float v0 = gam * s, v1 = gam * sh;
    size_t i0 = (size_t)b * 320 + n * 12 + m;   // lda 320 (zero-padded to BK=64)
    size_t i1 = i0 + 144;
    ushort_t h0, l0, h1, l1;
    splitf(v0, h0, l0); splitf(v1, h1, l1);
    rH[i0] = h0; rL[i0] = l0;
    rH[i1] = h1; rL[i1] = l1;
  }
}

// ---------------- z = mu + sig*eps (inline threefry RNG) ----------------
__global__ __launch_bounds__(256) void k_z(const float* __restrict__ stats,
                                           ushort_t* __restrict__ zH,
                                           ushort_t* __restrict__ zL,
                                           float* __restrict__ out_mu,
                                           float* __restrict__ out_sg, int t) {
  int i = blockIdx.x * 256 + threadIdx.x;  // < 65536
  int b = i >> 7, zi = i & 127;
  uint32_t kA, kB, o0, o1;
  threefry(0u, 42u, 0u, (uint32_t)t, kA, kB);          // split(key(42),32)[t]
  threefry(kA, kB, 0u, (uint32_t)i, o0, o1);           // random_bits
  float ep = bits_to_normal(o0 ^ o1);
  float mu = stats[(size_t)b * 256 + zi];
  float sg = expf(stats[(size_t)b * 256 + 128 + zi]);
  float zv = mu + sg * ep;
  ushort_t zh, zl;
  splitf(zv, zh, zl);
  zH[i] = zh; zL[i] = zl;
  out_mu[(size_t)b * 4096 + zi * 32 + t] = mu;
  out_sg[(size_t)b * 4096 + zi * 32 + t] = sg;
}

// ---------------- write: filterbank from precomputed wva + canvas update ----------------
__global__ __launch_bounds__(256) void k_fwrite(
    float* __restrict__ c, const float* __restrict__ wva) {
  int b = blockIdx.x;
  __shared__ float wsm[12][12];
  __shared__ float a_sh[5];
  __shared__ float fx[12][64], fy[12][64];
  __shared__ float srow[24];
  __shared__ float tmp[12][64];
  int tid = threadIdx.x;
  if (tid < 144) wsm[tid / 12][tid % 12] = wva[(size_t)b * 176 + tid];
  else if (tid < 149) a_sh[tid - 144] = wva[(size_t)b * 176 + tid];
  __syncthreads();
  float gx = 32.5f * (a_sh[0] + 1.f);
  float gy = 32.5f * (a_sh[1] + 1.f);
  float i2v = 0.5f * expf(-a_sh[2]);
  float delta = (63.f / 11.f) * expf(a_sh[3]);
  float gam = expf(-a_sh[4]);
  for (int e = tid; e < 768; e += 256) {
    int n = e >> 6, p = e & 63;
    float mu_x = gx + ((float)n - 5.5f) * delta;
    float mu_y = gy + ((float)n - 5.5f) * delta;
    float dx = (float)(p + 1) - mu_x;
    float dy = (float)(p + 1) - mu_y;
    fx[n][p] = expf(-i2v * dx * dx);
    fy[n][p] = expf(-i2v * dy * dy);
  }
  __syncthreads();
  if (tid < 24) {
    int n = tid % 12;
    float s = 0.f;
    if (tid < 12) { for (int p = 0; p < 64; ++p) s += fx[n][p]; }
    else          { for (int p = 0; p < 64; ++p) s += fy[n][p]; }
    srow[tid] = s + 6.4e-7f;
  }
  __syncthreads();
  for (int e = tid; e < 768; e += 256) {
    int n = e >> 6, p = e & 63;
    fx[n][p] /= srow[n];
    fy[n][p] /= srow[12 + n];
  }
  __syncthreads();
  for (int e = tid; e < 768; e += 256) {
    int n = e >> 6, w2 = e & 63;
    float s = 0.f;
#pragma unroll
    for (int m = 0; m < 12; ++m) s = fmaf(wsm[n][m], fx[m][w2], s);
    tmp[n][w2] = s;
  }
  __syncthreads();
  for (int e = tid; e < 4096; e += 256) {
    int hh = e >> 6, w2 = e & 63;
    float s = 0.f;
#pragma unroll
    for (int n = 0; n < 12; ++n) s = fmaf(fy[n][hh], tmp[n][w2], s);
    c[(size_t)b * 4096 + e] += gam * s;
  }
}

// ---------------- LSTM gates: reduce split-K halves + biases, split h ----------------
__global__ __launch_bounds__(256) void k_lstm(const float* __restrict__ g0,
                                              const float* __restrict__ g1,
                                              const float* __restrict__ bih,
                                              const float* __restrict__ bhh,
                                              float* __restrict__ cst,
                                              ushort_t* __restrict__ hH,
                                              ushort_t* __restrict__ hL) {
  int i = blockIdx.x * 256 + threadIdx.x;
  int b = i >> 10, u = i & 1023;
  size_t base = (size_t)b * 4096;
  float ig = g0[base + u]        + g1[base + u]        + bih[u]        + bhh[u];
  float fg = g0[base + 1024 + u] + g1[base + 1024 + u] + bih[1024 + u] + bhh[1024 + u];
  float gg = g0[base + 2048 + u] + g1[base + 2048 + u] + bih[2048 + u] + bhh[2048 + u];
  float og = g0[base + 3072 + u] + g1[base + 3072 + u] + bih[3072 + u] + bhh[3072 + u];
  float cv = sigf(fg) * cst[i] + sigf(ig) * tanhf(gg);
  cst[i] = cv;
  float hv = sigf(og) * tanhf(cv);
  ushort_t hh, hl;
  splitf(hv, hh, hl);
  hH[i] = hh; hL[i] = hl;
}

// ---------------- host launch ----------------
extern "C" void kernel_launch(void* const* d_in, const int* in_sizes, int n_in,
                              void* d_out, int out_size, void* d_ws, size_t ws_size,
                              hipStream_t stream) {
  const float* x       = (const float*)d_in[0];
  const float* enc_Wih = (const float*)d_in[1];
  const float* enc_Whh = (const float*)d_in[2];
  const float* enc_bih = (const float*)d_in[3];
  const float* enc_bhh = (const float*)d_in[4];
  const float* dec_Wih = (const float*)d_in[5];
  const float* dec_Whh = (const float*)d_in[6];
  const float* dec_bih = (const float*)d_in[7];
  const float* dec_bhh = (const float*)d_in[8];
  const float* zW  = (const float*)d_in[9];
  const float* zb  = (const float*)d_in[10];
  const float* wW  = (const float*)d_in[11];
  const float* wb  = (const float*)d_in[12];
  const float* raW = (const float*)d_in[13];
  const float* rab = (const float*)d_in[14];
  const float* waW = (const float*)d_in[15];
  const float* wab = (const float*)d_in[16];

  float* out = (float*)d_out;
  float* c      = out;
  float* out_mu = out + 2097152;
  float* out_sg = out + 4194304;

  // ---- workspace layout (bytes, 256-aligned) ----
  char* base = (char*)d_ws;
  size_t off = 0;
  auto alloc = [&](size_t bytes) -> char* {
    char* p = base + off;
    off = (off + bytes + 255) & ~(size_t)255;
    return p;
  };
  // zero-block (contiguous, first)
  float* c_enc = (float*)alloc(2097152);
  float* c_dec = (float*)alloc(2097152);
  ushort_t* hdH = (ushort_t*)alloc(1048576);
  ushort_t* hdL = (ushort_t*)alloc(1048576);
  ushort_t* heH = (ushort_t*)alloc(1048576);
  ushort_t* heL = (ushort_t*)alloc(1048576);
  ushort_t* rH  = (ushort_t*)alloc(327680);   // 512 x 320 (cols 288..319 stay zero)
  ushort_t* rL  = (ushort_t*)alloc(327680);
  ushort_t* cWH = (ushort_t*)alloc(360448);   // 176 x 1024 (rows 154..175 stay zero)
  ushort_t* cWL = (ushort_t*)alloc(360448);
  float* wva    = (float*)alloc(360448);      // 512 x 176 (zero for t=0 fread)
  size_t zero_bytes = off;
  // per-step buffers
  ushort_t* zH = (ushort_t*)alloc(131072);
  ushort_t* zL = (ushort_t*)alloc(131072);
  float* gbuf  = (float*)alloc(16777216);     // 2 x 512 x 4096 (split-K halves)
  float* stats = (float*)alloc(524288);
  float* cb    = (float*)alloc(704);          // 176 combined bias
  // weight splits (bf16 hi/lo)
  ushort_t* eWihH = (ushort_t*)alloc(10747904);
  ushort_t* eWihL = (ushort_t*)alloc(10747904);
  ushort_t* eWhhH = (ushort_t*)alloc(8388608);
  ushort_t* eWhhL = (ushort_t*)alloc(8388608);
  ushort_t* dWihH = (ushort_t*)alloc(1048576);
  ushort_t* dWihL = (ushort_t*)alloc(1048576);
  ushort_t* dWhhH = (ushort_t*)alloc(8388608);
  ushort_t* dWhhL = (ushort_t*)alloc(8388608);
  ushort_t* zWH   = (ushort_t*)alloc(524288);
  ushort_t* zWL   = (ushort_t*)alloc(524288);

  hipMemsetAsync(c, 0, (size_t)2097152 * sizeof(float), stream);
  hipMemsetAsync(base, 0, zero_bytes, stream);

  // split weights once per launch
  k_split<<<(5373952 + 255) / 256, 256, 0, stream>>>(enc_Wih, eWihH, eWihL, 5373952);
  k_split<<<(4194304 + 255) / 256, 256, 0, stream>>>(enc_Whh, eWhhH, eWhhL, 4194304);
  k_split<<<(524288 + 255) / 256, 256, 0, stream>>>(dec_Wih, dWihH, dWihL, 524288);
  k_split<<<(4194304 + 255) / 256, 256, 0, stream>>>(dec_Whh, dWhhH, dWhhL, 4194304);
  k_split<<<(262144 + 255) / 256, 256, 0, stream>>>(zW, zWH, zWL, 262144);
  k_split<<<(147456 + 255) / 256, 256, 0, stream>>>(wW, cWH, cWL, 147456);
  k_split<<<(5120 + 255) / 256, 256, 0, stream>>>(waW, cWH + 147456, cWL + 147456, 5120);
  k_split<<<(5120 + 255) / 256, 256, 0, stream>>>(raW, cWH + 152576, cWL + 152576, 5120);
  k_catbias<<<1, 176, 0, stream>>>(wb, wab, cb);

  // enc split-K: part0 = 55 iters, part1 = 56 iters (seg5 split at K=512)
  SegList2 encS;
  encS.n[0] = 6;
  encS.s[0][0] = {rH,  eWihH,             320,  320, 1312};
  encS.s[0][1] = {rL,  eWihH,             320,  320, 1312};
  encS.s[0][2] = {rH,  eWihL,             320,  320, 1312};
  encS.s[0][3] = {hdH, eWihH + 288,       1024, 1024, 1312};
  encS.s[0][4] = {hdL, eWihH + 288,       1024, 1024, 1312};
  encS.s[0][5] = {hdH, eWihL + 288,       512,  1024, 1312};
  encS.n[1] = 4;
  encS.s[1][0] = {hdH + 512, eWihL + 288 + 512, 512, 1024, 1312};
  encS.s[1][1] = {heH, eWhhH,             1024, 1024, 1024};
  encS.s[1][2] = {heL, eWhhH,             1024, 1024, 1024};
  encS.s[1][3] = {heH, eWhhL,             1024, 1024, 1024};
  // dec split-K: 27 / 27 (seg4 split at K=320)
  SegList2 decS;
  decS.n[0] = 5;
  decS.s[0][0] = {zH,  dWihH, 128,  128, 128};
  decS.s[0][1] = {zL,  dWihH, 128,  128, 128};
  decS.s[0][2] = {zH,  dWihL, 128,  128, 128};
  decS.s[0][3] = {hdH, dWhhH, 1024, 1024, 1024};
  decS.s[0][4] = {hdL, dWhhH, 320,  1024, 1024};
  decS.n[1] = 2;
  decS.s[1][0] = {hdL + 320, dWhhH + 320, 704, 1024, 1024};
  decS.s[1][1] = {hdH, dWhhL, 1024, 1024, 1024};
  // single-part lists (bias in-GEMM)
  SegList2 staS;
  staS.n[0] = 3; staS.n[1] = 0;
  staS.s[0][0] = {heH, zWH, 1024, 1024, 1024};
  staS.s[0][1] = {heL, zWH, 1024, 1024, 1024};
  staS.s[0][2] = {heH, zWL, 1024, 1024, 1024};
  SegList2 wvS;
  wvS.n[0] = 3; wvS.n[1] = 0;
  wvS.s[0][0] = {hdH, cWH, 1024, 1024, 1024};
  wvS.s[0][1] = {hdL, cWH, 1024, 1024, 1024};
  wvS.s[0][2] = {hdH, cWL, 1024, 1024, 1024};

  const unsigned GZ = 2097152;   // elements per split-K half of gbuf

  for (int t = 0; t < TT; ++t) {
    k_fread<<<512, 256, 0, stream>>>(x, c, wva, rab, rH, rL);
    mfma_gemm<<<dim3(32, 8, 2), 256, 0, stream>>>(gbuf, GZ, 4096, encS, nullptr, nullptr);
    k_lstm<<<2048, 256, 0, stream>>>(gbuf, gbuf + GZ, enc_bih, enc_bhh, c_enc, heH, heL);
    mfma_gemm<<<dim3(2, 8, 1), 256, 0, stream>>>(stats, 0, 256, staS, zb, nullptr);
    k_z<<<256, 256, 0, stream>>>(stats, zH, zL, out_mu, out_sg, t);
    mfma_gemm<<<dim3(32, 8, 2), 256, 0, stream>>>(gbuf, GZ, 4096, decS, nullptr, nullptr);
    k_lstm<<<2048, 256, 0, stream>>>(gbuf, gbuf + GZ, dec_bih, dec_bhh, c_dec, hdH, hdL);
    mfma_gemm<<<dim3(2, 8, 1), 256, 0, stream>>>(wva, 0, 176, wvS, cb, nullptr);
    k_fwrite<<<512, 256, 0, stream>>>(c, wva);
  }
}

// Round 13
// 4046.731 us; speedup vs baseline: 5.5640x; 1.6222x over previous
//
#include <hip/hip_runtime.h>
#include <cstdint>
#include <cstddef>

#define BB 512
#define TT 32
#define LL 1024
#define ZZ 128

typedef unsigned short ushort_t;
typedef __attribute__((ext_vector_type(8))) short s8v;    // 8 bf16 (4 VGPRs)
typedef __attribute__((ext_vector_type(4))) float f32x4;

// ---------------- math helpers ----------------
__device__ __forceinline__ float sigf(float x) { return 1.0f / (1.0f + expf(-x)); }

__device__ __forceinline__ ushort_t f2bf(float f) {
  uint32_t u = __float_as_uint(f);
  uint32_t r = (u + 0x7FFFu + ((u >> 16) & 1u)) >> 16;   // RNE
  return (ushort_t)r;
}
__device__ __forceinline__ float bf2f(ushort_t h) {
  return __uint_as_float(((uint32_t)h) << 16);
}
__device__ __forceinline__ void splitf(float v, ushort_t& hi, ushort_t& lo) {
  hi = f2bf(v);
  lo = f2bf(v - bf2f(hi));
}

// XLA ErfInv32 (Giles polynomial)
__device__ __forceinline__ float jax_erfinv(float x) {
  float w = -log1pf(-x * x);
  float p;
  if (w < 5.0f) {
    w = w - 2.5f;
    p = 2.81022636e-08f;
    p = fmaf(p, w, 3.43273939e-07f);
    p = fmaf(p, w, -3.5233877e-06f);
    p = fmaf(p, w, -4.39150654e-06f);
    p = fmaf(p, w, 0.00021858087f);
    p = fmaf(p, w, -0.00125372503f);
    p = fmaf(p, w, -0.00417768164f);
    p = fmaf(p, w, 0.246640727f);
    p = fmaf(p, w, 1.50140941f);
  } else {
    w = sqrtf(w) - 3.0f;
    p = -0.000200214257f;
    p = fmaf(p, w, 0.000100950558f);
    p = fmaf(p, w, 0.00134934322f);
    p = fmaf(p, w, -0.00367342844f);
    p = fmaf(p, w, 0.00573950773f);
    p = fmaf(p, w, -0.0076224613f);
    p = fmaf(p, w, 0.00943887047f);
    p = fmaf(p, w, 1.00167406f);
    p = fmaf(p, w, 2.83297682f);
  }
  return p * x;
}

// Threefry-2x32, 20 rounds (JAX schedule)
__device__ __forceinline__ void threefry(uint32_t k0, uint32_t k1,
                                         uint32_t x0, uint32_t x1,
                                         uint32_t& o0, uint32_t& o1) {
  uint32_t ks0 = k0, ks1 = k1, ks2 = k0 ^ k1 ^ 0x1BD11BDAu;
  x0 += ks0; x1 += ks1;
#define TF_ROT(x, d) (((x) << (d)) | ((x) >> (32 - (d))))
#define TF_RND(r) { x0 += x1; x1 = TF_ROT(x1, r); x1 ^= x0; }
  TF_RND(13) TF_RND(15) TF_RND(26) TF_RND(6)
  x0 += ks1; x1 += ks2 + 1u;
  TF_RND(17) TF_RND(29) TF_RND(16) TF_RND(24)
  x0 += ks2; x1 += ks0 + 2u;
  TF_RND(13) TF_RND(15) TF_RND(26) TF_RND(6)
  x0 += ks0; x1 += ks1 + 3u;
  TF_RND(17) TF_RND(29) TF_RND(16) TF_RND(24)
  x0 += ks1; x1 += ks2 + 4u;
  TF_RND(13) TF_RND(15) TF_RND(26) TF_RND(6)
  x0 += ks2; x1 += ks0 + 5u;
#undef TF_RND
#undef TF_ROT
  o0 = x0; o1 = x1;
}

__device__ __forceinline__ float bits_to_normal(uint32_t bits) {
  uint32_t fb = (bits >> 9) | 0x3f800000u;
  float f = __uint_as_float(fb) - 1.0f;
  const float lo = -0.99999994f;
  float u = fmaxf(lo, f * 2.0f + lo);
  return 1.41421356237f * jax_erfinv(u);
}

// ---------------- weight split: f32 -> bf16 hi/lo ----------------
__global__ __launch_bounds__(256) void k_split(const float* __restrict__ src,
                                               ushort_t* __restrict__ hi,
                                               ushort_t* __restrict__ lo, int n) {
  int i = blockIdx.x * 256 + threadIdx.x;
  if (i >= n) return;
  ushort_t h, l;
  splitf(src[i], h, l);
  hi[i] = h; lo[i] = l;
}

// combined bias for [wW | waW | raW] GEMM (raW rows get 0; fread adds rab itself)
__global__ void k_catbias(const float* __restrict__ wb, const float* __restrict__ wab,
                          float* __restrict__ cb) {
  int i = threadIdx.x;   // 176 threads
  cb[i] = (i < 144) ? wb[i] : (i < 149 ? wab[i - 144] : 0.f);
}

// ---------------- MFMA GEMM, 128x128 tile, iteration-range split-K ----------------
// 4 waves as 2x2; each wave computes 64x64 (4x4 16x16 frags). BK=64.
// blockIdx.z owns iterations [z*ipz, min((z+1)*ipz, T)) of the flattened BK-step
// space over all segments. Raw partial (no bias) written to C + z*zstride.
struct Seg { const ushort_t* A; const ushort_t* W; int K; int lda; int ldw; };
struct SegList { Seg s[9]; int n; };

__device__ __forceinline__ void load_tiles(const Seg& sg, int bm, int bn, int N, int k0,
                                           int tid, s8v va[4], s8v vw[4]) {
#pragma unroll
  for (int i = 0; i < 4; ++i) {
    int cch = tid + 256 * i;
    int row = cch >> 3, col = cch & 7;
    va[i] = *(const s8v*)(sg.A + (size_t)(bm + row) * sg.lda + k0 + col * 8);
    int n = bn + row;
    if (n < N) vw[i] = *(const s8v*)(sg.W + (size_t)n * sg.ldw + k0 + col * 8);
    else       vw[i] = (s8v)(short)0;
  }
}

__global__ __launch_bounds__(256, 2) void mfma_gemm(
    float* __restrict__ C, unsigned zstride, int N, SegList segs, int ipz, int T) {
  __shared__ __align__(16) ushort_t As[128][72];
  __shared__ __align__(16) ushort_t Ws[128][72];
  const int z = blockIdx.z;
  C += (size_t)z * zstride;
  const int bm = blockIdx.y * 128, bn = blockIdx.x * 128;
  const int tid = threadIdx.x;
  const int w = tid >> 6, lane = tid & 63;
  const int wr = w >> 1, wc = w & 1;               // wave grid 2(M) x 2(N)
  const int lr = lane & 15, lq = lane >> 4;
  f32x4 acc[4][4] = {};

  int it0 = z * ipz;
  int it1 = it0 + ipz; if (it1 > T) it1 = T;
  int iters = it1 - it0;
  if (iters > 0) {
    // walk to (si, k0) for it0
    int si = 0, rem = it0;
    while (rem >= (segs.s[si].K >> 6)) { rem -= segs.s[si].K >> 6; ++si; }
    int k0 = rem << 6;
    s8v va[4], vw[4];
    load_tiles(segs.s[si], bm, bn, N, k0, tid, va, vw);
    for (int it = 0; it < iters; ++it) {
      __syncthreads();
#pragma unroll
      for (int i = 0; i < 4; ++i) {
        int cch = tid + 256 * i;
        *(s8v*)&As[cch >> 3][(cch & 7) * 8] = va[i];
        *(s8v*)&Ws[cch >> 3][(cch & 7) * 8] = vw[i];
      }
      __syncthreads();
      int nsi = si, nk0 = k0 + 64;
      if (nk0 >= segs.s[si].K) { nk0 = 0; ++nsi; }
      if (it + 1 < iters) load_tiles(segs.s[nsi], bm, bn, N, nk0, tid, va, vw);
#pragma unroll
      for (int ks = 0; ks < 2; ++ks) {
        s8v af[4], bf[4];
#pragma unroll
        for (int m = 0; m < 4; ++m)
          af[m] = *(const s8v*)&As[wr * 64 + m * 16 + lr][ks * 32 + lq * 8];
#pragma unroll
        for (int j = 0; j < 4; ++j)
          bf[j] = *(const s8v*)&Ws[wc * 64 + j * 16 + lr][ks * 32 + lq * 8];
#pragma unroll
        for (int m = 0; m < 4; ++m)
#pragma unroll
          for (int j = 0; j < 4; ++j)
            acc[m][j] = __builtin_amdgcn_mfma_f32_16x16x32_bf16(af[m], bf[j], acc[m][j], 0, 0, 0);
      }
      si = nsi; k0 = nk0;
    }
  }
#pragma unroll
  for (int j = 0; j < 4; ++j) {
    int col = bn + wc * 64 + j * 16 + lr;
    if (col < N) {
#pragma unroll
      for (int m = 0; m < 4; ++m)
#pragma unroll
        for (int q = 0; q < 4; ++q) {
          int rr = bm + wr * 64 + m * 16 + lq * 4 + q;  // C/D: col=lane&15, row=(lane>>4)*4+q
          C[(size_t)rr * N + col] = acc[m][j][q];
        }
    }
  }
}

// ---------------- fused attn(read) + read einsums ----------------
// attn params come from ra5 (raW@h_dec computed by prev step's wv GEMM; 0 at t=0)
__global__ __launch_bounds__(256) void k_fread(
    const float* __restrict__ x, const float* __restrict__ c,
    const float* __restrict__ ra5, const float* __restrict__ rab,
    ushort_t* __restrict__ rH, ushort_t* __restrict__ rL) {
  int b = blockIdx.x;
  __shared__ float a_sh[5];
  __shared__ float fx[12][64], fy[12][64];
  __shared__ float srow[24];
  __shared__ float X[64][64];
  __shared__ float Xh[64][64];
  __shared__ float tmp[12][64], tmph[12][64];
  int tid = threadIdx.x;
  if (tid < 5) a_sh[tid] = ra5[b * 8 + tid] + rab[tid];
  for (int e = tid; e < 4096; e += 256) {
    float xv = x[(size_t)b * 4096 + e];
    float cv = c[(size_t)b * 4096 + e];
    X[e >> 6][e & 63] = xv;
    Xh[e >> 6][e & 63] = xv - sigf(cv);
  }
  __syncthreads();
  float gx = 32.5f * (a_sh[0] + 1.f);
  float gy = 32.5f * (a_sh[1] + 1.f);
  float i2v = 0.5f * expf(-a_sh[2]);
  float delta = (63.f / 11.f) * expf(a_sh[3]);
  float gam = expf(a_sh[4]);
  for (int e = tid; e < 768; e += 256) {
    int n = e >> 6, p = e & 63;
    float mu_x = gx + ((float)n - 5.5f) * delta;
    float mu_y = gy + ((float)n - 5.5f) * delta;
    float dx = (float)(p + 1) - mu_x;
    float dy = (float)(p + 1) - mu_y;
    fx[n][p] = expf(-i2v * dx * dx);
    fy[n][p] = expf(-i2v * dy * dy);
  }
  __syncthreads();
  if (tid < 24) {
    int n = tid % 12;
    float s = 0.f;
    if (tid < 12) { for (int p = 0; p < 64; ++p) s += fx[n][p]; }
    else          { for (int p = 0; p < 64; ++p) s += fy[n][p]; }
    srow[tid] = s + 6.4e-7f;   // sum(F + 1e-8) = sum(F) + 64e-8
  }
  __syncthreads();
  for (int e = tid; e < 768; e += 256) {
    int n = e >> 6, p = e & 63;
    fx[n][p] /= srow[n];
    fy[n][p] /= srow[12 + n];
  }
  __syncthreads();
  for (int e = tid; e < 768; e += 256) {
    int n = e >> 6, w2 = e & 63;
    float s = 0.f, sh = 0.f;
    for (int hh = 0; hh < 64; ++hh) {
      float f = fy[n][hh];
      s  = fmaf(f, X[hh][w2], s);
      sh = fmaf(f, Xh[hh][w2], sh);
    }
    tmp[n][w2] = s; tmph[n][w2] = sh;
  }
  __syncthreads();
  if (tid < 144) {
    int n = tid / 12, m = tid % 12;
    float s = 0.f, sh = 0.f;
    for (int w2 = 0; w2 < 64; ++w2) {
      float f = fx[m][w2];
      s  = fmaf(tmp[n][w2], f, s);
      sh = fmaf(tmph[n][w2], f, sh);
    }
    float v0 = gam * s, v1 = gam * sh;
    size_t i0 = (size_t)b * 320 + n * 12 + m;   // lda 320 (zero-padded to BK=64)
    size_t i1 = i0 + 144;
    ushort_t h0, l0, h1, l1;
    splitf(v0, h0, l0); splitf(v1, h1, l1);
    rH[i0] = h0; rL[i0] = l0;
    rH[i1] = h1; rL[i1] = l1;
  }
}

// ---------------- z = mu + sig*eps, reducing split-K parts + zb ----------------
__global__ __launch_bounds__(256) void k_z(const float* __restrict__ parts,
                                           unsigned SZ, int nz,
                                           const float* __restrict__ zb,
                                           ushort_t* __restrict__ zH,
                                           ushort_t* __restrict__ zL,
                                           float* __restrict__ out_mu,
                                           float* __restrict__ out_sg, int t) {
  int i = blockIdx.x * 256 + threadIdx.x;  // < 65536
  int b = i >> 7, zi = i & 127;
  float mu = zb[zi], ls = zb[128 + zi];
  for (int z = 0; z < nz; ++z) {
    size_t base = (size_t)z * SZ + (size_t)b * 256;
    mu += parts[base + zi];
    ls += parts[base + 128 + zi];
  }
  uint32_t kA, kB, o0, o1;
  threefry(0u, 42u, 0u, (uint32_t)t, kA, kB);          // split(key(42),32)[t]
  threefry(kA, kB, 0u, (uint32_t)i, o0, o1);           // random_bits
  float ep = bits_to_normal(o0 ^ o1);
  float sg = expf(ls);
  float zv = mu + sg * ep;
  ushort_t zh, zl;
  splitf(zv, zh, zl);
  zH[i] = zh; zL[i] = zl;
  out_mu[(size_t)b * 4096 + zi * 32 + t] = mu;
  out_sg[(size_t)b * 4096 + zi * 32 + t] = sg;
}

// ---------------- write: reduce wv parts + cb, filterbank, canvas update, export ra5 ----
__global__ __launch_bounds__(256) void k_fwrite(
    float* __restrict__ c, const float* __restrict__ parts, unsigned WZ, int nz,
    const float* __restrict__ cb, float* __restrict__ ra5) {
  int b = blockIdx.x;
  __shared__ float red[160];
  __shared__ float fx[12][64], fy[12][64];
  __shared__ float srow[24];
  __shared__ float tmp[12][64];
  int tid = threadIdx.x;
  if (tid < 154) {
    float s = cb[tid];
    for (int z = 0; z < nz; ++z) s += parts[(size_t)z * WZ + (size_t)b * 176 + tid];
    red[tid] = s;
    if (tid >= 149) ra5[b * 8 + tid - 149] = s;   // read-attn params for next step
  }
  __syncthreads();
  float gx = 32.5f * (red[144] + 1.f);
  float gy = 32.5f * (red[145] + 1.f);
  float i2v = 0.5f * expf(-red[146]);
  float delta = (63.f / 11.f) * expf(red[147]);
  float gam = expf(-red[148]);
  for (int e = tid; e < 768; e += 256) {
    int n = e >> 6, p = e & 63;
    float mu_x = gx + ((float)n - 5.5f) * delta;
    float mu_y = gy + ((float)n - 5.5f) * delta;
    float dx = (float)(p + 1) - mu_x;
    float dy = (float)(p + 1) - mu_y;
    fx[n][p] = expf(-i2v * dx * dx);
    fy[n][p] = expf(-i2v * dy * dy);
  }
  __syncthreads();
  if (tid < 24) {
    int n = tid % 12;
    float s = 0.f;
    if (tid < 12) { for (int p = 0; p < 64; ++p) s += fx[n][p]; }
    else          { for (int p = 0; p < 64; ++p) s += fy[n][p]; }
    srow[tid] = s + 6.4e-7f;
  }
  __syncthreads();
  for (int e = tid; e < 768; e += 256) {
    int n = e >> 6, p = e & 63;
    fx[n][p] /= srow[n];
    fy[n][p] /= srow[12 + n];
  }
  __syncthreads();
  for (int e = tid; e < 768; e += 256) {
    int n = e >> 6, w2 = e & 63;
    float s = 0.f;
#pragma unroll
    for (int m = 0; m < 12; ++m) s = fmaf(red[n * 12 + m], fx[m][w2], s);
    tmp[n][w2] = s;
  }
  __syncthreads();
  for (int e = tid; e < 4096; e += 256) {
    int hh = e >> 6, w2 = e & 63;
    float s = 0.f;
#pragma unroll
    for (int n = 0; n < 12; ++n) s = fmaf(fy[n][hh], tmp[n][w2], s);
    c[(size_t)b * 4096 + e] += gam * s;
  }
}

// ---------------- LSTM gates: reduce nz split-K parts + biases, split h ----------------
__global__ __launch_bounds__(256) void k_lstm(const float* __restrict__ g,
                                              unsigned GZ, int nz,
                                              const float* __restrict__ bih,
                                              const float* __restrict__ bhh,
                                              float* __restrict__ cst,
                                              ushort_t* __restrict__ hH,
                                              ushort_t* __restrict__ hL) {
  int i = blockIdx.x * 256 + threadIdx.x;
  int b = i >> 10, u = i & 1023;
  size_t base = (size_t)b * 4096;
  float ig = bih[u]        + bhh[u];
  float fg = bih[1024 + u] + bhh[1024 + u];
  float gg = bih[2048 + u] + bhh[2048 + u];
  float og = bih[3072 + u] + bhh[3072 + u];
  for (int z = 0; z < nz; ++z) {
    const float* gz = g + (size_t)z * GZ + base;
    ig += gz[u]; fg += gz[1024 + u]; gg += gz[2048 + u]; og += gz[3072 + u];
  }
  float cv = sigf(fg) * cst[i] + sigf(ig) * tanhf(gg);
  cst[i] = cv;
  float hv = sigf(og) * tanhf(cv);
  ushort_t hh, hl;
  splitf(hv, hh, hl);
  hH[i] = hh; hL[i] = hl;
}

// ---------------- host launch ----------------
extern "C" void kernel_launch(void* const* d_in, const int* in_sizes, int n_in,
                              void* d_out, int out_size, void* d_ws, size_t ws_size,
                              hipStream_t stream) {
  const float* x       = (const float*)d_in[0];
  const float* enc_Wih = (const float*)d_in[1];
  const float* enc_Whh = (const float*)d_in[2];
  const float* enc_bih = (const float*)d_in[3];
  const float* enc_bhh = (const float*)d_in[4];
  const float* dec_Wih = (const float*)d_in[5];
  const float* dec_Whh = (const float*)d_in[6];
  const float* dec_bih = (const float*)d_in[7];
  const float* dec_bhh = (const float*)d_in[8];
  const float* zW  = (const float*)d_in[9];
  const float* zb  = (const float*)d_in[10];
  const float* wW  = (const float*)d_in[11];
  const float* wb  = (const float*)d_in[12];
  const float* raW = (const float*)d_in[13];
  const float* rab = (const float*)d_in[14];
  const float* waW = (const float*)d_in[15];
  const float* wab = (const float*)d_in[16];

  float* out = (float*)d_out;
  float* c      = out;
  float* out_mu = out + 2097152;
  float* out_sg = out + 4194304;

  // ---- workspace layout: two-pass to pick NZ for the big GEMMs ----
  int NZ = 4;
  size_t need = 0;
  for (int pass = 0; pass < 2; ++pass) {
    size_t off = 0;
    auto sz = [&](size_t bytes) { off = (off + bytes + 255) & ~(size_t)255; };
    sz(2097152); sz(2097152);                       // c_enc, c_dec
    sz(1048576); sz(1048576); sz(1048576); sz(1048576); // hdH hdL heH heL
    sz(327680); sz(327680);                         // rH rL
    sz(360448); sz(360448);                         // cWH cWL
    sz(16384);                                      // ra5
    sz(131072); sz(131072);                         // zH zL
    sz((size_t)NZ * 8388608);                       // gbuf (also stats/wv parts)
    sz(704);                                        // cb
    sz(10747904); sz(10747904);                     // eWih
    sz(8388608); sz(8388608);                       // eWhh
    sz(1048576); sz(1048576);                       // dWih
    sz(8388608); sz(8388608);                       // dWhh
    sz(524288); sz(524288);                         // zW
    need = off;
    if (pass == 0 && ws_size < need) NZ = 2; else break;
  }

  char* base = (char*)d_ws;
  size_t off = 0;
  auto alloc = [&](size_t bytes) -> char* {
    char* p = base + off;
    off = (off + bytes + 255) & ~(size_t)255;
    return p;
  };
  // zero-block (contiguous, first)
  float* c_enc = (float*)alloc(2097152);
  float* c_dec = (float*)alloc(2097152);
  ushort_t* hdH = (ushort_t*)alloc(1048576);
  ushort_t* hdL = (ushort_t*)alloc(1048576);
  ushort_t* heH = (ushort_t*)alloc(1048576);
  ushort_t* heL = (ushort_t*)alloc(1048576);
  ushort_t* rH  = (ushort_t*)alloc(327680);   // 512 x 320 (cols 288..319 stay zero)
  ushort_t* rL  = (ushort_t*)alloc(327680);
  ushort_t* cWH = (ushort_t*)alloc(360448);   // 176 x 1024 (rows 154..175 stay zero)
  ushort_t* cWL = (ushort_t*)alloc(360448);
  float* ra5    = (float*)alloc(16384);       // 512 x 8, read-attn params (0 at t=0)
  size_t zero_bytes = off;
  // per-step buffers
  ushort_t* zH = (ushort_t*)alloc(131072);
  ushort_t* zL = (ushort_t*)alloc(131072);
  float* gbuf  = (float*)alloc((size_t)NZ * 8388608); // split-K parts; stats/wv alias
  float* cb    = (float*)alloc(704);          // 176 combined bias
  // weight splits (bf16 hi/lo)
  ushort_t* eWihH = (ushort_t*)alloc(10747904);
  ushort_t* eWihL = (ushort_t*)alloc(10747904);
  ushort_t* eWhhH = (ushort_t*)alloc(8388608);
  ushort_t* eWhhL = (ushort_t*)alloc(8388608);
  ushort_t* dWihH = (ushort_t*)alloc(1048576);
  ushort_t* dWihL = (ushort_t*)alloc(1048576);
  ushort_t* dWhhH = (ushort_t*)alloc(8388608);
  ushort_t* dWhhL = (ushort_t*)alloc(8388608);
  ushort_t* zWH   = (ushort_t*)alloc(524288);
  ushort_t* zWL   = (ushort_t*)alloc(524288);

  hipMemsetAsync(c, 0, (size_t)2097152 * sizeof(float), stream);
  hipMemsetAsync(base, 0, zero_bytes, stream);

  // split weights once per launch
  k_split<<<(5373952 + 255) / 256, 256, 0, stream>>>(enc_Wih, eWihH, eWihL, 5373952);
  k_split<<<(4194304 + 255) / 256, 256, 0, stream>>>(enc_Whh, eWhhH, eWhhL, 4194304);
  k_split<<<(524288 + 255) / 256, 256, 0, stream>>>(dec_Wih, dWihH, dWihL, 524288);
  k_split<<<(4194304 + 255) / 256, 256, 0, stream>>>(dec_Whh, dWhhH, dWhhL, 4194304);
  k_split<<<(262144 + 255) / 256, 256, 0, stream>>>(zW, zWH, zWL, 262144);
  k_split<<<(147456 + 255) / 256, 256, 0, stream>>>(wW, cWH, cWL, 147456);
  k_split<<<(5120 + 255) / 256, 256, 0, stream>>>(waW, cWH + 147456, cWL + 147456, 5120);
  k_split<<<(5120 + 255) / 256, 256, 0, stream>>>(raW, cWH + 152576, cWL + 152576, 5120);
  k_catbias<<<1, 176, 0, stream>>>(wb, wab, cb);

  SegList encS;   // T = 111
  encS.n = 9;
  encS.s[0] = {rH,  eWihH,       320,  320, 1312};
  encS.s[1] = {rL,  eWihH,       320,  320, 1312};
  encS.s[2] = {rH,  eWihL,       320,  320, 1312};
  encS.s[3] = {hdH, eWihH + 288, 1024, 1024, 1312};
  encS.s[4] = {hdL, eWihH + 288, 1024, 1024, 1312};
  encS.s[5] = {hdH, eWihL + 288, 1024, 1024, 1312};
  encS.s[6] = {heH, eWhhH,       1024, 1024, 1024};
  encS.s[7] = {heL, eWhhH,       1024, 1024, 1024};
  encS.s[8] = {heH, eWhhL,       1024, 1024, 1024};
  SegList decS;   // T = 54
  decS.n = 6;
  decS.s[0] = {zH,  dWihH, 128,  128, 128};
  decS.s[1] = {zL,  dWihH, 128,  128, 128};
  decS.s[2] = {zH,  dWihL, 128,  128, 128};
  decS.s[3] = {hdH, dWhhH, 1024, 1024, 1024};
  decS.s[4] = {hdL, dWhhH, 1024, 1024, 1024};
  decS.s[5] = {hdH, dWhhL, 1024, 1024, 1024};
  SegList staS;   // T = 48
  staS.n = 3;
  staS.s[0] = {heH, zWH, 1024, 1024, 1024};
  staS.s[1] = {heL, zWH, 1024, 1024, 1024};
  staS.s[2] = {heH, zWL, 1024, 1024, 1024};
  SegList wvS;    // T = 48
  wvS.n = 3;
  wvS.s[0] = {hdH, cWH, 1024, 1024, 1024};
  wvS.s[1] = {hdL, cWH, 1024, 1024, 1024};
  wvS.s[2] = {hdH, cWL, 1024, 1024, 1024};

  const unsigned GZ = 2097152;   // elements per part (512x4096)
  const unsigned SZ = 131072;    // 512x256
  const unsigned WZ = 90112;     // 512x176
  const int ipz_e = (111 + NZ - 1) / NZ;
  const int ipz_d = (54 + NZ - 1) / NZ;

  for (int t = 0; t < TT; ++t) {
    k_fread<<<512, 256, 0, stream>>>(x, c, ra5, rab, rH, rL);
    mfma_gemm<<<dim3(32, 4, NZ), 256, 0, stream>>>(gbuf, GZ, 4096, encS, ipz_e, 111);
    k_lstm<<<2048, 256, 0, stream>>>(gbuf, GZ, NZ, enc_bih, enc_bhh, c_enc, heH, heL);
    mfma_gemm<<<dim3(2, 4, 8), 256, 0, stream>>>(gbuf, SZ, 256, staS, 6, 48);
    k_z<<<256, 256, 0, stream>>>(gbuf, SZ, 8, zb, zH, zL, out_mu, out_sg, t);
    mfma_gemm<<<dim3(32, 4, NZ), 256, 0, stream>>>(gbuf, GZ, 4096, decS, ipz_d, 54);
    k_lstm<<<2048, 256, 0, stream>>>(gbuf, GZ, NZ, dec_bih, dec_bhh, c_dec, hdH, hdL);
    mfma_gemm<<<dim3(2, 4, 8), 256, 0, stream>>>(gbuf, WZ, 176, wvS, 6, 48);
    k_fwrite<<<512, 256, 0, stream>>>(c, gbuf, WZ, 8, cb, ra5);
  }
}

// Round 14
// 3917.523 us; speedup vs baseline: 5.7475x; 1.0330x over previous
//
#include <hip/hip_runtime.h>
#include <cstdint>
#include <cstddef>

#define BB 512
#define TT 32
#define LL 1024
#define ZZ 128

typedef unsigned short ushort_t;
typedef __attribute__((ext_vector_type(8))) short s8v;    // 8 bf16 (4 VGPRs)
typedef __attribute__((ext_vector_type(4))) float f32x4;

// ---------------- math helpers ----------------
__device__ __forceinline__ float sigf(float x) { return 1.0f / (1.0f + expf(-x)); }

__device__ __forceinline__ ushort_t f2bf(float f) {
  uint32_t u = __float_as_uint(f);
  uint32_t r = (u + 0x7FFFu + ((u >> 16) & 1u)) >> 16;   // RNE
  return (ushort_t)r;
}
__device__ __forceinline__ float bf2f(ushort_t h) {
  return __uint_as_float(((uint32_t)h) << 16);
}
__device__ __forceinline__ void splitf(float v, ushort_t& hi, ushort_t& lo) {
  hi = f2bf(v);
  lo = f2bf(v - bf2f(hi));
}

// XLA ErfInv32 (Giles polynomial)
__device__ __forceinline__ float jax_erfinv(float x) {
  float w = -log1pf(-x * x);
  float p;
  if (w < 5.0f) {
    w = w - 2.5f;
    p = 2.81022636e-08f;
    p = fmaf(p, w, 3.43273939e-07f);
    p = fmaf(p, w, -3.5233877e-06f);
    p = fmaf(p, w, -4.39150654e-06f);
    p = fmaf(p, w, 0.00021858087f);
    p = fmaf(p, w, -0.00125372503f);
    p = fmaf(p, w, -0.00417768164f);
    p = fmaf(p, w, 0.246640727f);
    p = fmaf(p, w, 1.50140941f);
  } else {
    w = sqrtf(w) - 3.0f;
    p = -0.000200214257f;
    p = fmaf(p, w, 0.000100950558f);
    p = fmaf(p, w, 0.00134934322f);
    p = fmaf(p, w, -0.00367342844f);
    p = fmaf(p, w, 0.00573950773f);
    p = fmaf(p, w, -0.0076224613f);
    p = fmaf(p, w, 0.00943887047f);
    p = fmaf(p, w, 1.00167406f);
    p = fmaf(p, w, 2.83297682f);
  }
  return p * x;
}

// Threefry-2x32, 20 rounds (JAX schedule)
__device__ __forceinline__ void threefry(uint32_t k0, uint32_t k1,
                                         uint32_t x0, uint32_t x1,
                                         uint32_t& o0, uint32_t& o1) {
  uint32_t ks0 = k0, ks1 = k1, ks2 = k0 ^ k1 ^ 0x1BD11BDAu;
  x0 += ks0; x1 += ks1;
#define TF_ROT(x, d) (((x) << (d)) | ((x) >> (32 - (d))))
#define TF_RND(r) { x0 += x1; x1 = TF_ROT(x1, r); x1 ^= x0; }
  TF_RND(13) TF_RND(15) TF_RND(26) TF_RND(6)
  x0 += ks1; x1 += ks2 + 1u;
  TF_RND(17) TF_RND(29) TF_RND(16) TF_RND(24)
  x0 += ks2; x1 += ks0 + 2u;
  TF_RND(13) TF_RND(15) TF_RND(26) TF_RND(6)
  x0 += ks0; x1 += ks1 + 3u;
  TF_RND(17) TF_RND(29) TF_RND(16) TF_RND(24)
  x0 += ks1; x1 += ks2 + 4u;
  TF_RND(13) TF_RND(15) TF_RND(26) TF_RND(6)
  x0 += ks2; x1 += ks0 + 5u;
#undef TF_RND
#undef TF_ROT
  o0 = x0; o1 = x1;
}

__device__ __forceinline__ float bits_to_normal(uint32_t bits) {
  uint32_t fb = (bits >> 9) | 0x3f800000u;
  float f = __uint_as_float(fb) - 1.0f;
  const float lo = -0.99999994f;
  float u = fmaxf(lo, f * 2.0f + lo);
  return 1.41421356237f * jax_erfinv(u);
}

// ---------------- weight split: f32 -> bf16 hi/lo ----------------
__global__ __launch_bounds__(256) void k_split(const float* __restrict__ src,
                                               ushort_t* __restrict__ hi,
                                               ushort_t* __restrict__ lo, int n) {
  int i = blockIdx.x * 256 + threadIdx.x;
  if (i >= n) return;
  ushort_t h, l;
  splitf(src[i], h, l);
  hi[i] = h; lo[i] = l;
}

// combined bias for [wW | waW | raW] GEMM (raW rows get 0; read adds rab itself)
__global__ void k_catbias(const float* __restrict__ wb, const float* __restrict__ wab,
                          float* __restrict__ cb) {
  int i = threadIdx.x;   // 176 threads
  cb[i] = (i < 144) ? wb[i] : (i < 149 ? wab[i - 144] : 0.f);
}

// ---------------- MFMA GEMM, 128x128 tile, iteration-range split-K ----------------
struct Seg { const ushort_t* A; const ushort_t* W; int K; int lda; int ldw; };
struct SegList { Seg s[9]; int n; };

__device__ __forceinline__ void load_tiles(const Seg& sg, int bm, int bn, int N, int k0,
                                           int tid, s8v va[4], s8v vw[4]) {
#pragma unroll
  for (int i = 0; i < 4; ++i) {
    int cch = tid + 256 * i;
    int row = cch >> 3, col = cch & 7;
    va[i] = *(const s8v*)(sg.A + (size_t)(bm + row) * sg.lda + k0 + col * 8);
    int n = bn + row;
    if (n < N) vw[i] = *(const s8v*)(sg.W + (size_t)n * sg.ldw + k0 + col * 8);
    else       vw[i] = (s8v)(short)0;
  }
}

__global__ __launch_bounds__(256, 2) void mfma_gemm(
    float* __restrict__ C, unsigned zstride, int N, SegList segs, int ipz, int T) {
  __shared__ __align__(16) ushort_t As[128][72];
  __shared__ __align__(16) ushort_t Ws[128][72];
  const int z = blockIdx.z;
  C += (size_t)z * zstride;
  const int bm = blockIdx.y * 128, bn = blockIdx.x * 128;
  const int tid = threadIdx.x;
  const int w = tid >> 6, lane = tid & 63;
  const int wr = w >> 1, wc = w & 1;               // wave grid 2(M) x 2(N)
  const int lr = lane & 15, lq = lane >> 4;
  f32x4 acc[4][4] = {};

  int it0 = z * ipz;
  int it1 = it0 + ipz; if (it1 > T) it1 = T;
  int iters = it1 - it0;
  if (iters > 0) {
    int si = 0, rem = it0;
    while (rem >= (segs.s[si].K >> 6)) { rem -= segs.s[si].K >> 6; ++si; }
    int k0 = rem << 6;
    s8v va[4], vw[4];
    load_tiles(segs.s[si], bm, bn, N, k0, tid, va, vw);
    for (int it = 0; it < iters; ++it) {
      __syncthreads();
#pragma unroll
      for (int i = 0; i < 4; ++i) {
        int cch = tid + 256 * i;
        *(s8v*)&As[cch >> 3][(cch & 7) * 8] = va[i];
        *(s8v*)&Ws[cch >> 3][(cch & 7) * 8] = vw[i];
      }
      __syncthreads();
      int nsi = si, nk0 = k0 + 64;
      if (nk0 >= segs.s[si].K) { nk0 = 0; ++nsi; }
      if (it + 1 < iters) load_tiles(segs.s[nsi], bm, bn, N, nk0, tid, va, vw);
#pragma unroll
      for (int ks = 0; ks < 2; ++ks) {
        s8v af[4], bf[4];
#pragma unroll
        for (int m = 0; m < 4; ++m)
          af[m] = *(const s8v*)&As[wr * 64 + m * 16 + lr][ks * 32 + lq * 8];
#pragma unroll
        for (int j = 0; j < 4; ++j)
          bf[j] = *(const s8v*)&Ws[wc * 64 + j * 16 + lr][ks * 32 + lq * 8];
#pragma unroll
        for (int m = 0; m < 4; ++m)
#pragma unroll
          for (int j = 0; j < 4; ++j)
            acc[m][j] = __builtin_amdgcn_mfma_f32_16x16x32_bf16(af[m], bf[j], acc[m][j], 0, 0, 0);
      }
      si = nsi; k0 = nk0;
    }
  }
#pragma unroll
  for (int j = 0; j < 4; ++j) {
    int col = bn + wc * 64 + j * 16 + lr;
    if (col < N) {
#pragma unroll
      for (int m = 0; m < 4; ++m)
#pragma unroll
        for (int q = 0; q < 4; ++q) {
          int rr = bm + wr * 64 + m * 16 + lq * 4 + q;  // C/D: col=lane&15, row=(lane>>4)*4+q
          C[(size_t)rr * N + col] = acc[m][j][q];
        }
    }
  }
}

// ---------------- t=0 read: attn params = rab, c = current canvas ----------------
__global__ __launch_bounds__(256) void k_fread(
    const float* __restrict__ x, const float* __restrict__ c,
    const float* __restrict__ rab,
    ushort_t* __restrict__ rH, ushort_t* __restrict__ rL) {
  int b = blockIdx.x;
  __shared__ float a_sh[5];
  __shared__ float fx[12][64], fy[12][64];
  __shared__ float srow[24];
  __shared__ float X[64][64];
  __shared__ float Xh[64][64];
  __shared__ float tmp[12][64], tmph[12][64];
  int tid = threadIdx.x;
  if (tid < 5) a_sh[tid] = rab[tid];
  for (int e = tid; e < 4096; e += 256) {
    float xv = x[(size_t)b * 4096 + e];
    float cv = c[(size_t)b * 4096 + e];
    X[e >> 6][e & 63] = xv;
    Xh[e >> 6][e & 63] = xv - sigf(cv);
  }
  __syncthreads();
  float gx = 32.5f * (a_sh[0] + 1.f);
  float gy = 32.5f * (a_sh[1] + 1.f);
  float i2v = 0.5f * expf(-a_sh[2]);
  float delta = (63.f / 11.f) * expf(a_sh[3]);
  float gam = expf(a_sh[4]);
  for (int e = tid; e < 768; e += 256) {
    int n = e >> 6, p = e & 63;
    float mu_x = gx + ((float)n - 5.5f) * delta;
    float mu_y = gy + ((float)n - 5.5f) * delta;
    float dx = (float)(p + 1) - mu_x;
    float dy = (float)(p + 1) - mu_y;
    fx[n][p] = expf(-i2v * dx * dx);
    fy[n][p] = expf(-i2v * dy * dy);
  }
  __syncthreads();
  if (tid < 24) {
    int n = tid % 12;
    float s = 0.f;
    if (tid < 12) { for (int p = 0; p < 64; ++p) s += fx[n][p]; }
    else          { for (int p = 0; p < 64; ++p) s += fy[n][p]; }
    srow[tid] = s + 6.4e-7f;   // sum(F + 1e-8) = sum(F) + 64e-8
  }
  __syncthreads();
  for (int e = tid; e < 768; e += 256) {
    int n = e >> 6, p = e & 63;
    fx[n][p] /= srow[n];
    fy[n][p] /= srow[12 + n];
  }
  __syncthreads();
  for (int e = tid; e < 768; e += 256) {
    int n = e >> 6, w2 = e & 63;
    float s = 0.f, sh = 0.f;
    for (int hh = 0; hh < 64; ++hh) {
      float f = fy[n][hh];
      s  = fmaf(f, X[hh][w2], s);
      sh = fmaf(f, Xh[hh][w2], sh);
    }
    tmp[n][w2] = s; tmph[n][w2] = sh;
  }
  __syncthreads();
  if (tid < 144) {
    int n = tid / 12, m = tid % 12;
    float s = 0.f, sh = 0.f;
    for (int w2 = 0; w2 < 64; ++w2) {
      float f = fx[m][w2];
      s  = fmaf(tmp[n][w2], f, s);
      sh = fmaf(tmph[n][w2], f, sh);
    }
    float v0 = gam * s, v1 = gam * sh;
    size_t i0 = (size_t)b * 320 + n * 12 + m;   // lda 320 (zero-padded to BK=64)
    size_t i1 = i0 + 144;
    ushort_t h0, l0, h1, l1;
    splitf(v0, h0, l0); splitf(v1, h1, l1);
    rH[i0] = h0; rL[i0] = l0;
    rH[i1] = h1; rL[i1] = l1;
  }
}

// ---------------- z = mu + sig*eps, reducing split-K parts + zb ----------------
__global__ __launch_bounds__(256) void k_z(const float* __restrict__ parts,
                                           unsigned SZ, int nz,
                                           const float* __restrict__ zb,
                                           ushort_t* __restrict__ zH,
                                           ushort_t* __restrict__ zL,
                                           float* __restrict__ out_mu,
                                           float* __restrict__ out_sg, int t) {
  int i = blockIdx.x * 256 + threadIdx.x;  // < 65536
  int b = i >> 7, zi = i & 127;
  float mu = zb[zi], ls = zb[128 + zi];
  for (int z = 0; z < nz; ++z) {
    size_t base = (size_t)z * SZ + (size_t)b * 256;
    mu += parts[base + zi];
    ls += parts[base + 128 + zi];
  }
  uint32_t kA, kB, o0, o1;
  threefry(0u, 42u, 0u, (uint32_t)t, kA, kB);          // split(key(42),32)[t]
  threefry(kA, kB, 0u, (uint32_t)i, o0, o1);           // random_bits
  float ep = bits_to_normal(o0 ^ o1);
  float sg = expf(ls);
  float zv = mu + sg * ep;
  ushort_t zh, zl;
  splitf(zv, zh, zl);
  zH[i] = zh; zL[i] = zl;
  out_mu[(size_t)b * 4096 + zi * 32 + t] = mu;
  out_sg[(size_t)b * 4096 + zi * 32 + t] = sg;
}

// ---------------- fused write(t) + read(t+1) ----------------
// Reduce wv parts + cb -> wsm & attn params; update canvas in-kernel; then
// (unless last) run the read-attention for the NEXT step using the fresh canvas.
__global__ __launch_bounds__(256) void k_fwr(
    float* __restrict__ c, const float* __restrict__ x,
    const float* __restrict__ parts, unsigned WZ, int nz,
    const float* __restrict__ cb, const float* __restrict__ rab,
    ushort_t* __restrict__ rH, ushort_t* __restrict__ rL, int last) {
  int b = blockIdx.x;
  __shared__ float red[160];
  __shared__ float a_sh[5];
  __shared__ float fx[12][64], fy[12][64];
  __shared__ float srow[24];
  __shared__ float tmp[12][64], tmph[12][64];
  __shared__ float X[64][64];
  __shared__ float Xh[64][64];
  int tid = threadIdx.x;
  // 1. reduce wv partials + combined bias
  if (tid < 154) {
    float s = cb[tid];
    for (int z = 0; z < nz; ++z) s += parts[(size_t)z * WZ + (size_t)b * 176 + tid];
    red[tid] = s;
  }
  __syncthreads();
  // 2. write filterbank
  {
    float gx = 32.5f * (red[144] + 1.f);
    float gy = 32.5f * (red[145] + 1.f);
    float i2v = 0.5f * expf(-red[146]);
    float delta = (63.f / 11.f) * expf(red[147]);
    for (int e = tid; e < 768; e += 256) {
      int n = e >> 6, p = e & 63;
      float mu_x = gx + ((float)n - 5.5f) * delta;
      float mu_y = gy + ((float)n - 5.5f) * delta;
      float dx = (float)(p + 1) - mu_x;
      float dy = (float)(p + 1) - mu_y;
      fx[n][p] = expf(-i2v * dx * dx);
      fy[n][p] = expf(-i2v * dy * dy);
    }
  }
  __syncthreads();
  if (tid < 24) {
    int n = tid % 12;
    float s = 0.f;
    if (tid < 12) { for (int p = 0; p < 64; ++p) s += fx[n][p]; }
    else          { for (int p = 0; p < 64; ++p) s += fy[n][p]; }
    srow[tid] = s + 6.4e-7f;
  }
  __syncthreads();
  for (int e = tid; e < 768; e += 256) {
    int n = e >> 6, p = e & 63;
    fx[n][p] /= srow[n];
    fy[n][p] /= srow[12 + n];
  }
  __syncthreads();
  // 3. tmp = wsm @ Fx
  for (int e = tid; e < 768; e += 256) {
    int n = e >> 6, w2 = e & 63;
    float s = 0.f;
#pragma unroll
    for (int m = 0; m < 12; ++m) s = fmaf(red[n * 12 + m], fx[m][w2], s);
    tmp[n][w2] = s;
  }
  __syncthreads();
  // 4. canvas update (write-through) + stage X / Xh for the next read
  {
    float gam = expf(-red[148]);
    for (int e = tid; e < 4096; e += 256) {
      int hh = e >> 6, w2 = e & 63;
      float s = 0.f;
#pragma unroll
      for (int n = 0; n < 12; ++n) s = fmaf(fy[n][hh], tmp[n][w2], s);
      float cv = c[(size_t)b * 4096 + e] + gam * s;
      c[(size_t)b * 4096 + e] = cv;
      float xv = x[(size_t)b * 4096 + e];
      X[hh][w2] = xv;
      Xh[hh][w2] = xv - sigf(cv);
    }
  }
  if (last) return;
  if (tid < 5) a_sh[tid] = red[149 + tid] + rab[tid];
  __syncthreads();
  // 5. read filterbank (read params)
  {
    float gx = 32.5f * (a_sh[0] + 1.f);
    float gy = 32.5f * (a_sh[1] + 1.f);
    float i2v = 0.5f * expf(-a_sh[2]);
    float delta = (63.f / 11.f) * expf(a_sh[3]);
    for (int e = tid; e < 768; e += 256) {
      int n = e >> 6, p = e & 63;
      float mu_x = gx + ((float)n - 5.5f) * delta;
      float mu_y = gy + ((float)n - 5.5f) * delta;
      float dx = (float)(p + 1) - mu_x;
      float dy = (float)(p + 1) - mu_y;
      fx[n][p] = expf(-i2v * dx * dx);
      fy[n][p] = expf(-i2v * dy * dy);
    }
  }
  __syncthreads();
  if (tid < 24) {
    int n = tid % 12;
    float s = 0.f;
    if (tid < 12) { for (int p = 0; p < 64; ++p) s += fx[n][p]; }
    else          { for (int p = 0; p < 64; ++p) s += fy[n][p]; }
    srow[tid] = s + 6.4e-7f;
  }
  __syncthreads();
  for (int e = tid; e < 768; e += 256) {
    int n = e >> 6, p = e & 63;
    fx[n][p] /= srow[n];
    fy[n][p] /= srow[12 + n];
  }
  __syncthreads();
  // 6. read einsums
  for (int e = tid; e < 768; e += 256) {
    int n = e >> 6, w2 = e & 63;
    float s = 0.f, sh = 0.f;
    for (int hh = 0; hh < 64; ++hh) {
      float f = fy[n][hh];
      s  = fmaf(f, X[hh][w2], s);
      sh = fmaf(f, Xh[hh][w2], sh);
    }
    tmp[n][w2] = s; tmph[n][w2] = sh;
  }
  __syncthreads();
  if (tid < 144) {
    float gam = expf(a_sh[4]);
    int n = tid / 12, m = tid % 12;
    float s = 0.f, sh = 0.f;
    for (int w2 = 0; w2 < 64; ++w2) {
      float f = fx[m][w2];
      s  = fmaf(tmp[n][w2], f, s);
      sh = fmaf(tmph[n][w2], f, sh);
    }
    float v0 = gam * s, v1 = gam * sh;
    size_t i0 = (size_t)b * 320 + n * 12 + m;
    size_t i1 = i0 + 144;
    ushort_t h0, l0, h1, l1;
    splitf(v0, h0, l0); splitf(v1, h1, l1);
    rH[i0] = h0; rL[i0] = l0;
    rH[i1] = h1; rL[i1] = l1;
  }
}

// ---------------- LSTM gates: float4, reduce nz split-K parts + biases ----------------
typedef unsigned short us4 __attribute__((ext_vector_type(4)));
__global__ __launch_bounds__(256) void k_lstm(const float* __restrict__ g,
                                              unsigned GZ, int nz,
                                              const float* __restrict__ bih,
                                              const float* __restrict__ bhh,
                                              float* __restrict__ cst,
                                              ushort_t* __restrict__ hH,
                                              ushort_t* __restrict__ hL) {
  int q = blockIdx.x * 256 + threadIdx.x;   // quad index < 131072
  int b = q >> 8, uq = q & 255;             // 256 quads of u per batch row
  size_t base = (size_t)b * 1024;           // float4 units per row = 4096/4
  float4 ig = *(const float4*)&bih[uq * 4];
  float4 fg = *(const float4*)&bih[1024 + uq * 4];
  float4 gg = *(const float4*)&bih[2048 + uq * 4];
  float4 og = *(const float4*)&bih[3072 + uq * 4];
  {
    float4 t0 = *(const float4*)&bhh[uq * 4];
    float4 t1 = *(const float4*)&bhh[1024 + uq * 4];
    float4 t2 = *(const float4*)&bhh[2048 + uq * 4];
    float4 t3 = *(const float4*)&bhh[3072 + uq * 4];
    ig.x += t0.x; ig.y += t0.y; ig.z += t0.z; ig.w += t0.w;
    fg.x += t1.x; fg.y += t1.y; fg.z += t1.z; fg.w += t1.w;
    gg.x += t2.x; gg.y += t2.y; gg.z += t2.z; gg.w += t2.w;
    og.x += t3.x; og.y += t3.y; og.z += t3.z; og.w += t3.w;
  }
  for (int z = 0; z < nz; ++z) {
    const float* gz = g + (size_t)z * GZ + base * 4;
    float4 t0 = *(const float4*)&gz[uq * 4];
    float4 t1 = *(const float4*)&gz[1024 + uq * 4];
    float4 t2 = *(const float4*)&gz[2048 + uq * 4];
    float4 t3 = *(const float4*)&gz[3072 + uq * 4];
    ig.x += t0.x; ig.y += t0.y; ig.z += t0.z; ig.w += t0.w;
    fg.x += t1.x; fg.y += t1.y; fg.z += t1.z; fg.w += t1.w;
    gg.x += t2.x; gg.y += t2.y; gg.z += t2.z; gg.w += t2.w;
    og.x += t3.x; og.y += t3.y; og.z += t3.z; og.w += t3.w;
  }
  float4 cv = *(const float4*)&cst[(size_t)q * 4];
  float cva[4] = {cv.x, cv.y, cv.z, cv.w};
  float iga[4] = {ig.x, ig.y, ig.z, ig.w};
  float fga[4] = {fg.x, fg.y, fg.z, fg.w};
  float gga[4] = {gg.x, gg.y, gg.z, gg.w};
  float oga[4] = {og.x, og.y, og.z, og.w};
  us4 hhv, hlv;
  float cvo[4];
#pragma unroll
  for (int j = 0; j < 4; ++j) {
    float cnew = sigf(fga[j]) * cva[j] + sigf(iga[j]) * tanhf(gga[j]);
    cvo[j] = cnew;
    float hv = sigf(oga[j]) * tanhf(cnew);
    ushort_t hh, hl;
    splitf(hv, hh, hl);
    hhv[j] = hh; hlv[j] = hl;
  }
  *(float4*)&cst[(size_t)q * 4] = make_float4(cvo[0], cvo[1], cvo[2], cvo[3]);
  *(us4*)&hH[(size_t)q * 4] = hhv;
  *(us4*)&hL[(size_t)q * 4] = hlv;
}

// ---------------- host launch ----------------
extern "C" void kernel_launch(void* const* d_in, const int* in_sizes, int n_in,
                              void* d_out, int out_size, void* d_ws, size_t ws_size,
                              hipStream_t stream) {
  const float* x       = (const float*)d_in[0];
  const float* enc_Wih = (const float*)d_in[1];
  const float* enc_Whh = (const float*)d_in[2];
  const float* enc_bih = (const float*)d_in[3];
  const float* enc_bhh = (const float*)d_in[4];
  const float* dec_Wih = (const float*)d_in[5];
  const float* dec_Whh = (const float*)d_in[6];
  const float* dec_bih = (const float*)d_in[7];
  const float* dec_bhh = (const float*)d_in[8];
  const float* zW  = (const float*)d_in[9];
  const float* zb  = (const float*)d_in[10];
  const float* wW  = (const float*)d_in[11];
  const float* wb  = (const float*)d_in[12];
  const float* raW = (const float*)d_in[13];
  const float* rab = (const float*)d_in[14];
  const float* waW = (const float*)d_in[15];
  const float* wab = (const float*)d_in[16];

  float* out = (float*)d_out;
  float* c      = out;
  float* out_mu = out + 2097152;
  float* out_sg = out + 4194304;

  // ---- workspace layout: two-pass to pick NZ for the big GEMMs ----
  int NZ = 4;
  size_t need = 0;
  for (int pass = 0; pass < 2; ++pass) {
    size_t off = 0;
    auto sz = [&](size_t bytes) { off = (off + bytes + 255) & ~(size_t)255; };
    sz(2097152); sz(2097152);
    sz(1048576); sz(1048576); sz(1048576); sz(1048576);
    sz(327680); sz(327680);
    sz(360448); sz(360448);
    sz(131072); sz(131072);
    sz((size_t)NZ * 8388608);
    sz(704);
    sz(10747904); sz(10747904);
    sz(8388608); sz(8388608);
    sz(1048576); sz(1048576);
    sz(8388608); sz(8388608);
    sz(524288); sz(524288);
    need = off;
    if (pass == 0 && ws_size < need) NZ = 2; else break;
  }

  char* base = (char*)d_ws;
  size_t off = 0;
  auto alloc = [&](size_t bytes) -> char* {
    char* p = base + off;
    off = (off + bytes + 255) & ~(size_t)255;
    return p;
  };
  // zero-block (contiguous, first)
  float* c_enc = (float*)alloc(2097152);
  float* c_dec = (float*)alloc(2097152);
  ushort_t* hdH = (ushort_t*)alloc(1048576);
  ushort_t* hdL = (ushort_t*)alloc(1048576);
  ushort_t* heH = (ushort_t*)alloc(1048576);
  ushort_t* heL = (ushort_t*)alloc(1048576);
  ushort_t* rH  = (ushort_t*)alloc(327680);   // 512 x 320 (cols 288..319 stay zero)
  ushort_t* rL  = (ushort_t*)alloc(327680);
  ushort_t* cWH = (ushort_t*)alloc(360448);   // 176 x 1024 (rows 154..175 stay zero)
  ushort_t* cWL = (ushort_t*)alloc(360448);
  size_t zero_bytes = off;
  // per-step buffers
  ushort_t* zH = (ushort_t*)alloc(131072);
  ushort_t* zL = (ushort_t*)alloc(131072);
  float* gbuf  = (float*)alloc((size_t)NZ * 8388608); // split-K parts; stats/wv alias
  float* cb    = (float*)alloc(704);          // 176 combined bias
  // weight splits (bf16 hi/lo)
  ushort_t* eWihH = (ushort_t*)alloc(10747904);
  ushort_t* eWihL = (ushort_t*)alloc(10747904);
  ushort_t* eWhhH = (ushort_t*)alloc(8388608);
  ushort_t* eWhhL = (ushort_t*)alloc(8388608);
  ushort_t* dWihH = (ushort_t*)alloc(1048576);
  ushort_t* dWihL = (ushort_t*)alloc(1048576);
  ushort_t* dWhhH = (ushort_t*)alloc(8388608);
  ushort_t* dWhhL = (ushort_t*)alloc(8388608);
  ushort_t* zWH   = (ushort_t*)alloc(524288);
  ushort_t* zWL   = (ushort_t*)alloc(524288);

  hipMemsetAsync(c, 0, (size_t)2097152 * sizeof(float), stream);
  hipMemsetAsync(base, 0, zero_bytes, stream);

  // split weights once per launch
  k_split<<<(5373952 + 255) / 256, 256, 0, stream>>>(enc_Wih, eWihH, eWihL, 5373952);
  k_split<<<(4194304 + 255) / 256, 256, 0, stream>>>(enc_Whh, eWhhH, eWhhL, 4194304);
  k_split<<<(524288 + 255) / 256, 256, 0, stream>>>(dec_Wih, dWihH, dWihL, 524288);
  k_split<<<(4194304 + 255) / 256, 256, 0, stream>>>(dec_Whh, dWhhH, dWhhL, 4194304);
  k_split<<<(262144 + 255) / 256, 256, 0, stream>>>(zW, zWH, zWL, 262144);
  k_split<<<(147456 + 255) / 256, 256, 0, stream>>>(wW, cWH, cWL, 147456);
  k_split<<<(5120 + 255) / 256, 256, 0, stream>>>(waW, cWH + 147456, cWL + 147456, 5120);
  k_split<<<(5120 + 255) / 256, 256, 0, stream>>>(raW, cWH + 152576, cWL + 152576, 5120);
  k_catbias<<<1, 176, 0, stream>>>(wb, wab, cb);

  SegList encS;   // T = 111
  encS.n = 9;
  encS.s[0] = {rH,  eWihH,       320,  320, 1312};
  encS.s[1] = {rL,  eWihH,       320,  320, 1312};
  encS.s[2] = {rH,  eWihL,       320,  320, 1312};
  encS.s[3] = {hdH, eWihH + 288, 1024, 1024, 1312};
  encS.s[4] = {hdL, eWihH + 288, 1024, 1024, 1312};
  encS.s[5] = {hdH, eWihL + 288, 1024, 1024, 1312};
  encS.s[6] = {heH, eWhhH,       1024, 1024, 1024};
  encS.s[7] = {heL, eWhhH,       1024, 1024, 1024};
  encS.s[8] = {heH, eWhhL,       1024, 1024, 1024};
  SegList decS;   // T = 54
  decS.n = 6;
  decS.s[0] = {zH,  dWihH, 128,  128, 128};
  decS.s[1] = {zL,  dWihH, 128,  128, 128};
  decS.s[2] = {zH,  dWihL, 128,  128, 128};
  decS.s[3] = {hdH, dWhhH, 1024, 1024, 1024};
  decS.s[4] = {hdL, dWhhH, 1024, 1024, 1024};
  decS.s[5] = {hdH, dWhhL, 1024, 1024, 1024};
  SegList staS;   // T = 48
  staS.n = 3;
  staS.s[0] = {heH, zWH, 1024, 1024, 1024};
  staS.s[1] = {heL, zWH, 1024, 1024, 1024};
  staS.s[2] = {heH, zWL, 1024, 1024, 1024};
  SegList wvS;    // T = 48
  wvS.n = 3;
  wvS.s[0] = {hdH, cWH, 1024, 1024, 1024};
  wvS.s[1] = {hdL, cWH, 1024, 1024, 1024};
  wvS.s[2] = {hdH, cWL, 1024, 1024, 1024};

  const unsigned GZ = 2097152;   // elements per part (512x4096)
  const unsigned SZ = 131072;    // 512x256
  const unsigned WZ = 90112;     // 512x176
  const int ipz_e = (111 + NZ - 1) / NZ;
  const int ipz_d = (54 + NZ - 1) / NZ;

  k_fread<<<512, 256, 0, stream>>>(x, c, rab, rH, rL);
  for (int t = 0; t < TT; ++t) {
    mfma_gemm<<<dim3(32, 4, NZ), 256, 0, stream>>>(gbuf, GZ, 4096, encS, ipz_e, 111);
    k_lstm<<<512, 256, 0, stream>>>(gbuf, GZ, NZ, enc_bih, enc_bhh, c_enc, heH, heL);
    mfma_gemm<<<dim3(2, 4, 8), 256, 0, stream>>>(gbuf, SZ, 256, staS, 6, 48);
    k_z<<<256, 256, 0, stream>>>(gbuf, SZ, 8, zb, zH, zL, out_mu, out_sg, t);
    mfma_gemm<<<dim3(32, 4, NZ), 256, 0, stream>>>(gbuf, GZ, 4096, decS, ipz_d, 54);
    k_lstm<<<512, 256, 0, stream>>>(gbuf, GZ, NZ, dec_bih, dec_bhh, c_dec, hdH, hdL);
    mfma_gemm<<<dim3(2, 4, 8), 256, 0, stream>>>(gbuf, WZ, 176, wvS, 6, 48);
    k_fwr<<<512, 256, 0, stream>>>(c, x, gbuf, WZ, 8, cb, rab, rH, rL, t == TT - 1);
  }
}

// Round 15
// 3763.154 us; speedup vs baseline: 5.9833x; 1.0410x over previous
//
#include <hip/hip_runtime.h>
#include <cstdint>
#include <cstddef>

#define BB 512
#define TT 32
#define LL 1024
#define ZZ 128

typedef unsigned short ushort_t;
typedef __attribute__((ext_vector_type(8))) short s8v;    // 8 bf16 (4 VGPRs)
typedef __attribute__((ext_vector_type(4))) float f32x4;

// ---------------- math helpers ----------------
__device__ __forceinline__ float sigf(float x) { return 1.0f / (1.0f + expf(-x)); }

__device__ __forceinline__ ushort_t f2bf(float f) {
  uint32_t u = __float_as_uint(f);
  uint32_t r = (u + 0x7FFFu + ((u >> 16) & 1u)) >> 16;   // RNE
  return (ushort_t)r;
}
__device__ __forceinline__ float bf2f(ushort_t h) {
  return __uint_as_float(((uint32_t)h) << 16);
}
__device__ __forceinline__ void splitf(float v, ushort_t& hi, ushort_t& lo) {
  hi = f2bf(v);
  lo = f2bf(v - bf2f(hi));
}

// XLA ErfInv32 (Giles polynomial)
__device__ __forceinline__ float jax_erfinv(float x) {
  float w = -log1pf(-x * x);
  float p;
  if (w < 5.0f) {
    w = w - 2.5f;
    p = 2.81022636e-08f;
    p = fmaf(p, w, 3.43273939e-07f);
    p = fmaf(p, w, -3.5233877e-06f);
    p = fmaf(p, w, -4.39150654e-06f);
    p = fmaf(p, w, 0.00021858087f);
    p = fmaf(p, w, -0.00125372503f);
    p = fmaf(p, w, -0.00417768164f);
    p = fmaf(p, w, 0.246640727f);
    p = fmaf(p, w, 1.50140941f);
  } else {
    w = sqrtf(w) - 3.0f;
    p = -0.000200214257f;
    p = fmaf(p, w, 0.000100950558f);
    p = fmaf(p, w, 0.00134934322f);
    p = fmaf(p, w, -0.00367342844f);
    p = fmaf(p, w, 0.00573950773f);
    p = fmaf(p, w, -0.0076224613f);
    p = fmaf(p, w, 0.00943887047f);
    p = fmaf(p, w, 1.00167406f);
    p = fmaf(p, w, 2.83297682f);
  }
  return p * x;
}

// Threefry-2x32, 20 rounds (JAX schedule)
__device__ __forceinline__ void threefry(uint32_t k0, uint32_t k1,
                                         uint32_t x0, uint32_t x1,
                                         uint32_t& o0, uint32_t& o1) {
  uint32_t ks0 = k0, ks1 = k1, ks2 = k0 ^ k1 ^ 0x1BD11BDAu;
  x0 += ks0; x1 += ks1;
#define TF_ROT(x, d) (((x) << (d)) | ((x) >> (32 - (d))))
#define TF_RND(r) { x0 += x1; x1 = TF_ROT(x1, r); x1 ^= x0; }
  TF_RND(13) TF_RND(15) TF_RND(26) TF_RND(6)
  x0 += ks1; x1 += ks2 + 1u;
  TF_RND(17) TF_RND(29) TF_RND(16) TF_RND(24)
  x0 += ks2; x1 += ks0 + 2u;
  TF_RND(13) TF_RND(15) TF_RND(26) TF_RND(6)
  x0 += ks0; x1 += ks1 + 3u;
  TF_RND(17) TF_RND(29) TF_RND(16) TF_RND(24)
  x0 += ks1; x1 += ks2 + 4u;
  TF_RND(13) TF_RND(15) TF_RND(26) TF_RND(6)
  x0 += ks2; x1 += ks0 + 5u;
#undef TF_RND
#undef TF_ROT
  o0 = x0; o1 = x1;
}

__device__ __forceinline__ float bits_to_normal(uint32_t bits) {
  uint32_t fb = (bits >> 9) | 0x3f800000u;
  float f = __uint_as_float(fb) - 1.0f;
  const float lo = -0.99999994f;
  float u = fmaxf(lo, f * 2.0f + lo);
  return 1.41421356237f * jax_erfinv(u);
}

// ---------------- weight split: f32 -> bf16 hi/lo ----------------
__global__ __launch_bounds__(256) void k_split(const float* __restrict__ src,
                                               ushort_t* __restrict__ hi,
                                               ushort_t* __restrict__ lo, int n) {
  int i = blockIdx.x * 256 + threadIdx.x;
  if (i >= n) return;
  ushort_t h, l;
  splitf(src[i], h, l);
  hi[i] = h; lo[i] = l;
}

// combined bias for [wW | waW | raW] GEMM (raW rows get 0; read adds rab itself)
__global__ void k_catbias(const float* __restrict__ wb, const float* __restrict__ wab,
                          float* __restrict__ cb) {
  int i = threadIdx.x;   // 176 threads
  cb[i] = (i < 144) ? wb[i] : (i < 149 ? wab[i - 144] : 0.f);
}

// ---------------- async global->LDS (width 16), swizzled source ----------------
__device__ __forceinline__ void gload16(const ushort_t* g, ushort_t* l) {
  __builtin_amdgcn_global_load_lds(
      (const __attribute__((address_space(1))) unsigned int*)g,
      (__attribute__((address_space(3))) unsigned int*)l, 16, 0, 0);
}

// ---------------- MFMA GEMM, 128x128 tile, iteration-range split-K ----------------
// Double-buffered LDS, global_load_lds staging, counted-vmcnt pipeline.
// LDS layout linear [128][64] bf16; XOR-swizzle (chunk ^= row&7) applied on the
// global SOURCE address and on the ds_read side (rule 21: both-sides-or-neither).
struct Seg { const ushort_t* A; const ushort_t* W; int K; int lda; int ldw; };
struct SegList { Seg s[9]; int n; };

__device__ __forceinline__ void issue_tile(const Seg& sg, int bm, int bn, int k0,
                                           int tid, ushort_t* Ab, ushort_t* Wb) {
  const int w = tid >> 6, lane = tid & 63;
  const int sub = lane >> 3;                       // 0..7 (= row&7 of the 8-row group)
  const int colE = (((lane & 7) ^ sub) << 3);      // pre-swizzled source col (elements)
#pragma unroll
  for (int i = 0; i < 4; ++i) {
    int row = w * 32 + i * 8 + sub;
    ushort_t* ldst = Ab + w * 2048 + i * 512;      // wave-uniform base (+lane*16B in HW)
    gload16(sg.A + (size_t)(bm + row) * sg.lda + k0 + colE, ldst);
    ushort_t* ldstw = Wb + w * 2048 + i * 512;
    gload16(sg.W + (size_t)(bn + row) * sg.ldw + k0 + colE, ldstw);
  }
}

__global__ __launch_bounds__(256, 2) void mfma_gemm(
    float* __restrict__ C, unsigned zstride, int N, SegList segs, int ipz, int T) {
  __shared__ __align__(16) ushort_t As[2][128][64];
  __shared__ __align__(16) ushort_t Ws[2][128][64];
  const int z = blockIdx.z;
  C += (size_t)z * zstride;
  const int bm = blockIdx.y * 128, bn = blockIdx.x * 128;
  const int tid = threadIdx.x;
  const int w = tid >> 6, lane = tid & 63;
  const int wr = w >> 1, wc = w & 1;               // wave grid 2(M) x 2(N)
  const int lr = lane & 15, lq = lane >> 4;
  const int swz = lr & 7;
  f32x4 acc[4][4] = {};

  int it0 = z * ipz;
  int it1 = it0 + ipz; if (it1 > T) it1 = T;
  int iters = it1 - it0;
  if (iters > 0) {
    int si = 0, rem = it0;
    while (rem >= (segs.s[si].K >> 6)) { rem -= segs.s[si].K >> 6; ++si; }
    int k0 = rem << 6;
    issue_tile(segs.s[si], bm, bn, k0, tid, &As[0][0][0], &Ws[0][0][0]);
    int cur = 0;
    for (int it = 0; it < iters; ++it) {
      int nsi = si, nk0 = k0 + 64;
      if (nk0 >= segs.s[si].K) { nk0 = 0; ++nsi; }
      const bool more = (it + 1 < iters);
      // barrier A: all waves done reading buf[cur^1]; ds_reads drained first.
      asm volatile("s_waitcnt lgkmcnt(0)" ::: "memory");
      __builtin_amdgcn_s_barrier();
      if (more) {
        issue_tile(segs.s[nsi], bm, bn, nk0, tid, &As[cur ^ 1][0][0], &Ws[cur ^ 1][0][0]);
        asm volatile("s_waitcnt vmcnt(8)" ::: "memory");   // buf[cur]'s 8 loads done
      } else {
        asm volatile("s_waitcnt vmcnt(0)" ::: "memory");
      }
      __builtin_amdgcn_s_barrier();   // barrier B: buf[cur] visible to all waves
#pragma unroll
      for (int ks = 0; ks < 2; ++ks) {
        s8v af[4], bf[4];
#pragma unroll
        for (int m = 0; m < 4; ++m) {
          int chunk = ((ks * 4 + lq) ^ swz) * 8;
          af[m] = *(const s8v*)&As[cur][wr * 64 + m * 16 + lr][chunk];
          bf[m] = *(const s8v*)&Ws[cur][wc * 64 + m * 16 + lr][chunk];
        }
#pragma unroll
        for (int m = 0; m < 4; ++m)
#pragma unroll
          for (int j = 0; j < 4; ++j)
            acc[m][j] = __builtin_amdgcn_mfma_f32_16x16x32_bf16(af[m], bf[j], acc[m][j], 0, 0, 0);
      }
      cur ^= 1; si = nsi; k0 = nk0;
    }
  }
#pragma unroll
  for (int j = 0; j < 4; ++j) {
    int col = bn + wc * 64 + j * 16 + lr;
    if (col < N) {
#pragma unroll
      for (int m = 0; m < 4; ++m)
#pragma unroll
        for (int q = 0; q < 4; ++q) {
          int rr = bm + wr * 64 + m * 16 + lq * 4 + q;  // C/D: col=lane&15, row=(lane>>4)*4+q
          C[(size_t)rr * N + col] = acc[m][j][q];
        }
    }
  }
}

// ---------------- t=0 read: attn params = rab, c = current canvas ----------------
__global__ __launch_bounds__(256) void k_fread(
    const float* __restrict__ x, const float* __restrict__ c,
    const float* __restrict__ rab,
    ushort_t* __restrict__ rH, ushort_t* __restrict__ rL) {
  int b = blockIdx.x;
  __shared__ float a_sh[5];
  __shared__ float fx[12][64], fy[12][64];
  __shared__ float srow[24];
  __shared__ float X[64][64];
  __shared__ float Xh[64][64];
  __shared__ float tmp[12][64], tmph[12][64];
  int tid = threadIdx.x;
  if (tid < 5) a_sh[tid] = rab[tid];
  for (int e = tid; e < 4096; e += 256) {
    float xv = x[(size_t)b * 4096 + e];
    float cv = c[(size_t)b * 4096 + e];
    X[e >> 6][e & 63] = xv;
    Xh[e >> 6][e & 63] = xv - sigf(cv);
  }
  __syncthreads();
  float gx = 32.5f * (a_sh[0] + 1.f);
  float gy = 32.5f * (a_sh[1] + 1.f);
  float i2v = 0.5f * expf(-a_sh[2]);
  float delta = (63.f / 11.f) * expf(a_sh[3]);
  float gam = expf(a_sh[4]);
  for (int e = tid; e < 768; e += 256) {
    int n = e >> 6, p = e & 63;
    float mu_x = gx + ((float)n - 5.5f) * delta;
    float mu_y = gy + ((float)n - 5.5f) * delta;
    float dx = (float)(p + 1) - mu_x;
    float dy = (float)(p + 1) - mu_y;
    fx[n][p] = expf(-i2v * dx * dx);
    fy[n][p] = expf(-i2v * dy * dy);
  }
  __syncthreads();
  if (tid < 24) {
    int n = tid % 12;
    float s = 0.f;
    if (tid < 12) { for (int p = 0; p < 64; ++p) s += fx[n][p]; }
    else          { for (int p = 0; p < 64; ++p) s += fy[n][p]; }
    srow[tid] = s + 6.4e-7f;   // sum(F + 1e-8) = sum(F) + 64e-8
  }
  __syncthreads();
  for (int e = tid; e < 768; e += 256) {
    int n = e >> 6, p = e & 63;
    fx[n][p] /= srow[n];
    fy[n][p] /= srow[12 + n];
  }
  __syncthreads();
  for (int e = tid; e < 768; e += 256) {
    int n = e >> 6, w2 = e & 63;
    float s = 0.f, sh = 0.f;
    for (int hh = 0; hh < 64; ++hh) {
      float f = fy[n][hh];
      s  = fmaf(f, X[hh][w2], s);
      sh = fmaf(f, Xh[hh][w2], sh);
    }
    tmp[n][w2] = s; tmph[n][w2] = sh;
  }
  __syncthreads();
  if (tid < 144) {
    int n = tid / 12, m = tid % 12;
    float s = 0.f, sh = 0.f;
    for (int w2 = 0; w2 < 64; ++w2) {
      float f = fx[m][w2];
      s  = fmaf(tmp[n][w2], f, s);
      sh = fmaf(tmph[n][w2], f, sh);
    }
    float v0 = gam * s, v1 = gam * sh;
    size_t i0 = (size_t)b * 320 + n * 12 + m;   // lda 320 (zero-padded to BK=64)
    size_t i1 = i0 + 144;
    ushort_t h0, l0, h1, l1;
    splitf(v0, h0, l0); splitf(v1, h1, l1);
    rH[i0] = h0; rL[i0] = l0;
    rH[i1] = h1; rL[i1] = l1;
  }
}

// ---------------- z = mu + sig*eps, reducing split-K parts + zb ----------------
__global__ __launch_bounds__(256) void k_z(const float* __restrict__ parts,
                                           unsigned SZ, int nz,
                                           const float* __restrict__ zb,
                                           ushort_t* __restrict__ zH,
                                           ushort_t* __restrict__ zL,
                                           float* __restrict__ out_mu,
                                           float* __restrict__ out_sg, int t) {
  int i = blockIdx.x * 256 + threadIdx.x;  // < 65536
  int b = i >> 7, zi = i & 127;
  float mu = zb[zi], ls = zb[128 + zi];
  for (int z = 0; z < nz; ++z) {
    size_t base = (size_t)z * SZ + (size_t)b * 256;
    mu += parts[base + zi];
    ls += parts[base + 128 + zi];
  }
  uint32_t kA, kB, o0, o1;
  threefry(0u, 42u, 0u, (uint32_t)t, kA, kB);          // split(key(42),32)[t]
  threefry(kA, kB, 0u, (uint32_t)i, o0, o1);           // random_bits
  float ep = bits_to_normal(o0 ^ o1);
  float sg = expf(ls);
  float zv = mu + sg * ep;
  ushort_t zh, zl;
  splitf(zv, zh, zl);
  zH[i] = zh; zL[i] = zl;
  out_mu[(size_t)b * 4096 + zi * 32 + t] = mu;
  out_sg[(size_t)b * 4096 + zi * 32 + t] = sg;
}

// ---------------- fused write(t) + read(t+1) ----------------
__global__ __launch_bounds__(256) void k_fwr(
    float* __restrict__ c, const float* __restrict__ x,
    const float* __restrict__ parts, unsigned WZ, int nz,
    const float* __restrict__ cb, const float* __restrict__ rab,
    ushort_t* __restrict__ rH, ushort_t* __restrict__ rL, int last) {
  int b = blockIdx.x;
  __shared__ float red[160];
  __shared__ float a_sh[5];
  __shared__ float fx[12][64], fy[12][64];
  __shared__ float srow[24];
  __shared__ float tmp[12][64], tmph[12][64];
  __shared__ float X[64][64];
  __shared__ float Xh[64][64];
  int tid = threadIdx.x;
  // 1. reduce wv partials + combined bias (parts row stride 256 now)
  if (tid < 154) {
    float s = cb[tid];
    for (int z = 0; z < nz; ++z) s += parts[(size_t)z * WZ + (size_t)b * 256 + tid];
    red[tid] = s;
  }
  __syncthreads();
  // 2. write filterbank
  {
    float gx = 32.5f * (red[144] + 1.f);
    float gy = 32.5f * (red[145] + 1.f);
    float i2v = 0.5f * expf(-red[146]);
    float delta = (63.f / 11.f) * expf(red[147]);
    for (int e = tid; e < 768; e += 256) {
      int n = e >> 6, p = e & 63;
      float mu_x = gx + ((float)n - 5.5f) * delta;
      float mu_y = gy + ((float)n - 5.5f) * delta;
      float dx = (float)(p + 1) - mu_x;
      float dy = (float)(p + 1) - mu_y;
      fx[n][p] = expf(-i2v * dx * dx);
      fy[n][p] = expf(-i2v * dy * dy);
    }
  }
  __syncthreads();
  if (tid < 24) {
    int n = tid % 12;
    float s = 0.f;
    if (tid < 12) { for (int p = 0; p < 64; ++p) s += fx[n][p]; }
    else          { for (int p = 0; p < 64; ++p) s += fy[n][p]; }
    srow[tid] = s + 6.4e-7f;
  }
  __syncthreads();
  for (int e = tid; e < 768; e += 256) {
    int n = e >> 6, p = e & 63;
    fx[n][p] /= srow[n];
    fy[n][p] /= srow[12 + n];
  }
  __syncthreads();
  // 3. tmp = wsm @ Fx
  for (int e = tid; e < 768; e += 256) {
    int n = e >> 6, w2 = e & 63;
    float s = 0.f;
#pragma unroll
    for (int m = 0; m < 12; ++m) s = fmaf(red[n * 12 + m], fx[m][w2], s);
    tmp[n][w2] = s;
  }
  __syncthreads();
  // 4. canvas update (write-through) + stage X / Xh for the next read
  {
    float gam = expf(-red[148]);
    for (int e = tid; e < 4096; e += 256) {
      int hh = e >> 6, w2 = e & 63;
      float s = 0.f;
#pragma unroll
      for (int n = 0; n < 12; ++n) s = fmaf(fy[n][hh], tmp[n][w2], s);
      float cv = c[(size_t)b * 4096 + e] + gam * s;
      c[(size_t)b * 4096 + e] = cv;
      float xv = x[(size_t)b * 4096 + e];
      X[hh][w2] = xv;
      Xh[hh][w2] = xv - sigf(cv);
    }
  }
  if (last) return;
  if (tid < 5) a_sh[tid] = red[149 + tid] + rab[tid];
  __syncthreads();
  // 5. read filterbank (read params)
  {
    float gx = 32.5f * (a_sh[0] + 1.f);
    float gy = 32.5f * (a_sh[1] + 1.f);
    float i2v = 0.5f * expf(-a_sh[2]);
    float delta = (63.f / 11.f) * expf(a_sh[3]);
    for (int e = tid; e < 768; e += 256) {
      int n = e >> 6, p = e & 63;
      float mu_x = gx + ((float)n - 5.5f) * delta;
      float mu_y = gy + ((float)n - 5.5f) * delta;
      float dx = (float)(p + 1) - mu_x;
      float dy = (float)(p + 1) - mu_y;
      fx[n][p] = expf(-i2v * dx * dx);
      fy[n][p] = expf(-i2v * dy * dy);
    }
  }
  __syncthreads();
  if (tid < 24) {
    int n = tid % 12;
    float s = 0.f;
    if (tid < 12) { for (int p = 0; p < 64; ++p) s += fx[n][p]; }
    else          { for (int p = 0; p < 64; ++p) s += fy[n][p]; }
    srow[tid] = s + 6.4e-7f;
  }
  __syncthreads();
  for (int e = tid; e < 768; e += 256) {
    int n = e >> 6, p = e & 63;
    fx[n][p] /= srow[n];
    fy[n][p] /= srow[12 + n];
  }
  __syncthreads();
  // 6. read einsums
  for (int e = tid; e < 768; e += 256) {
    int n = e >> 6, w2 = e & 63;
    float s = 0.f, sh = 0.f;
    for (int hh = 0; hh < 64; ++hh) {
      float f = fy[n][hh];
      s  = fmaf(f, X[hh][w2], s);
      sh = fmaf(f, Xh[hh][w2], sh);
    }
    tmp[n][w2] = s; tmph[n][w2] = sh;
  }
  __syncthreads();
  if (tid < 144) {
    float gam = expf(a_sh[4]);
    int n = tid / 12, m = tid % 12;
    float s = 0.f, sh = 0.f;
    for (int w2 = 0; w2 < 64; ++w2) {
      float f = fx[m][w2];
      s  = fmaf(tmp[n][w2], f, s);
      sh = fmaf(tmph[n][w2], f, sh);
    }
    float v0 = gam * s, v1 = gam * sh;
    size_t i0 = (size_t)b * 320 + n * 12 + m;
    size_t i1 = i0 + 144;
    ushort_t h0, l0, h1, l1;
    splitf(v0, h0, l0); splitf(v1, h1, l1);
    rH[i0] = h0; rL[i0] = l0;
    rH[i1] = h1; rL[i1] = l1;
  }
}

// ---------------- LSTM gates: float4, reduce nz split-K parts + biases ----------------
typedef unsigned short us4 __attribute__((ext_vector_type(4)));
__global__ __launch_bounds__(256) void k_lstm(const float* __restrict__ g,
                                              unsigned GZ, int nz,
                                              const float* __restrict__ bih,
                                              const float* __restrict__ bhh,
                                              float* __restrict__ cst,
                                              ushort_t* __restrict__ hH,
                                              ushort_t* __restrict__ hL) {
  int q = blockIdx.x * 256 + threadIdx.x;   // quad index < 131072
  int b = q >> 8, uq = q & 255;             // 256 quads of u per batch row
  size_t base = (size_t)b * 1024;           // float4 units per row = 4096/4
  float4 ig = *(const float4*)&bih[uq * 4];
  float4 fg = *(const float4*)&bih[1024 + uq * 4];
  float4 gg = *(const float4*)&bih[2048 + uq * 4];
  float4 og = *(const float4*)&bih[3072 + uq * 4];
  {
    float4 t0 = *(const float4*)&bhh[uq * 4];
    float4 t1 = *(const float4*)&bhh[1024 + uq * 4];
    float4 t2 = *(const float4*)&bhh[2048 + uq * 4];
    float4 t3 = *(const float4*)&bhh[3072 + uq * 4];
    ig.x += t0.x; ig.y += t0.y; ig.z += t0.z; ig.w += t0.w;
    fg.x += t1.x; fg.y += t1.y; fg.z += t1.z; fg.w += t1.w;
    gg.x += t2.x; gg.y += t2.y; gg.z += t2.z; gg.w += t2.w;
    og.x += t3.x; og.y += t3.y; og.z += t3.z; og.w += t3.w;
  }
  for (int z = 0; z < nz; ++z) {
    const float* gz = g + (size_t)z * GZ + base * 4;
    float4 t0 = *(const float4*)&gz[uq * 4];
    float4 t1 = *(const float4*)&gz[1024 + uq * 4];
    float4 t2 = *(const float4*)&gz[2048 + uq * 4];
    float4 t3 = *(const float4*)&gz[3072 + uq * 4];
    ig.x += t0.x; ig.y += t0.y; ig.z += t0.z; ig.w += t0.w;
    fg.x += t1.x; fg.y += t1.y; fg.z += t1.z; fg.w += t1.w;
    gg.x += t2.x; gg.y += t2.y; gg.z += t2.z; gg.w += t2.w;
    og.x += t3.x; og.y += t3.y; og.z += t3.z; og.w += t3.w;
  }
  float4 cv = *(const float4*)&cst[(size_t)q * 4];
  float cva[4] = {cv.x, cv.y, cv.z, cv.w};
  float iga[4] = {ig.x, ig.y, ig.z, ig.w};
  float fga[4] = {fg.x, fg.y, fg.z, fg.w};
  float gga[4] = {gg.x, gg.y, gg.z, gg.w};
  float oga[4] = {og.x, og.y, og.z, og.w};
  us4 hhv, hlv;
  float cvo[4];
#pragma unroll
  for (int j = 0; j < 4; ++j) {
    float cnew = sigf(fga[j]) * cva[j] + sigf(iga[j]) * tanhf(gga[j]);
    cvo[j] = cnew;
    float hv = sigf(oga[j]) * tanhf(cnew);
    ushort_t hh, hl;
    splitf(hv, hh, hl);
    hhv[j] = hh; hlv[j] = hl;
  }
  *(float4*)&cst[(size_t)q * 4] = make_float4(cvo[0], cvo[1], cvo[2], cvo[3]);
  *(us4*)&hH[(size_t)q * 4] = hhv;
  *(us4*)&hL[(size_t)q * 4] = hlv;
}

// ---------------- host launch ----------------
extern "C" void kernel_launch(void* const* d_in, const int* in_sizes, int n_in,
                              void* d_out, int out_size, void* d_ws, size_t ws_size,
                              hipStream_t stream) {
  const float* x       = (const float*)d_in[0];
  const float* enc_Wih = (const float*)d_in[1];
  const float* enc_Whh = (const float*)d_in[2];
  const float* enc_bih = (const float*)d_in[3];
  const float* enc_bhh = (const float*)d_in[4];
  const float* dec_Wih = (const float*)d_in[5];
  const float* dec_Whh = (const float*)d_in[6];
  const float* dec_bih = (const float*)d_in[7];
  const float* dec_bhh = (const float*)d_in[8];
  const float* zW  = (const float*)d_in[9];
  const float* zb  = (const float*)d_in[10];
  const float* wW  = (const float*)d_in[11];
  const float* wb  = (const float*)d_in[12];
  const float* raW = (const float*)d_in[13];
  const float* rab = (const float*)d_in[14];
  const float* waW = (const float*)d_in[15];
  const float* wab = (const float*)d_in[16];

  float* out = (float*)d_out;
  float* c      = out;
  float* out_mu = out + 2097152;
  float* out_sg = out + 4194304;

  // ---- workspace layout: two-pass to pick NZ for the big GEMMs ----
  int NZ = 4;
  size_t need = 0;
  for (int pass = 0; pass < 2; ++pass) {
    size_t off = 0;
    auto sz = [&](size_t bytes) { off = (off + bytes + 255) & ~(size_t)255; };
    sz(2097152); sz(2097152);
    sz(1048576); sz(1048576); sz(1048576); sz(1048576);
    sz(327680); sz(327680);
    sz(524288); sz(524288);                        // cW padded to 256 rows
    sz(131072); sz(131072);
    sz((size_t)NZ * 8388608);
    sz(704);
    sz(10747904); sz(10747904);
    sz(8388608); sz(8388608);
    sz(1048576); sz(1048576);
    sz(8388608); sz(8388608);
    sz(524288); sz(524288);
    need = off;
    if (pass == 0 && ws_size < need) NZ = 2; else break;
  }

  char* base = (char*)d_ws;
  size_t off = 0;
  auto alloc = [&](size_t bytes) -> char* {
    char* p = base + off;
    off = (off + bytes + 255) & ~(size_t)255;
    return p;
  };
  // zero-block (contiguous, first)
  float* c_enc = (float*)alloc(2097152);
  float* c_dec = (float*)alloc(2097152);
  ushort_t* hdH = (ushort_t*)alloc(1048576);
  ushort_t* hdL = (ushort_t*)alloc(1048576);
  ushort_t* heH = (ushort_t*)alloc(1048576);
  ushort_t* heL = (ushort_t*)alloc(1048576);
  ushort_t* rH  = (ushort_t*)alloc(327680);   // 512 x 320 (cols 288..319 stay zero)
  ushort_t* rL  = (ushort_t*)alloc(327680);
  ushort_t* cWH = (ushort_t*)alloc(524288);   // 256 x 1024 (rows 154..255 stay zero)
  ushort_t* cWL = (ushort_t*)alloc(524288);
  size_t zero_bytes = off;
  // per-step buffers
  ushort_t* zH = (ushort_t*)alloc(131072);
  ushort_t* zL = (ushort_t*)alloc(131072);
  float* gbuf  = (float*)alloc((size_t)NZ * 8388608); // split-K parts; stats/wv alias
  float* cb    = (float*)alloc(704);          // 176 combined bias
  // weight splits (bf16 hi/lo)
  ushort_t* eWihH = (ushort_t*)alloc(10747904);
  ushort_t* eWihL = (ushort_t*)alloc(10747904);
  ushort_t* eWhhH = (ushort_t*)alloc(8388608);
  ushort_t* eWhhL = (ushort_t*)alloc(8388608);
  ushort_t* dWihH = (ushort_t*)alloc(1048576);
  ushort_t* dWihL = (ushort_t*)alloc(1048576);
  ushort_t* dWhhH = (ushort_t*)alloc(8388608);
  ushort_t* dWhhL = (ushort_t*)alloc(8388608);
  ushort_t* zWH   = (ushort_t*)alloc(524288);
  ushort_t* zWL   = (ushort_t*)alloc(524288);

  hipMemsetAsync(c, 0, (size_t)2097152 * sizeof(float), stream);
  hipMemsetAsync(base, 0, zero_bytes, stream);

  // split weights once per launch
  k_split<<<(5373952 + 255) / 256, 256, 0, stream>>>(enc_Wih, eWihH, eWihL, 5373952);
  k_split<<<(4194304 + 255) / 256, 256, 0, stream>>>(enc_Whh, eWhhH, eWhhL, 4194304);
  k_split<<<(524288 + 255) / 256, 256, 0, stream>>>(dec_Wih, dWihH, dWihL, 524288);
  k_split<<<(4194304 + 255) / 256, 256, 0, stream>>>(dec_Whh, dWhhH, dWhhL, 4194304);
  k_split<<<(262144 + 255) / 256, 256, 0, stream>>>(zW, zWH, zWL, 262144);
  k_split<<<(147456 + 255) / 256, 256, 0, stream>>>(wW, cWH, cWL, 147456);
  k_split<<<(5120 + 255) / 256, 256, 0, stream>>>(waW, cWH + 147456, cWL + 147456, 5120);
  k_split<<<(5120 + 255) / 256, 256, 0, stream>>>(raW, cWH + 152576, cWL + 152576, 5120);
  k_catbias<<<1, 176, 0, stream>>>(wb, wab, cb);

  SegList encS;   // T = 111
  encS.n = 9;
  encS.s[0] = {rH,  eWihH,       320,  320, 1312};
  encS.s[1] = {rL,  eWihH,       320,  320, 1312};
  encS.s[2] = {rH,  eWihL,       320,  320, 1312};
  encS.s[3] = {hdH, eWihH + 288, 1024, 1024, 1312};
  encS.s[4] = {hdL, eWihH + 288, 1024, 1024, 1312};
  encS.s[5] = {hdH, eWihL + 288, 1024, 1024, 1312};
  encS.s[6] = {heH, eWhhH,       1024, 1024, 1024};
  encS.s[7] = {heL, eWhhH,       1024, 1024, 1024};
  encS.s[8] = {heH, eWhhL,       1024, 1024, 1024};
  SegList decS;   // T = 54
  decS.n = 6;
  decS.s[0] = {zH,  dWihH, 128,  128, 128};
  decS.s[1] = {zL,  dWihH, 128,  128, 128};
  decS.s[2] = {zH,  dWihL, 128,  128, 128};
  decS.s[3] = {hdH, dWhhH, 1024, 1024, 1024};
  decS.s[4] = {hdL, dWhhH, 1024, 1024, 1024};
  decS.s[5] = {hdH, dWhhL, 1024, 1024, 1024};
  SegList staS;   // T = 48
  staS.n = 3;
  staS.s[0] = {heH, zWH, 1024, 1024, 1024};
  staS.s[1] = {heL, zWH, 1024, 1024, 1024};
  staS.s[2] = {heH, zWL, 1024, 1024, 1024};
  SegList wvS;    // T = 48 (N padded to 256, rows 154..255 of cW are zero)
  wvS.n = 3;
  wvS.s[0] = {hdH, cWH, 1024, 1024, 1024};
  wvS.s[1] = {hdL, cWH, 1024, 1024, 1024};
  wvS.s[2] = {hdH, cWL, 1024, 1024, 1024};

  const unsigned GZ = 2097152;   // elements per part (512x4096)
  const unsigned SZ = 131072;    // 512x256
  const unsigned WZ = 131072;    // 512x256 (wv padded)
  const int ipz_e = (111 + NZ - 1) / NZ;
  const int ipz_d = (54 + NZ - 1) / NZ;

  k_fread<<<512, 256, 0, stream>>>(x, c, rab, rH, rL);
  for (int t = 0; t < TT; ++t) {
    mfma_gemm<<<dim3(32, 4, NZ), 256, 0, stream>>>(gbuf, GZ, 4096, encS, ipz_e, 111);
    k_lstm<<<512, 256, 0, stream>>>(gbuf, GZ, NZ, enc_bih, enc_bhh, c_enc, heH, heL);
    mfma_gemm<<<dim3(2, 4, 8), 256, 0, stream>>>(gbuf, SZ, 256, staS, 6, 48);
    k_z<<<256, 256, 0, stream>>>(gbuf, SZ, 8, zb, zH, zL, out_mu, out_sg, t);
    mfma_gemm<<<dim3(32, 4, NZ), 256, 0, stream>>>(gbuf, GZ, 4096, decS, ipz_d, 54);
    k_lstm<<<512, 256, 0, stream>>>(gbuf, GZ, NZ, dec_bih, dec_bhh, c_dec, hdH, hdL);
    mfma_gemm<<<dim3(2, 4, 8), 256, 0, stream>>>(gbuf, WZ, 256, wvS, 6, 48);
    k_fwr<<<512, 256, 0, stream>>>(c, x, gbuf, WZ, 8, cb, rab, rH, rL, t == TT - 1);
  }
}

// Round 18
// 3762.833 us; speedup vs baseline: 5.9838x; 1.0001x over previous
//
#include <hip/hip_runtime.h>
#include <cstdint>
#include <cstddef>

#define BB 512
#define TT 32
#define LL 1024
#define ZZ 128

typedef unsigned short ushort_t;
typedef __attribute__((ext_vector_type(8))) short s8v;    // 8 bf16 (4 VGPRs)
typedef __attribute__((ext_vector_type(4))) float f32x4;

// ---------------- math helpers ----------------
__device__ __forceinline__ float sigf(float x) { return 1.0f / (1.0f + expf(-x)); }

__device__ __forceinline__ ushort_t f2bf(float f) {
  uint32_t u = __float_as_uint(f);
  uint32_t r = (u + 0x7FFFu + ((u >> 16) & 1u)) >> 16;   // RNE
  return (ushort_t)r;
}
__device__ __forceinline__ float bf2f(ushort_t h) {
  return __uint_as_float(((uint32_t)h) << 16);
}
__device__ __forceinline__ void splitf(float v, ushort_t& hi, ushort_t& lo) {
  hi = f2bf(v);
  lo = f2bf(v - bf2f(hi));
}

// XLA ErfInv32 (Giles polynomial)
__device__ __forceinline__ float jax_erfinv(float x) {
  float w = -log1pf(-x * x);
  float p;
  if (w < 5.0f) {
    w = w - 2.5f;
    p = 2.81022636e-08f;
    p = fmaf(p, w, 3.43273939e-07f);
    p = fmaf(p, w, -3.5233877e-06f);
    p = fmaf(p, w, -4.39150654e-06f);
    p = fmaf(p, w, 0.00021858087f);
    p = fmaf(p, w, -0.00125372503f);
    p = fmaf(p, w, -0.00417768164f);
    p = fmaf(p, w, 0.246640727f);
    p = fmaf(p, w, 1.50140941f);
  } else {
    w = sqrtf(w) - 3.0f;
    p = -0.000200214257f;
    p = fmaf(p, w, 0.000100950558f);
    p = fmaf(p, w, 0.00134934322f);
    p = fmaf(p, w, -0.00367342844f);
    p = fmaf(p, w, 0.00573950773f);
    p = fmaf(p, w, -0.0076224613f);
    p = fmaf(p, w, 0.00943887047f);
    p = fmaf(p, w, 1.00167406f);
    p = fmaf(p, w, 2.83297682f);
  }
  return p * x;
}

// Threefry-2x32, 20 rounds (JAX schedule)
__device__ __forceinline__ void threefry(uint32_t k0, uint32_t k1,
                                         uint32_t x0, uint32_t x1,
                                         uint32_t& o0, uint32_t& o1) {
  uint32_t ks0 = k0, ks1 = k1, ks2 = k0 ^ k1 ^ 0x1BD11BDAu;
  x0 += ks0; x1 += ks1;
#define TF_ROT(x, d) (((x) << (d)) | ((x) >> (32 - (d))))
#define TF_RND(r) { x0 += x1; x1 = TF_ROT(x1, r); x1 ^= x0; }
  TF_RND(13) TF_RND(15) TF_RND(26) TF_RND(6)
  x0 += ks1; x1 += ks2 + 1u;
  TF_RND(17) TF_RND(29) TF_RND(16) TF_RND(24)
  x0 += ks2; x1 += ks0 + 2u;
  TF_RND(13) TF_RND(15) TF_RND(26) TF_RND(6)
  x0 += ks0; x1 += ks1 + 3u;
  TF_RND(17) TF_RND(29) TF_RND(16) TF_RND(24)
  x0 += ks1; x1 += ks2 + 4u;
  TF_RND(13) TF_RND(15) TF_RND(26) TF_RND(6)
  x0 += ks2; x1 += ks0 + 5u;
#undef TF_RND
#undef TF_ROT
  o0 = x0; o1 = x1;
}

__device__ __forceinline__ float bits_to_normal(uint32_t bits) {
  uint32_t fb = (bits >> 9) | 0x3f800000u;
  float f = __uint_as_float(fb) - 1.0f;
  const float lo = -0.99999994f;
  float u = fmaxf(lo, f * 2.0f + lo);
  return 1.41421356237f * jax_erfinv(u);
}

// ---------------- weight split: f32 -> bf16 hi/lo ----------------
__global__ __launch_bounds__(256) void k_split(const float* __restrict__ src,
                                               ushort_t* __restrict__ hi,
                                               ushort_t* __restrict__ lo, int n) {
  int i = blockIdx.x * 256 + threadIdx.x;
  if (i >= n) return;
  ushort_t h, l;
  splitf(src[i], h, l);
  hi[i] = h; lo[i] = l;
}

// combined bias for [wW | waW | raW] GEMM (raW rows get 0; read adds rab itself)
__global__ void k_catbias(const float* __restrict__ wb, const float* __restrict__ wab,
                          float* __restrict__ cb) {
  int i = threadIdx.x;   // 176 threads
  cb[i] = (i < 144) ? wb[i] : (i < 149 ? wab[i - 144] : 0.f);
}

// ---------------- async global->LDS (width 16), swizzled source ----------------
__device__ __forceinline__ void gload16(const ushort_t* g, ushort_t* l) {
  __builtin_amdgcn_global_load_lds(
      (const __attribute__((address_space(1))) unsigned int*)g,
      (__attribute__((address_space(3))) unsigned int*)l, 16, 0, 0);
}

// ---------------- MFMA GEMM, 128x128 tile, iteration-range split-K ----------------
// Double-buffered LDS, global_load_lds staging, counted-vmcnt pipeline.
// LDS layout linear [128][64] bf16; XOR-swizzle (chunk ^= row&7) applied on the
// global SOURCE address and on the ds_read side (rule 21: both-sides-or-neither).
struct Seg { const ushort_t* A; const ushort_t* W; int K; int lda; int ldw; };
struct SegList { Seg s[9]; int n; };

__device__ __forceinline__ void issue_tile(const Seg& sg, int bm, int bn, int k0,
                                           int tid, ushort_t* Ab, ushort_t* Wb) {
  const int w = tid >> 6, lane = tid & 63;
  const int sub = lane >> 3;                       // 0..7 (= row&7 of the 8-row group)
  const int colE = (((lane & 7) ^ sub) << 3);      // pre-swizzled source col (elements)
#pragma unroll
  for (int i = 0; i < 4; ++i) {
    int row = w * 32 + i * 8 + sub;
    ushort_t* ldst = Ab + w * 2048 + i * 512;      // wave-uniform base (+lane*16B in HW)
    gload16(sg.A + (size_t)(bm + row) * sg.lda + k0 + colE, ldst);
    ushort_t* ldstw = Wb + w * 2048 + i * 512;
    gload16(sg.W + (size_t)(bn + row) * sg.ldw + k0 + colE, ldstw);
  }
}

__global__ __launch_bounds__(256, 2) void mfma_gemm(
    float* __restrict__ C, unsigned zstride, int N, SegList segs, int ipz, int T) {
  __shared__ __align__(16) ushort_t As[2][128][64];
  __shared__ __align__(16) ushort_t Ws[2][128][64];
  const int z = blockIdx.z;
  C += (size_t)z * zstride;
  const int bm = blockIdx.y * 128, bn = blockIdx.x * 128;
  const int tid = threadIdx.x;
  const int w = tid >> 6, lane = tid & 63;
  const int wr = w >> 1, wc = w & 1;               // wave grid 2(M) x 2(N)
  const int lr = lane & 15, lq = lane >> 4;
  const int swz = lr & 7;
  f32x4 acc[4][4] = {};

  int it0 = z * ipz;
  int it1 = it0 + ipz; if (it1 > T) it1 = T;
  int iters = it1 - it0;
  if (iters > 0) {
    int si = 0, rem = it0;
    while (rem >= (segs.s[si].K >> 6)) { rem -= segs.s[si].K >> 6; ++si; }
    int k0 = rem << 6;
    issue_tile(segs.s[si], bm, bn, k0, tid, &As[0][0][0], &Ws[0][0][0]);
    int cur = 0;
    for (int it = 0; it < iters; ++it) {
      int nsi = si, nk0 = k0 + 64;
      if (nk0 >= segs.s[si].K) { nk0 = 0; ++nsi; }
      const bool more = (it + 1 < iters);
      // barrier A: all waves done reading buf[cur^1]; ds_reads drained first.
      asm volatile("s_waitcnt lgkmcnt(0)" ::: "memory");
      __builtin_amdgcn_s_barrier();
      if (more) {
        issue_tile(segs.s[nsi], bm, bn, nk0, tid, &As[cur ^ 1][0][0], &Ws[cur ^ 1][0][0]);
        asm volatile("s_waitcnt vmcnt(8)" ::: "memory");   // buf[cur]'s 8 loads done
      } else {
        asm volatile("s_waitcnt vmcnt(0)" ::: "memory");
      }
      __builtin_amdgcn_s_barrier();   // barrier B: buf[cur] visible to all waves
#pragma unroll
      for (int ks = 0; ks < 2; ++ks) {
        s8v af[4], bf[4];
#pragma unroll
        for (int m = 0; m < 4; ++m) {
          int chunk = ((ks * 4 + lq) ^ swz) * 8;
          af[m] = *(const s8v*)&As[cur][wr * 64 + m * 16 + lr][chunk];
          bf[m] = *(const s8v*)&Ws[cur][wc * 64 + m * 16 + lr][chunk];
        }
#pragma unroll
        for (int m = 0; m < 4; ++m)
#pragma unroll
          for (int j = 0; j < 4; ++j)
            acc[m][j] = __builtin_amdgcn_mfma_f32_16x16x32_bf16(af[m], bf[j], acc[m][j], 0, 0, 0);
      }
      cur ^= 1; si = nsi; k0 = nk0;
    }
  }
#pragma unroll
  for (int j = 0; j < 4; ++j) {
    int col = bn + wc * 64 + j * 16 + lr;
    if (col < N) {
#pragma unroll
      for (int m = 0; m < 4; ++m)
#pragma unroll
        for (int q = 0; q < 4; ++q) {
          int rr = bm + wr * 64 + m * 16 + lq * 4 + q;  // C/D: col=lane&15, row=(lane>>4)*4+q
          C[(size_t)rr * N + col] = acc[m][j][q];
        }
    }
  }
}

// ---------------- t=0 read: attn params = rab, c = current canvas ----------------
__global__ __launch_bounds__(256) void k_fread(
    const float* __restrict__ x, const float* __restrict__ c,
    const float* __restrict__ rab,
    ushort_t* __restrict__ rH, ushort_t* __restrict__ rL) {
  int b = blockIdx.x;
  __shared__ float a_sh[5];
  __shared__ float fx[12][64], fy[12][64];
  __shared__ float srow[24];
  __shared__ float X[64][64];
  __shared__ float Xh[64][64];
  __shared__ float tmp[12][64], tmph[12][64];
  int tid = threadIdx.x;
  if (tid < 5) a_sh[tid] = rab[tid];
  for (int e = tid; e < 4096; e += 256) {
    float xv = x[(size_t)b * 4096 + e];
    float cv = c[(size_t)b * 4096 + e];
    X[e >> 6][e & 63] = xv;
    Xh[e >> 6][e & 63] = xv - sigf(cv);
  }
  __syncthreads();
  float gx = 32.5f * (a_sh[0] + 1.f);
  float gy = 32.5f * (a_sh[1] + 1.f);
  float i2v = 0.5f * expf(-a_sh[2]);
  float delta = (63.f / 11.f) * expf(a_sh[3]);
  float gam = expf(a_sh[4]);
  for (int e = tid; e < 768; e += 256) {
    int n = e >> 6, p = e & 63;
    float mu_x = gx + ((float)n - 5.5f) * delta;
    float mu_y = gy + ((float)n - 5.5f) * delta;
    float dx = (float)(p + 1) - mu_x;
    float dy = (float)(p + 1) - mu_y;
    fx[n][p] = expf(-i2v * dx * dx);
    fy[n][p] = expf(-i2v * dy * dy);
  }
  __syncthreads();
  if (tid < 24) {
    int n = tid % 12;
    float s = 0.f;
    if (tid < 12) { for (int p = 0; p < 64; ++p) s += fx[n][p]; }
    else          { for (int p = 0; p < 64; ++p) s += fy[n][p]; }
    srow[tid] = s + 6.4e-7f;   // sum(F + 1e-8) = sum(F) + 64e-8
  }
  __syncthreads();
  for (int e = tid; e < 768; e += 256) {
    int n = e >> 6, p = e & 63;
    fx[n][p] /= srow[n];
    fy[n][p] /= srow[12 + n];
  }
  __syncthreads();
  for (int e = tid; e < 768; e += 256) {
    int n = e >> 6, w2 = e & 63;
    float s = 0.f, sh = 0.f;
    for (int hh = 0; hh < 64; ++hh) {
      float f = fy[n][hh];
      s  = fmaf(f, X[hh][w2], s);
      sh = fmaf(f, Xh[hh][w2], sh);
    }
    tmp[n][w2] = s; tmph[n][w2] = sh;
  }
  __syncthreads();
  if (tid < 144) {
    int n = tid / 12, m = tid % 12;
    float s = 0.f, sh = 0.f;
    for (int w2 = 0; w2 < 64; ++w2) {
      float f = fx[m][w2];
      s  = fmaf(tmp[n][w2], f, s);
      sh = fmaf(tmph[n][w2], f, sh);
    }
    float v0 = gam * s, v1 = gam * sh;
    size_t i0 = (size_t)b * 320 + n * 12 + m;   // lda 320 (zero-padded to BK=64)
    size_t i1 = i0 + 144;
    ushort_t h0, l0, h1, l1;
    splitf(v0, h0, l0); splitf(v1, h1, l1);
    rH[i0] = h0; rL[i0] = l0;
    rH[i1] = h1; rL[i1] = l1;
  }
}

// ---------------- z = mu + sig*eps, reducing split-K parts + zb ----------------
__global__ __launch_bounds__(256) void k_z(const float* __restrict__ parts,
                                           unsigned SZ, int nz,
                                           const float* __restrict__ zb,
                                           ushort_t* __restrict__ zH,
                                           ushort_t* __restrict__ zL,
                                           float* __restrict__ out_mu,
                                           float* __restrict__ out_sg, int t) {
  int i = blockIdx.x * 256 + threadIdx.x;  // < 65536
  int b = i >> 7, zi = i & 127;
  float mu = zb[zi], ls = zb[128 + zi];
  for (int z = 0; z < nz; ++z) {
    size_t base = (size_t)z * SZ + (size_t)b * 256;
    mu += parts[base + zi];
    ls += parts[base + 128 + zi];
  }
  uint32_t kA, kB, o0, o1;
  threefry(0u, 42u, 0u, (uint32_t)t, kA, kB);          // split(key(42),32)[t]
  threefry(kA, kB, 0u, (uint32_t)i, o0, o1);           // random_bits
  float ep = bits_to_normal(o0 ^ o1);
  float sg = expf(ls);
  float zv = mu + sg * ep;
  ushort_t zh, zl;
  splitf(zv, zh, zl);
  zH[i] = zh; zL[i] = zl;
  out_mu[(size_t)b * 4096 + zi * 32 + t] = mu;
  out_sg[(size_t)b * 4096 + zi * 32 + t] = sg;
}

// ---------------- fused write(t) + read(t+1) ----------------
__global__ __launch_bounds__(256) void k_fwr(
    float* __restrict__ c, const float* __restrict__ x,
    const float* __restrict__ parts, unsigned WZ, int nz,
    const float* __restrict__ cb, const float* __restrict__ rab,
    ushort_t* __restrict__ rH, ushort_t* __restrict__ rL, int last) {
  int b = blockIdx.x;
  __shared__ float red[160];
  __shared__ float a_sh[5];
  __shared__ float fx[12][64], fy[12][64];
  __shared__ float srow[24];
  __shared__ float tmp[12][64], tmph[12][64];
  __shared__ float X[64][64];
  __shared__ float Xh[64][64];
  int tid = threadIdx.x;
  // 1. reduce wv partials + combined bias (parts row stride 256)
  if (tid < 154) {
    float s = cb[tid];
    for (int z = 0; z < nz; ++z) s += parts[(size_t)z * WZ + (size_t)b * 256 + tid];
    red[tid] = s;
  }
  __syncthreads();
  // 2. write filterbank
  {
    float gx = 32.5f * (red[144] + 1.f);
    float gy = 32.5f * (red[145] + 1.f);
    float i2v = 0.5f * expf(-red[146]);
    float delta = (63.f / 11.f) * expf(red[147]);
    for (int e = tid; e < 768; e += 256) {
      int n = e >> 6, p = e & 63;
      float mu_x = gx + ((float)n - 5.5f) * delta;
      float mu_y = gy + ((float)n - 5.5f) * delta;
      float dx = (float)(p + 1) - mu_x;
      float dy = (float)(p + 1) - mu_y;
      fx[n][p] = expf(-i2v * dx * dx);
      fy[n][p] = expf(-i2v * dy * dy);
    }
  }
  __syncthreads();
  if (tid < 24) {
    int n = tid % 12;
    float s = 0.f;
    if (tid < 12) { for (int p = 0; p < 64; ++p) s += fx[n][p]; }
    else          { for (int p = 0; p < 64; ++p) s += fy[n][p]; }
    srow[tid] = s + 6.4e-7f;
  }
  __syncthreads();
  for (int e = tid; e < 768; e += 256) {
    int n = e >> 6, p = e & 63;
    fx[n][p] /= srow[n];
    fy[n][p] /= srow[12 + n];
  }
  __syncthreads();
  // 3. tmp = wsm @ Fx
  for (int e = tid; e < 768; e += 256) {
    int n = e >> 6, w2 = e & 63;
    float s = 0.f;
#pragma unroll
    for (int m = 0; m < 12; ++m) s = fmaf(red[n * 12 + m], fx[m][w2], s);
    tmp[n][w2] = s;
  }
  __syncthreads();
  // 4. canvas update (write-through) + stage X / Xh for the next read
  {
    float gam = expf(-red[148]);
    for (int e = tid; e < 4096; e += 256) {
      int hh = e >> 6, w2 = e & 63;
      float s = 0.f;
#pragma unroll
      for (int n = 0; n < 12; ++n) s = fmaf(fy[n][hh], tmp[n][w2], s);
      float cv = c[(size_t)b * 4096 + e] + gam * s;
      c[(size_t)b * 4096 + e] = cv;
      float xv = x[(size_t)b * 4096 + e];
      X[hh][w2] = xv;
      Xh[hh][w2] = xv - sigf(cv);
    }
  }
  if (last) return;
  if (tid < 5) a_sh[tid] = red[149 + tid] + rab[tid];
  __syncthreads();
  // 5. read filterbank (read params)
  {
    float gx = 32.5f * (a_sh[0] + 1.f);
    float gy = 32.5f * (a_sh[1] + 1.f);
    float i2v = 0.5f * expf(-a_sh[2]);
    float delta = (63.f / 11.f) * expf(a_sh[3]);
    for (int e = tid; e < 768; e += 256) {
      int n = e >> 6, p = e & 63;
      float mu_x = gx + ((float)n - 5.5f) * delta;
      float mu_y = gy + ((float)n - 5.5f) * delta;
      float dx = (float)(p + 1) - mu_x;
      float dy = (float)(p + 1) - mu_y;
      fx[n][p] = expf(-i2v * dx * dx);
      fy[n][p] = expf(-i2v * dy * dy);
    }
  }
  __syncthreads();
  if (tid < 24) {
    int n = tid % 12;
    float s = 0.f;
    if (tid < 12) { for (int p = 0; p < 64; ++p) s += fx[n][p]; }
    else          { for (int p = 0; p < 64; ++p) s += fy[n][p]; }
    srow[tid] = s + 6.4e-7f;
  }
  __syncthreads();
  for (int e = tid; e < 768; e += 256) {
    int n = e >> 6, p = e & 63;
    fx[n][p] /= srow[n];
    fy[n][p] /= srow[12 + n];
  }
  __syncthreads();
  // 6. read einsums
  for (int e = tid; e < 768; e += 256) {
    int n = e >> 6, w2 = e & 63;
    float s = 0.f, sh = 0.f;
    for (int hh = 0; hh < 64; ++hh) {
      float f = fy[n][hh];
      s  = fmaf(f, X[hh][w2], s);
      sh = fmaf(f, Xh[hh][w2], sh);
    }
    tmp[n][w2] = s; tmph[n][w2] = sh;
  }
  __syncthreads();
  if (tid < 144) {
    float gam = expf(a_sh[4]);
    int n = tid / 12, m = tid % 12;
    float s = 0.f, sh = 0.f;
    for (int w2 = 0; w2 < 64; ++w2) {
      float f = fx[m][w2];
      s  = fmaf(tmp[n][w2], f, s);
      sh = fmaf(tmph[n][w2], f, sh);
    }
    float v0 = gam * s, v1 = gam * sh;
    size_t i0 = (size_t)b * 320 + n * 12 + m;
    size_t i1 = i0 + 144;
    ushort_t h0, l0, h1, l1;
    splitf(v0, h0, l0); splitf(v1, h1, l1);
    rH[i0] = h0; rL[i0] = l0;
    rH[i1] = h1; rL[i1] = l1;
  }
}

// ---------------- LSTM gates: float4, reduce nz split-K parts + biases ----------------
typedef unsigned short us4 __attribute__((ext_vector_type(4)));
__global__ __launch_bounds__(256) void k_lstm(const float* __restrict__ g,
                                              unsigned GZ, int nz,
                                              const float* __restrict__ bih,
                                              const float* __restrict__ bhh,
                                              float* __restrict__ cst,
                                              ushort_t* __restrict__ hH,
                                              ushort_t* __restrict__ hL) {
  int q = blockIdx.x * 256 + threadIdx.x;   // quad index < 131072
  int b = q >> 8, uq = q & 255;             // 256 quads of u per batch row
  size_t base = (size_t)b * 1024;           // float4 units per row = 4096/4
  float4 ig = *(const float4*)&bih[uq * 4];
  float4 fg = *(const float4*)&bih[1024 + uq * 4];
  float4 gg = *(const float4*)&bih[2048 + uq * 4];
  float4 og = *(const float4*)&bih[3072 + uq * 4];
  {
    float4 t0 = *(const float4*)&bhh[uq * 4];
    float4 t1 = *(const float4*)&bhh[1024 + uq * 4];
    float4 t2 = *(const float4*)&bhh[2048 + uq * 4];
    float4 t3 = *(const float4*)&bhh[3072 + uq * 4];
    ig.x += t0.x; ig.y += t0.y; ig.z += t0.z; ig.w += t0.w;
    fg.x += t1.x; fg.y += t1.y; fg.z += t1.z; fg.w += t1.w;
    gg.x += t2.x; gg.y += t2.y; gg.z += t2.z; gg.w += t2.w;
    og.x += t3.x; og.y += t3.y; og.z += t3.z; og.w += t3.w;
  }
  for (int z = 0; z < nz; ++z) {
    const float* gz = g + (size_t)z * GZ + base * 4;
    float4 t0 = *(const float4*)&gz[uq * 4];
    float4 t1 = *(const float4*)&gz[1024 + uq * 4];
    float4 t2 = *(const float4*)&gz[2048 + uq * 4];
    float4 t3 = *(const float4*)&gz[3072 + uq * 4];
    ig.x += t0.x; ig.y += t0.y; ig.z += t0.z; ig.w += t0.w;
    fg.x += t1.x; fg.y += t1.y; fg.z += t1.z; fg.w += t1.w;
    gg.x += t2.x; gg.y += t2.y; gg.z += t2.z; gg.w += t2.w;
    og.x += t3.x; og.y += t3.y; og.z += t3.z; og.w += t3.w;
  }
  float4 cv = *(const float4*)&cst[(size_t)q * 4];
  float cva[4] = {cv.x, cv.y, cv.z, cv.w};
  float iga[4] = {ig.x, ig.y, ig.z, ig.w};
  float fga[4] = {fg.x, fg.y, fg.z, fg.w};
  float gga[4] = {gg.x, gg.y, gg.z, gg.w};
  float oga[4] = {og.x, og.y, og.z, og.w};
  us4 hhv, hlv;
  float cvo[4];
#pragma unroll
  for (int j = 0; j < 4; ++j) {
    float cnew = sigf(fga[j]) * cva[j] + sigf(iga[j]) * tanhf(gga[j]);
    cvo[j] = cnew;
    float hv = sigf(oga[j]) * tanhf(cnew);
    ushort_t hh, hl;
    splitf(hv, hh, hl);
    hhv[j] = hh; hlv[j] = hl;
  }
  *(float4*)&cst[(size_t)q * 4] = make_float4(cvo[0], cvo[1], cvo[2], cvo[3]);
  *(us4*)&hH[(size_t)q * 4] = hhv;
  *(us4*)&hL[(size_t)q * 4] = hlv;
}

// ---------------- host launch ----------------
extern "C" void kernel_launch(void* const* d_in, const int* in_sizes, int n_in,
                              void* d_out, int out_size, void* d_ws, size_t ws_size,
                              hipStream_t stream) {
  const float* x       = (const float*)d_in[0];
  const float* enc_Wih = (const float*)d_in[1];
  const float* enc_Whh = (const float*)d_in[2];
  const float* enc_bih = (const float*)d_in[3];
  const float* enc_bhh = (const float*)d_in[4];
  const float* dec_Wih = (const float*)d_in[5];
  const float* dec_Whh = (const float*)d_in[6];
  const float* dec_bih = (const float*)d_in[7];
  const float* dec_bhh = (const float*)d_in[8];
  const float* zW  = (const float*)d_in[9];
  const float* zb  = (const float*)d_in[10];
  const float* wW  = (const float*)d_in[11];
  const float* wb  = (const float*)d_in[12];
  const float* raW = (const float*)d_in[13];
  const float* rab = (const float*)d_in[14];
  const float* waW = (const float*)d_in[15];
  const float* wab = (const float*)d_in[16];

  float* out = (float*)d_out;
  float* c      = out;
  float* out_mu = out + 2097152;
  float* out_sg = out + 4194304;

  // ---- workspace layout: two-pass to pick NZ for the big GEMMs ----
  int NZ = 4;
  size_t need = 0;
  for (int pass = 0; pass < 2; ++pass) {
    size_t off = 0;
    auto sz = [&](size_t bytes) { off = (off + bytes + 255) & ~(size_t)255; };
    sz(2097152); sz(2097152);
    sz(1048576); sz(1048576); sz(1048576); sz(1048576);
    sz(327680); sz(327680);
    sz(524288); sz(524288);                        // cW padded to 256 rows
    sz(131072); sz(131072);
    sz((size_t)NZ * 8388608);
    sz(704);
    sz(10747904); sz(10747904);
    sz(8388608); sz(8388608);
    sz(1048576); sz(1048576);
    sz(8388608); sz(8388608);
    sz(524288); sz(524288);
    need = off;
    if (pass == 0 && ws_size < need) NZ = 2; else break;
  }

  char* base = (char*)d_ws;
  size_t off = 0;
  auto alloc = [&](size_t bytes) -> char* {
    char* p = base + off;
    off = (off + bytes + 255) & ~(size_t)255;
    return p;
  };
  // zero-block (contiguous, first)
  float* c_enc = (float*)alloc(2097152);
  float* c_dec = (float*)alloc(2097152);
  ushort_t* hdH = (ushort_t*)alloc(1048576);
  ushort_t* hdL = (ushort_t*)alloc(1048576);
  ushort_t* heH = (ushort_t*)alloc(1048576);
  ushort_t* heL = (ushort_t*)alloc(1048576);
  ushort_t* rH  = (ushort_t*)alloc(327680);   // 512 x 320 (cols 288..319 stay zero)
  ushort_t* rL  = (ushort_t*)alloc(327680);
  ushort_t* cWH = (ushort_t*)alloc(524288);   // 256 x 1024 (rows 154..255 stay zero)
  ushort_t* cWL = (ushort_t*)alloc(524288);
  size_t zero_bytes = off;
  // per-step buffers
  ushort_t* zH = (ushort_t*)alloc(131072);
  ushort_t* zL = (ushort_t*)alloc(131072);
  float* gbuf  = (float*)alloc((size_t)NZ * 8388608); // split-K parts; stats/wv alias
  float* cb    = (float*)alloc(704);          // 176 combined bias
  // weight splits (bf16 hi/lo)
  ushort_t* eWihH = (ushort_t*)alloc(10747904);
  ushort_t* eWihL = (ushort_t*)alloc(10747904);
  ushort_t* eWhhH = (ushort_t*)alloc(8388608);
  ushort_t* eWhhL = (ushort_t*)alloc(8388608);
  ushort_t* dWihH = (ushort_t*)alloc(1048576);
  ushort_t* dWihL = (ushort_t*)alloc(1048576);
  ushort_t* dWhhH = (ushort_t*)alloc(8388608);
  ushort_t* dWhhL = (ushort_t*)alloc(8388608);
  ushort_t* zWH   = (ushort_t*)alloc(524288);
  ushort_t* zWL   = (ushort_t*)alloc(524288);

  hipMemsetAsync(c, 0, (size_t)2097152 * sizeof(float), stream);
  hipMemsetAsync(base, 0, zero_bytes, stream);

  // split weights once per launch
  k_split<<<(5373952 + 255) / 256, 256, 0, stream>>>(enc_Wih, eWihH, eWihL, 5373952);
  k_split<<<(4194304 + 255) / 256, 256, 0, stream>>>(enc_Whh, eWhhH, eWhhL, 4194304);
  k_split<<<(524288 + 255) / 256, 256, 0, stream>>>(dec_Wih, dWihH, dWihL, 524288);
  k_split<<<(4194304 + 255) / 256, 256, 0, stream>>>(dec_Whh, dWhhH, dWhhL, 4194304);
  k_split<<<(262144 + 255) / 256, 256, 0, stream>>>(zW, zWH, zWL, 262144);
  k_split<<<(147456 + 255) / 256, 256, 0, stream>>>(wW, cWH, cWL, 147456);
  k_split<<<(5120 + 255) / 256, 256, 0, stream>>>(waW, cWH + 147456, cWL + 147456, 5120);
  k_split<<<(5120 + 255) / 256, 256, 0, stream>>>(raW, cWH + 152576, cWL + 152576, 5120);
  k_catbias<<<1, 176, 0, stream>>>(wb, wab, cb);

  SegList encS;   // T = 111
  encS.n = 9;
  encS.s[0] = {rH,  eWihH,       320,  320, 1312};
  encS.s[1] = {rL,  eWihH,       320,  320, 1312};
  encS.s[2] = {rH,  eWihL,       320,  320, 1312};
  encS.s[3] = {hdH, eWihH + 288, 1024, 1024, 1312};
  encS.s[4] = {hdL, eWihH + 288, 1024, 1024, 1312};
  encS.s[5] = {hdH, eWihL + 288, 1024, 1024, 1312};
  encS.s[6] = {heH, eWhhH,       1024, 1024, 1024};
  encS.s[7] = {heL, eWhhH,       1024, 1024, 1024};
  encS.s[8] = {heH, eWhhL,       1024, 1024, 1024};
  SegList decS;   // T = 54
  decS.n = 6;
  decS.s[0] = {zH,  dWihH, 128,  128, 128};
  decS.s[1] = {zL,  dWihH, 128,  128, 128};
  decS.s[2] = {zH,  dWihL, 128,  128, 128};
  decS.s[3] = {hdH, dWhhH, 1024, 1024, 1024};
  decS.s[4] = {hdL, dWhhH, 1024, 1024, 1024};
  decS.s[5] = {hdH, dWhhL, 1024, 1024, 1024};
  SegList staS;   // T = 48
  staS.n = 3;
  staS.s[0] = {heH, zWH, 1024, 1024, 1024};
  staS.s[1] = {heL, zWH, 1024, 1024, 1024};
  staS.s[2] = {heH, zWL, 1024, 1024, 1024};
  SegList wvS;    // T = 48 (N padded to 256, rows 154..255 of cW are zero)
  wvS.n = 3;
  wvS.s[0] = {hdH, cWH, 1024, 1024, 1024};
  wvS.s[1] = {hdL, cWH, 1024, 1024, 1024};
  wvS.s[2] = {hdH, cWL, 1024, 1024, 1024};

  const unsigned GZ = 2097152;   // elements per part (512x4096)
  const unsigned SZ = 131072;    // 512x256
  const unsigned WZ = 131072;    // 512x256 (wv padded)
  const int ipz_e = (111 + NZ - 1) / NZ;
  const int ipz_d = (54 + NZ - 1) / NZ;

  k_fread<<<512, 256, 0, stream>>>(x, c, rab, rH, rL);
  for (int t = 0; t < TT; ++t) {
    mfma_gemm<<<dim3(32, 4, NZ), 256, 0, stream>>>(gbuf, GZ, 4096, encS, ipz_e, 111);
    k_lstm<<<512, 256, 0, stream>>>(gbuf, GZ, NZ, enc_bih, enc_bhh, c_enc, heH, heL);
    mfma_gemm<<<dim3(2, 4, 8), 256, 0, stream>>>(gbuf, SZ, 256, staS, 6, 48);
    k_z<<<256, 256, 0, stream>>>(gbuf, SZ, 8, zb, zH, zL, out_mu, out_sg, t);
    mfma_gemm<<<dim3(32, 4, NZ), 256, 0, stream>>>(gbuf, GZ, 4096, decS, ipz_d, 54);
    k_lstm<<<512, 256, 0, stream>>>(gbuf, GZ, NZ, dec_bih, dec_bhh, c_dec, hdH, hdL);
    mfma_gemm<<<dim3(2, 4, 8), 256, 0, stream>>>(gbuf, WZ, 256, wvS, 6, 48);
    k_fwr<<<512, 256, 0, stream>>>(c, x, gbuf, WZ, 8, cb, rab, rH, rL, t == TT - 1);
  }
}